// Round 9
// baseline (4162.132 us; speedup 1.0000x reference)
//
#include <hip/hip_runtime.h>
#include <hip/hip_bf16.h>
#include <stdint.h>

#define B_    8
#define S_    1024
#define HIST_ 128
#define T_    1152
#define D_    1024
#define NH_   16
#define DH_   64
#define FF_   4096
#define L_    6
#define NROWS_ (B_*T_)   /* 9216 */

typedef __attribute__((ext_vector_type(8))) __bf16 bf16x8;
typedef __attribute__((ext_vector_type(4))) __bf16 bf16x4;
typedef __attribute__((ext_vector_type(4))) float  f32x4;

static __device__ __forceinline__ f32x4 mfma16(bf16x8 a, bf16x8 b, f32x4 c) {
  return __builtin_amdgcn_mfma_f32_16x16x32_bf16(a, b, c, 0, 0, 0);
}
static __device__ __forceinline__ void gload16(const __bf16* g, __bf16* l) {
  __builtin_amdgcn_global_load_lds((const __attribute__((address_space(1))) void*)g,
                                   (__attribute__((address_space(3))) void*)l, 16, 0, 0);
}
static __device__ __forceinline__ void gload16b(const char* g, char* l) {
  __builtin_amdgcn_global_load_lds((const __attribute__((address_space(1))) void*)g,
                                   (__attribute__((address_space(3))) void*)l, 16, 0, 0);
}
// bijective XCD swizzle (m204)
static __device__ __forceinline__ int xcd_swz(int orig, int nwg) {
  const int q = nwg >> 3, r = nwg & 7;
  const int x = orig & 7, i = orig >> 3;
  return (x < r ? x*(q+1) : r*(q+1) + (x-r)*q) + i;
}

// ---------------- 192x256 GEMM, BK=64, 8 waves (2Mx4N), counted-vmcnt pipeline ----------------
// C[M,N] = Aeff[M,K](bf16) @ Bt[N,K]^T(bf16) + bias; Aeff = (n0<asplit) ? A : A2.
// LDS 112 KiB (2 buf x 56 KB): [A ks0 12288][A ks1 12288][B ks0 16384][B ks1 16384]
// -> exactly 7 linear 8KB staging passes (512 thr x 16B); vmcnt(7) gate; vmcnt(0) last tile.
// OUTMODE: 0 = f32 RM (ldc), 1 = bf16 RM (ldc),
//          3 = split: col<tsplit -> bf16 RM CoutRM (ldc); col>=tsplit -> CoutT[(col-tsplit)*M+row]
// bias: col<s1 -> b1[col]; col<s2 -> b2[col-s1]; else b3[col-s2]
template<int OUTMODE, int RELU>
__global__ __launch_bounds__(512, 2) void gemm192_k(const __bf16* __restrict__ A,
                                                    const __bf16* __restrict__ A2, int asplit,
                                                    const __bf16* __restrict__ Bt,
                                                    const float* __restrict__ b1,
                                                    const float* __restrict__ b2,
                                                    const float* __restrict__ b3, int s1, int s2,
                                                    void* __restrict__ CoutRM,
                                                    __bf16* __restrict__ CoutT,
                                                    int M, int N, int K, int ldc, int tsplit) {
  __shared__ __align__(16) char Lds[2][57344];
  const int tid = threadIdx.x;
  const int wid = tid >> 6, ln = tid & 63;
  const int wm = wid >> 2, wn = wid & 3;
  const int l15 = ln & 15, g = ln >> 4;
  const int nbx = N >> 8;
  const int wg = xcd_swz(blockIdx.x, gridDim.x);
  const int m0 = (wg / nbx) * 192, n0 = (wg % nbx) << 8;
  const size_t rstep = (size_t)K * 2;
  const __bf16* Aeff = (n0 < asplit) ? A : A2;

  // 7 staging source pointers (pre-swizzled) + dest offsets
  const char* srcp[7];
  int dsto[7];
#pragma unroll
  for (int p = 0; p < 7; ++p) {
    const int off = p*8192 + tid*16;
    int mat, ks, row;
    if (off < 12288)      { mat = 0; ks = 0; row = off >> 6; }
    else if (off < 24576) { mat = 0; ks = 1; row = (off - 12288) >> 6; }
    else if (off < 40960) { mat = 1; ks = 0; row = (off - 24576) >> 6; }
    else                  { mat = 1; ks = 1; row = (off - 40960) >> 6; }
    const int ch = (off >> 4) & 3;
    const int kb = ks*64 + ((ch ^ ((row >> 1) & 3)) << 4);
    srcp[p] = (mat ? (const char*)Bt   + (size_t)(n0 + row)*rstep
                   : (const char*)Aeff + (size_t)(m0 + row)*rstep) + kb;
    dsto[p] = off;
  }
  auto stage = [&](int buf, int t) {
    char* lb = &Lds[buf][0];
    const size_t tb = (size_t)t << 7;
#pragma unroll
    for (int p = 0; p < 7; ++p) gload16b(srcp[p] + tb, lb + dsto[p]);
  };

  // read-side XOR swizzle
  const int xr = (g ^ ((l15 >> 1) & 3)) << 4;
  const int arow = l15*64 + xr;
  const int aoffm = (wm*96) * 64;
  const int boff  = 24576 + (wn*64) * 64;

  const f32x4 zero = {0.f,0.f,0.f,0.f};
  f32x4 acc[6][4];
#pragma unroll
  for (int i=0;i<6;i++)
#pragma unroll
    for (int j=0;j<4;j++) acc[i][j] = zero;

  stage(0, 0); stage(1, 1);

  const int NT = K >> 6;
  for (int t = 0; t < NT; ++t) {
    const int buf = t & 1;
    if (t == NT-1) { asm volatile("s_waitcnt vmcnt(0)" ::: "memory"); }
    else           { asm volatile("s_waitcnt vmcnt(7)" ::: "memory"); }
    __builtin_amdgcn_s_barrier();
    const char* bufp = &Lds[buf][0];
    bf16x8 a0[6], a1[6], b0[4], b1[4];
#pragma unroll
    for (int mi=0;mi<6;mi++) a0[mi] = *(const bf16x8*)(bufp + aoffm + mi*1024 + arow);
#pragma unroll
    for (int ni=0;ni<4;ni++) b0[ni] = *(const bf16x8*)(bufp + boff + ni*1024 + arow);
#pragma unroll
    for (int mi=0;mi<6;mi++) a1[mi] = *(const bf16x8*)(bufp + 12288 + aoffm + mi*1024 + arow);
    // ph1: ks0 (24 MFMA)
    __builtin_amdgcn_s_setprio(1);
#pragma unroll
    for (int mi=0;mi<6;mi++)
#pragma unroll
      for (int ni=0;ni<4;ni++) acc[mi][ni] = mfma16(a0[mi], b0[ni], acc[mi][ni]);
    __builtin_amdgcn_s_setprio(0);
#pragma unroll
    for (int ni=0;ni<4;ni++) b1[ni] = *(const bf16x8*)(bufp + boff + 16384 + ni*1024 + arow);
    asm volatile("s_waitcnt lgkmcnt(0)" ::: "memory");
    __builtin_amdgcn_sched_barrier(0);
    __builtin_amdgcn_s_barrier();           // all waves done reading buf
    if (t + 2 <= NT - 1) stage(buf, t + 2); // overwrite buf with tile t+2
    // ph2: ks1 (24 MFMA, registers only)
    __builtin_amdgcn_s_setprio(1);
#pragma unroll
    for (int mi=0;mi<6;mi++)
#pragma unroll
      for (int ni=0;ni<4;ni++) acc[mi][ni] = mfma16(a1[mi], b1[ni], acc[mi][ni]);
    __builtin_amdgcn_s_setprio(0);
  }

  // epilogue
  const int colb = n0 + wn*64 + l15;
#pragma unroll
  for (int mi=0;mi<6;mi++) {
    const int row = m0 + wm*96 + mi*16 + g*4;
#pragma unroll
    for (int ni=0;ni<4;ni++) {
      const int col = colb + ni*16;
      const float bv = (col < s1) ? b1[col] : ((col < s2) ? b2[col-s1] : b3[col-s2]);
      if (OUTMODE == 3 && col >= tsplit) {
        bf16x4 ct;
#pragma unroll
        for (int j=0;j<4;j++) {
          float v = acc[mi][ni][j] + bv;
          if (RELU) v = fmaxf(v, 0.f);
          ct[j] = (__bf16)v;
        }
        *(bf16x4*)(CoutT + (size_t)(col - tsplit)*M + row) = ct;
      } else {
#pragma unroll
        for (int j=0;j<4;j++) {
          float v = acc[mi][ni][j] + bv;
          if (RELU) v = fmaxf(v, 0.f);
          if (OUTMODE == 0) ((float*)CoutRM)[(size_t)(row+j)*ldc + col] = v;
          else              ((__bf16*)CoutRM)[(size_t)(row+j)*ldc + col] = (__bf16)v;
        }
      }
    }
  }
}

// ---------------- Flash attention, causal, NH=16 DH=64, T13 defer-max (unchanged) ----------------
__global__ __launch_bounds__(256) void attn_k(const __bf16* __restrict__ QK,
                                              const __bf16* __restrict__ Vt,
                                              __bf16* __restrict__ O) {
  __shared__ __align__(16) __bf16 Ks[2][4096];
  __shared__ __align__(16) __bf16 Vs[2][4096];
  __shared__ __align__(16) __bf16 Pl[4][32*72];
  const int tid = threadIdx.x;
  const int wv = tid >> 6, ln = tid & 63;
  const int l15 = ln & 15, g = ln >> 4;
  const int wg = xcd_swz(blockIdx.x, 1152);
  const int qb = 8 - (wg % 9);
  const int hd = (wg / 9) & 15;
  const int b  = wg / 144;
  const int q0 = qb*128 + wv*32;

  bf16x8 qf[2][2];
#pragma unroll
  for (int f=0; f<2; ++f)
#pragma unroll
    for (int h=0; h<2; ++h)
      qf[f][h] = *(const bf16x8*)(QK + (size_t)(b*T_ + q0 + f*16 + l15)*2048 + hd*64 + h*32 + g*8);

  const int sr = tid >> 3;
  const int si = tid & 7;
  const int cb0 = (si*16) ^ ((sr & 7) << 4);
  const char* kg = (const char*)(QK + (size_t)b*T_*2048 + 1024 + hd*64);
  const char* vg = (const char*)(Vt + (size_t)hd*64*NROWS_ + (size_t)b*T_);

  const f32x4 zero = {0.f,0.f,0.f,0.f};
  f32x4 o[2][4];
#pragma unroll
  for (int f=0; f<2; ++f)
#pragma unroll
    for (int d=0; d<4; ++d) o[f][d] = zero;
  float mrun[2] = {-3.0e38f, -3.0e38f};
  float lrun[2] = {0.f, 0.f};
  const int nt = 2*qb + 2;

  {
    const int c = 0, kt = 0;
#pragma unroll
    for (int hr=0; hr<2; ++hr) {
      const int r = sr + hr*32;
      gload16((const __bf16*)(kg + (size_t)(kt + r)*4096 + cb0), &Ks[c][0] + hr*2048 + wv*512);
      gload16((const __bf16*)(vg + (size_t)r*(NROWS_*2) + (size_t)kt*2 + cb0), &Vs[c][0] + hr*2048 + wv*512);
    }
  }

  for (int t = 0; t < nt; ++t) {
    __syncthreads();
    if (t+1 < nt) {
      const int c = (t+1)&1, kt2 = (t+1)*64;
#pragma unroll
      for (int hr=0; hr<2; ++hr) {
        const int r = sr + hr*32;
        gload16((const __bf16*)(kg + (size_t)(kt2 + r)*4096 + cb0), &Ks[c][0] + hr*2048 + wv*512);
        gload16((const __bf16*)(vg + (size_t)r*(NROWS_*2) + (size_t)kt2*2 + cb0), &Vs[c][0] + hr*2048 + wv*512);
      }
    }
    const int kt = t*64;
    if (kt > q0 + 31) continue;
    const char* ks = (const char*)&Ks[t&1][0];
    const char* vs = (const char*)&Vs[t&1][0];

#pragma unroll
    for (int f=0; f<2; ++f) {
      const int qrow = q0 + f*16 + l15;
      f32x4 st[4];
      __builtin_amdgcn_s_setprio(1);
#pragma unroll
      for (int kf=0; kf<4; ++kf) {
        const int row = kf*16 + l15;
        const int swz = (row & 7) << 4;
        const bf16x8 k0 = *(const bf16x8*)(ks + row*128 + ((g*16) ^ swz));
        const bf16x8 k1 = *(const bf16x8*)(ks + row*128 + ((64 + g*16) ^ swz));
        st[kf] = mfma16(k1, qf[f][1], mfma16(k0, qf[f][0], zero));
      }
      __builtin_amdgcn_s_setprio(0);
      float p[16];
#pragma unroll
      for (int kf=0; kf<4; ++kf)
#pragma unroll
        for (int r=0; r<4; ++r) {
          const int kgl = kt + kf*16 + g*4 + r;
          p[kf*4+r] = (kgl <= qrow) ? st[kf][r]*0.125f : -3.0e38f;
        }
      float mloc = p[0];
#pragma unroll
      for (int i=1;i<16;i++) mloc = fmaxf(mloc, p[i]);
      mloc = fmaxf(mloc, __shfl_xor(mloc, 16));
      mloc = fmaxf(mloc, __shfl_xor(mloc, 32));
      if (__all(mloc - mrun[f] <= 8.f)) {
        float ls = 0.f;
#pragma unroll
        for (int i=0;i<16;i++) { p[i] = __expf(p[i] - mrun[f]); ls += p[i]; }
        ls += __shfl_xor(ls, 16); ls += __shfl_xor(ls, 32);
        lrun[f] += ls;
      } else {
        const float mnew = fmaxf(mrun[f], mloc);
        const float corr = __expf(mrun[f] - mnew);
        float ls = 0.f;
#pragma unroll
        for (int i=0;i<16;i++) { p[i] = __expf(p[i] - mnew); ls += p[i]; }
        ls += __shfl_xor(ls, 16); ls += __shfl_xor(ls, 32);
        lrun[f] = lrun[f]*corr + ls;
        mrun[f] = mnew;
        float cr[4];
#pragma unroll
        for (int r=0;r<4;r++) cr[r] = __shfl(corr, g*4 + r);
#pragma unroll
        for (int db=0; db<4; ++db)
#pragma unroll
          for (int r=0;r<4;r++) o[f][db][r] *= cr[r];
      }
#pragma unroll
      for (int kf=0; kf<4; ++kf) {
        bf16x4 pw;
#pragma unroll
        for (int r=0;r<4;r++) pw[r] = (__bf16)p[kf*4+r];
        *(bf16x4*)(&Pl[wv][(f*16 + l15)*72 + kf*16 + g*4]) = pw;
      }
    }
    __builtin_amdgcn_s_setprio(1);
#pragma unroll
    for (int f=0; f<2; ++f)
#pragma unroll
      for (int ks2=0; ks2<2; ++ks2) {
        const bf16x8 pa = *(const bf16x8*)(&Pl[wv][(f*16 + l15)*72 + ks2*32 + g*8]);
#pragma unroll
        for (int db=0; db<4; ++db) {
          const int d = db*16 + l15;
          const bf16x8 vf = *(const bf16x8*)(vs + d*128 + ((ks2*64 + g*16) ^ ((d & 7) << 4)));
          o[f][db] = mfma16(pa, vf, o[f][db]);
        }
      }
    __builtin_amdgcn_s_setprio(0);
  }

#pragma unroll
  for (int f=0; f<2; ++f) {
    const float inv = 1.f / lrun[f];
    float ir[4];
#pragma unroll
    for (int r=0;r<4;r++) ir[r] = __shfl(inv, g*4 + r);
#pragma unroll
    for (int db=0; db<4; ++db)
#pragma unroll
      for (int r=0;r<4;r++)
        O[(size_t)(b*T_ + q0 + f*16 + g*4 + r)*D_ + hd*64 + db*16 + l15] = (__bf16)(o[f][db][r]*ir[r]);
  }
}

// ---------------- batched weight prep ----------------
__global__ __launch_bounds__(256) void wprep_k(const float* __restrict__ q, const float* __restrict__ k,
                                               const float* __restrict__ v, const float* __restrict__ o,
                                               const float* __restrict__ cq, const float* __restrict__ ck,
                                               const float* __restrict__ cv, const float* __restrict__ co,
                                               const float* __restrict__ f1, const float* __restrict__ f2,
                                               __bf16* __restrict__ wb) {
  __shared__ float tile[32][33];
  const int id = blockIdx.x;
  const float* src; __bf16* dst; int R, C, bx, by;
  if (id < 8192) {
    const int m = id >> 10, t = id & 1023; bx = t & 31; by = t >> 5;
    const float* srcs[8] = {q,k,v,o,cq,ck,cv,co};
    src = srcs[m]; dst = wb + (size_t)m*1048576; R = 1024; C = 1024;
  } else if (id < 12288) {
    const int t = id - 8192; bx = t & 127; by = t >> 7;
    src = f1; dst = wb + (size_t)8*1048576; R = 1024; C = 4096;
  } else {
    const int t = id - 12288; bx = t & 31; by = t >> 5;
    src = f2; dst = wb + (size_t)12*1048576; R = 4096; C = 1024;
  }
  const int tx = threadIdx.x & 31, ty = threadIdx.x >> 5;
  const int r0 = by*32, c0 = bx*32;
#pragma unroll
  for (int i=0;i<4;i++) tile[ty+i*8][tx] = src[(size_t)(r0+ty+i*8)*C + c0+tx];
  __syncthreads();
#pragma unroll
  for (int i=0;i<4;i++) dst[(size_t)(c0+ty+i*8)*R + r0+tx] = (__bf16)tile[tx][ty+i*8];
}

// ---------------- fused residual + LayerNorm (y is bf16) ----------------
__global__ __launch_bounds__(256) void ln_k(const float* __restrict__ zin, const __bf16* __restrict__ yin,
                                            const float* __restrict__ gam, const float* __restrict__ bet,
                                            float* __restrict__ zout, __bf16* __restrict__ zbout) {
  const int row = blockIdx.x, tid = threadIdx.x;
  const f32x4 zv = ((const f32x4*)(zin + (size_t)row*D_))[tid];
  const bf16x4 yv4 = ((const bf16x4*)(yin + (size_t)row*D_))[tid];
  f32x4 v;
#pragma unroll
  for (int j=0;j<4;j++) v[j] = zv[j] + (float)yv4[j];
  float s1 = v[0]+v[1]+v[2]+v[3];
  float s2 = v[0]*v[0]+v[1]*v[1]+v[2]*v[2]+v[3]*v[3];
#pragma unroll
  for (int off=32; off; off>>=1) { s1 += __shfl_xor(s1,off); s2 += __shfl_xor(s2,off); }
  __shared__ float red[8];
  const int wv = tid>>6, ln = tid&63;
  if (ln==0) { red[wv] = s1; red[4+wv] = s2; }
  __syncthreads();
  s1 = red[0]+red[1]+red[2]+red[3];
  s2 = red[4]+red[5]+red[6]+red[7];
  const float mean = s1 * (1.f/1024.f);
  const float var = s2 * (1.f/1024.f) - mean*mean;
  const float rs = rsqrtf(var + 1e-5f);
  const f32x4 gv = ((const f32x4*)gam)[tid];
  const f32x4 bv = ((const f32x4*)bet)[tid];
  f32x4 r; bf16x4 rb;
#pragma unroll
  for (int j=0;j<4;j++) { float t = (v[j]-mean)*rs*gv[j] + bv[j]; r[j] = t; rb[j] = (__bf16)t; }
  ((f32x4*)(zout + (size_t)row*D_))[tid] = r;
  ((bf16x4*)(zbout + (size_t)row*D_))[tid] = rb;
}

// ---------------- cond MLP branch hiddens ----------------
__global__ __launch_bounds__(256) void cond1_k(const int* __restrict__ t, const float* __restrict__ target,
                                               const float* __restrict__ action,
                                               const float* __restrict__ t_w1, const float* __restrict__ t_b1,
                                               const float* __restrict__ tg_w1, const float* __restrict__ tg_b1,
                                               const float* __restrict__ ac_w1, const float* __restrict__ ac_b1,
                                               float* __restrict__ h3) {
  const int i = blockIdx.x*256 + threadIdx.x;
  const int b = i >> 10, d = i & 1023;
  float u = (float)t[b] * t_w1[d] + t_b1[d];
  h3[i] = u / (1.f + __expf(-u));
  u = tg_b1[d];
#pragma unroll
  for (int j=0;j<3;j++) u += target[b*3+j]*tg_w1[j*1024+d];
  h3[8192 + i] = u / (1.f + __expf(-u));
  u = ac_b1[d];
#pragma unroll
  for (int j=0;j<5;j++) u += action[b*5+j]*ac_w1[j*1024+d];
  h3[16384 + i] = u / (1.f + __expf(-u));
}

__global__ __launch_bounds__(256) void cond2_k(const float* __restrict__ h3,
                                               const float* __restrict__ t_w2, const float* __restrict__ tg_w2,
                                               const float* __restrict__ ac_w2, float* __restrict__ cpart) {
  const int i = blockIdx.x*256 + threadIdx.x;
  const int ks = blockIdx.y;
  const int b = i >> 10, d = i & 1023;
  const float* ht = h3 + b*1024;
  const float* hg = h3 + 8192 + b*1024;
  const float* ha = h3 + 16384 + b*1024;
  float a = 0.f;
  for (int k = ks*128; k < ks*128+128; ++k)
    a += ht[k]*t_w2[(size_t)k*1024+d] + hg[k]*tg_w2[(size_t)k*1024+d] + ha[k]*ac_w2[(size_t)k*1024+d];
  cpart[ks*8192 + i] = a;
}

// ---------------- embedding ----------------
__global__ __launch_bounds__(256) void embed_k(const float* __restrict__ x, const float* __restrict__ hist,
                                               const float* __restrict__ in_w, const float* __restrict__ in_b,
                                               const float* __restrict__ cpart,
                                               const float* __restrict__ t_b2, const float* __restrict__ tg_b2,
                                               const float* __restrict__ ac_b2,
                                               float* __restrict__ z, __bf16* __restrict__ zb,
                                               __bf16* __restrict__ memb) {
  const int row = blockIdx.x, tid = threadIdx.x;
  const int b = row / T_, tt = row - b*T_;
  const float* feat = (tt < HIST_) ? (hist + ((size_t)b*HIST_ + tt)*10) : (x + ((size_t)b*S_ + (tt-HIST_))*10);
  float f[10];
#pragma unroll
  for (int s=0;s<10;s++) f[s] = feat[s];
  const float te = (float)((tt < HIST_) ? tt : tt - HIST_);
  f32x4 a = ((const f32x4*)in_b)[tid];
#pragma unroll
  for (int u=0;u<2;u++) {
    const int d = tid*4 + 2*u;
    const float freq = __expf((float)d * (-9.210340371976184f/1024.f));
    float sn, cs;
    __sincosf(te*freq, &sn, &cs);
    a[2*u] += sn; a[2*u+1] += cs;
  }
  a += ((const f32x4*)t_b2)[tid];
  a += ((const f32x4*)tg_b2)[tid];
  a += ((const f32x4*)ac_b2)[tid];
  const int cb = b*256 + tid;
#pragma unroll
  for (int ks=0;ks<8;ks++) a += ((const f32x4*)cpart)[ks*2048 + cb];
#pragma unroll
  for (int s=0;s<10;s++) {
    const f32x4 wv = ((const f32x4*)(in_w + s*1024))[tid];
    a += wv * f[s];
  }
  ((f32x4*)(z + (size_t)row*D_))[tid] = a;
  bf16x4 ab;
#pragma unroll
  for (int j=0;j<4;j++) ab[j] = (__bf16)a[j];
  ((bf16x4*)(zb + (size_t)row*D_))[tid] = ab;
  ((bf16x4*)(memb + (size_t)row*D_))[tid] = ab;
}

// ---------------- output projection ----------------
__global__ __launch_bounds__(256) void outp_k(const float* __restrict__ z, const float* __restrict__ w,
                                              const float* __restrict__ bo, float* __restrict__ out) {
  const int wv = threadIdx.x>>6, ln = threadIdx.x&63;
  const int row = blockIdx.x*4 + wv;
  const int b = row >> 10, s = row & 1023;
  const float* zr = z + ((size_t)b*T_ + HIST_ + s)*D_;
  float acc[10];
#pragma unroll
  for (int o=0;o<10;o++) acc[o]=0.f;
  for (int k=ln; k<1024; k+=64) {
    const float zv = zr[k];
    const float* wr = w + k*10;
#pragma unroll
    for (int o=0;o<10;o++) acc[o] += zv*wr[o];
  }
#pragma unroll
  for (int o=0;o<10;o++) {
#pragma unroll
    for (int off=32; off; off>>=1) acc[o] += __shfl_xor(acc[o], off);
  }
  if (ln==0) {
#pragma unroll
    for (int o=0;o<10;o++) out[(size_t)row*10+o] = acc[o] + bo[o];
  }
}

extern "C" void kernel_launch(void* const* d_in, const int* in_sizes, int n_in,
                              void* d_out, int out_size, void* d_ws, size_t ws_size,
                              hipStream_t stream) {
  const float* x      = (const float*)d_in[0];
  const int*   t      = (const int*)  d_in[1];
  const float* target = (const float*)d_in[2];
  const float* action = (const float*)d_in[3];
  const float* hist   = (const float*)d_in[4];
  const float* in_w   = (const float*)d_in[5];
  const float* in_b   = (const float*)d_in[6];
  const float* t_w1   = (const float*)d_in[7];
  const float* t_b1   = (const float*)d_in[8];
  const float* t_w2   = (const float*)d_in[9];
  const float* t_b2   = (const float*)d_in[10];
  const float* tg_w1  = (const float*)d_in[11];
  const float* tg_b1  = (const float*)d_in[12];
  const float* tg_w2  = (const float*)d_in[13];
  const float* tg_b2  = (const float*)d_in[14];
  const float* ac_w1  = (const float*)d_in[15];
  const float* ac_b1  = (const float*)d_in[16];
  const float* ac_w2  = (const float*)d_in[17];
  const float* ac_b2  = (const float*)d_in[18];
  const float* sa_wq  = (const float*)d_in[19];
  const float* sa_bq  = (const float*)d_in[20];
  const float* sa_wk  = (const float*)d_in[21];
  const float* sa_bk  = (const float*)d_in[22];
  const float* sa_wv  = (const float*)d_in[23];
  const float* sa_bv  = (const float*)d_in[24];
  const float* sa_wo  = (const float*)d_in[25];
  const float* sa_bo  = (const float*)d_in[26];
  const float* ca_wq  = (const float*)d_in[27];
  const float* ca_bq  = (const float*)d_in[28];
  const float* ca_wk  = (const float*)d_in[29];
  const float* ca_bk  = (const float*)d_in[30];
  const float* ca_wv  = (const float*)d_in[31];
  const float* ca_bv  = (const float*)d_in[32];
  const float* ca_wo  = (const float*)d_in[33];
  const float* ca_bo  = (const float*)d_in[34];
  const float* ln1_g  = (const float*)d_in[35];
  const float* ln1_b  = (const float*)d_in[36];
  const float* ln2_g  = (const float*)d_in[37];
  const float* ln2_b  = (const float*)d_in[38];
  const float* ln3_g  = (const float*)d_in[39];
  const float* ln3_b  = (const float*)d_in[40];
  const float* ff_w1  = (const float*)d_in[41];
  const float* ff_b1  = (const float*)d_in[42];
  const float* ff_w2  = (const float*)d_in[43];
  const float* ff_b2  = (const float*)d_in[44];
  const float* out_w  = (const float*)d_in[45];
  const float* out_b  = (const float*)d_in[46];

  if (ws_size < (size_t)224*1024*1024) return;

  char* p = (char*)d_ws;
  auto take = [&](size_t bytes) { char* r = p; p += (bytes + 255) & ~(size_t)255; return r; };
  __bf16* wbuf = (__bf16*)take((size_t)16*1024*1024*2);
  float*  z    = (float*) take((size_t)NROWS_*D_*4);
  __bf16* zb   = (__bf16*)take((size_t)NROWS_*D_*2);
  __bf16* memb = (__bf16*)take((size_t)NROWS_*D_*2);
  __bf16* qk   = (__bf16*)take((size_t)NROWS_*2048*2);
  __bf16* vt   = (__bf16*)take((size_t)1024*NROWS_*2);
  __bf16* ob   = (__bf16*)take((size_t)NROWS_*D_*2);
  __bf16* y    = (__bf16*)take((size_t)NROWS_*D_*2);
  float*  h3   = (float*) take((size_t)3*8192*4);
  float*  cpart= (float*) take((size_t)8*8192*4);
  __bf16* ffh  = qk;   // FFN hidden aliases qk+vt+ob (75.5 MB)

  const dim3 blk(256);
  const dim3 blk5(512);
  const int BIG = 1<<30;
  cond1_k<<<32, blk, 0, stream>>>(t, target, action, t_w1, t_b1, tg_w1, tg_b1, ac_w1, ac_b1, h3);
  cond2_k<<<dim3(32,8), blk, 0, stream>>>(h3, t_w2, tg_w2, ac_w2, cpart);
  embed_k<<<NROWS_, blk, 0, stream>>>(x, hist, in_w, in_b, cpart, t_b2, tg_b2, ac_b2, z, zb, memb);

  const int M = NROWS_;
  for (int li=0; li<L_; ++li) {
    const size_t w0 = (size_t)li*D_*D_, b0 = (size_t)li*D_;
    const size_t f1 = (size_t)li*D_*FF_, fb1 = (size_t)li*FF_;
    wprep_k<<<16384, blk, 0, stream>>>(sa_wq+w0, sa_wk+w0, sa_wv+w0, sa_wo+w0,
                                       ca_wq+w0, ca_wk+w0, ca_wv+w0, ca_wo+w0,
                                       ff_w1+f1, ff_w2+f1, wbuf);
    // self-attention: fused QKV (N=3072): cols 0-2047 -> qk RM; 2048+ -> vt transposed
    gemm192_k<3,0><<<48*12, blk5, 0, stream>>>(zb, zb, BIG, wbuf+0*1048576,
                                               sa_bq+b0, sa_bk+b0, sa_bv+b0, 1024, 2048,
                                               qk, vt, M, 3072, 1024, 2048, 2048);
    attn_k<<<1152, blk, 0, stream>>>(qk, vt, ob);
    gemm192_k<1,0><<<48*4, blk5, 0, stream>>>(ob, ob, BIG, wbuf+3*1048576,
                                              sa_bo+b0, sa_bo+b0, sa_bo+b0, BIG, BIG,
                                              y, vt, M, 1024, 1024, 1024, BIG);
    ln_k<<<NROWS_, blk, 0, stream>>>(z, y, ln1_g+b0, ln1_b+b0, z, zb);
    // cross-attention: fused Q|KV (N=3072); Q cols (<1024) read zb, K/V cols read memb
    gemm192_k<3,0><<<48*12, blk5, 0, stream>>>(zb, memb, 1024, wbuf+4*1048576,
                                               ca_bq+b0, ca_bk+b0, ca_bv+b0, 1024, 2048,
                                               qk, vt, M, 3072, 1024, 2048, 2048);
    attn_k<<<1152, blk, 0, stream>>>(qk, vt, ob);
    gemm192_k<1,0><<<48*4, blk5, 0, stream>>>(ob, ob, BIG, wbuf+7*1048576,
                                              ca_bo+b0, ca_bo+b0, ca_bo+b0, BIG, BIG,
                                              y, vt, M, 1024, 1024, 1024, BIG);
    ln_k<<<NROWS_, blk, 0, stream>>>(z, y, ln2_g+b0, ln2_b+b0, z, zb);
    // FFN
    gemm192_k<1,1><<<48*16, blk5, 0, stream>>>(zb, zb, BIG, wbuf+(size_t)8*1048576,
                                               ff_b1+fb1, ff_b1+fb1, ff_b1+fb1, BIG, BIG,
                                               ffh, vt, M, 4096, 1024, 4096, BIG);
    gemm192_k<1,0><<<48*4, blk5, 0, stream>>>(ffh, ffh, BIG, wbuf+(size_t)12*1048576,
                                              ff_b2+b0, ff_b2+b0, ff_b2+b0, BIG, BIG,
                                              y, vt, M, 1024, 4096, 1024, BIG);
    ln_k<<<NROWS_, blk, 0, stream>>>(z, y, ln3_g+b0, ln3_b+b0, z, zb);
  }
  outp_k<<<2048, blk, 0, stream>>>(z, out_w, out_b, (float*)d_out);
}

// Round 10
// 3939.525 us; speedup vs baseline: 1.0565x; 1.0565x over previous
//
#include <hip/hip_runtime.h>
#include <hip/hip_bf16.h>
#include <stdint.h>

#define B_    8
#define S_    1024
#define HIST_ 128
#define T_    1152
#define D_    1024
#define NH_   16
#define DH_   64
#define FF_   4096
#define L_    6
#define NROWS_ (B_*T_)   /* 9216 */

typedef __attribute__((ext_vector_type(8))) __bf16 bf16x8;
typedef __attribute__((ext_vector_type(4))) __bf16 bf16x4;
typedef __attribute__((ext_vector_type(4))) float  f32x4;

static __device__ __forceinline__ f32x4 mfma16(bf16x8 a, bf16x8 b, f32x4 c) {
  return __builtin_amdgcn_mfma_f32_16x16x32_bf16(a, b, c, 0, 0, 0);
}
static __device__ __forceinline__ void gload16(const __bf16* g, __bf16* l) {
  __builtin_amdgcn_global_load_lds((const __attribute__((address_space(1))) void*)g,
                                   (__attribute__((address_space(3))) void*)l, 16, 0, 0);
}
static __device__ __forceinline__ void gload16b(const char* g, char* l) {
  __builtin_amdgcn_global_load_lds((const __attribute__((address_space(1))) void*)g,
                                   (__attribute__((address_space(3))) void*)l, 16, 0, 0);
}
// bijective XCD swizzle (m204)
static __device__ __forceinline__ int xcd_swz(int orig, int nwg) {
  const int q = nwg >> 3, r = nwg & 7;
  const int x = orig & 7, i = orig >> 3;
  return (x < r ? x*(q+1) : r*(q+1) + (x-r)*q) + i;
}

// ---------------- 192x256 GEMM, BK=64, 8 waves (2Mx4N), counted-vmcnt pipeline ----------------
// (R8-proven: used for o-proj, FFN1, FFN2 — NOT for QKV, which regressed on this geometry)
template<int BF16OUT, int RELU>
__global__ __launch_bounds__(512, 2) void gemm192_k(const __bf16* __restrict__ A,
                                                    const __bf16* __restrict__ Bt,
                                                    const float* __restrict__ bias,
                                                    void* __restrict__ Cout,
                                                    int M, int N, int K, int ldc) {
  __shared__ __align__(16) char Lds[2][57344];
  const int tid = threadIdx.x;
  const int wid = tid >> 6, ln = tid & 63;
  const int wm = wid >> 2, wn = wid & 3;
  const int l15 = ln & 15, g = ln >> 4;
  const int nbx = N >> 8;
  const int wg = xcd_swz(blockIdx.x, gridDim.x);
  const int m0 = (wg / nbx) * 192, n0 = (wg % nbx) << 8;
  const size_t rstep = (size_t)K * 2;

  const char* srcp[7];
  int dsto[7];
#pragma unroll
  for (int p = 0; p < 7; ++p) {
    const int off = p*8192 + tid*16;
    int mat, ks, row;
    if (off < 12288)      { mat = 0; ks = 0; row = off >> 6; }
    else if (off < 24576) { mat = 0; ks = 1; row = (off - 12288) >> 6; }
    else if (off < 40960) { mat = 1; ks = 0; row = (off - 24576) >> 6; }
    else                  { mat = 1; ks = 1; row = (off - 40960) >> 6; }
    const int ch = (off >> 4) & 3;
    const int kb = ks*64 + ((ch ^ ((row >> 1) & 3)) << 4);
    srcp[p] = (mat ? (const char*)Bt + (size_t)(n0 + row)*rstep
                   : (const char*)A  + (size_t)(m0 + row)*rstep) + kb;
    dsto[p] = off;
  }
  auto stage = [&](int buf, int t) {
    char* lb = &Lds[buf][0];
    const size_t tb = (size_t)t << 7;
#pragma unroll
    for (int p = 0; p < 7; ++p) gload16b(srcp[p] + tb, lb + dsto[p]);
  };

  const int xr = (g ^ ((l15 >> 1) & 3)) << 4;
  const int arow = l15*64 + xr;
  const int aoffm = (wm*96) * 64;
  const int boff  = 24576 + (wn*64) * 64;

  const f32x4 zero = {0.f,0.f,0.f,0.f};
  f32x4 acc[6][4];
#pragma unroll
  for (int i=0;i<6;i++)
#pragma unroll
    for (int j=0;j<4;j++) acc[i][j] = zero;

  stage(0, 0); stage(1, 1);

  const int NT = K >> 6;
  for (int t = 0; t < NT; ++t) {
    const int buf = t & 1;
    if (t == NT-1) { asm volatile("s_waitcnt vmcnt(0)" ::: "memory"); }
    else           { asm volatile("s_waitcnt vmcnt(7)" ::: "memory"); }
    __builtin_amdgcn_s_barrier();
    const char* bufp = &Lds[buf][0];
    bf16x8 a0[6], a1[6], b0[4], b1[4];
#pragma unroll
    for (int mi=0;mi<6;mi++) a0[mi] = *(const bf16x8*)(bufp + aoffm + mi*1024 + arow);
#pragma unroll
    for (int ni=0;ni<4;ni++) b0[ni] = *(const bf16x8*)(bufp + boff + ni*1024 + arow);
#pragma unroll
    for (int mi=0;mi<6;mi++) a1[mi] = *(const bf16x8*)(bufp + 12288 + aoffm + mi*1024 + arow);
    __builtin_amdgcn_s_setprio(1);
#pragma unroll
    for (int mi=0;mi<6;mi++)
#pragma unroll
      for (int ni=0;ni<4;ni++) acc[mi][ni] = mfma16(a0[mi], b0[ni], acc[mi][ni]);
    __builtin_amdgcn_s_setprio(0);
#pragma unroll
    for (int ni=0;ni<4;ni++) b1[ni] = *(const bf16x8*)(bufp + boff + 16384 + ni*1024 + arow);
    asm volatile("s_waitcnt lgkmcnt(0)" ::: "memory");
    __builtin_amdgcn_sched_barrier(0);
    __builtin_amdgcn_s_barrier();
    if (t + 2 <= NT - 1) stage(buf, t + 2);
    __builtin_amdgcn_s_setprio(1);
#pragma unroll
    for (int mi=0;mi<6;mi++)
#pragma unroll
      for (int ni=0;ni<4;ni++) acc[mi][ni] = mfma16(a1[mi], b1[ni], acc[mi][ni]);
    __builtin_amdgcn_s_setprio(0);
  }

  const int colb = n0 + wn*64 + l15;
#pragma unroll
  for (int mi=0;mi<6;mi++) {
    const int row = m0 + wm*96 + mi*16 + g*4;
#pragma unroll
    for (int ni=0;ni<4;ni++) {
      const int col = colb + ni*16;
      const float bv = bias[col];
#pragma unroll
      for (int j=0;j<4;j++) {
        float v = acc[mi][ni][j] + bv;
        if (RELU) v = fmaxf(v, 0.f);
        if (BF16OUT) ((__bf16*)Cout)[(size_t)(row+j)*ldc + col] = (__bf16)v;
        else         ((float*)Cout)[(size_t)(row+j)*ldc + col] = v;
      }
    }
  }
}

// ---------------- 256x256 GEMM (QKV shapes) — R8-proven ----------------
template<int OUTMODE, int RELU>
__global__ __launch_bounds__(512, 2) void gemm256_k(const __bf16* __restrict__ A,
                                                    const __bf16* __restrict__ A2, int asplit,
                                                    const __bf16* __restrict__ Bt,
                                                    const float* __restrict__ b1,
                                                    const float* __restrict__ b2,
                                                    const float* __restrict__ b3, int s1, int s2,
                                                    void* __restrict__ CoutRM,
                                                    __bf16* __restrict__ CoutT,
                                                    int M, int N, int K, int ldc, int tsplit) {
  __shared__ __align__(16) __bf16 Lds[2][2][2][8192];
  const int tid = threadIdx.x;
  const int wid = tid >> 6, ln = tid & 63;
  const int wm = wid >> 2, wn = wid & 3;
  const int l15 = ln & 15, g = ln >> 4;
  const int nbx = N >> 8;
  const int wg = xcd_swz(blockIdx.x, gridDim.x);
  const int m0 = (wg / nbx) << 8, n0 = (wg % nbx) << 8;
  const size_t rstep = (size_t)K * 2;
  const __bf16* Aeff = (n0 < asplit) ? A : A2;

  const int srow = tid >> 2, schunk = tid & 3;
  const int sx = (schunk ^ ((srow >> 1) & 3)) << 4;
  const char* gAr = (const char*)Aeff + (size_t)(m0 + srow)*rstep + sx;
  const char* gBr = (const char*)Bt   + (size_t)(n0 + srow)*rstep + sx;
  const size_t hstep = (size_t)128 * rstep;

  const int xr = (g ^ ((l15 >> 1) & 3)) << 4;
  const int arow = l15 * 64 + xr;
  const int aoffm = (wm*128) * 64;
  const int boff  = (wn*64) * 64;

  const f32x4 zero = {0.f,0.f,0.f,0.f};
  f32x4 acc[8][4];
#pragma unroll
  for (int i=0;i<8;i++)
#pragma unroll
    for (int j=0;j<4;j++) acc[i][j] = zero;

  auto stage4 = [&](int buf, int ks, int tile) {
    const size_t off = (size_t)tile*128 + (size_t)ks*64;
    char* la = (char*)&Lds[buf][ks][0][0];
    char* lb = (char*)&Lds[buf][ks][1][0];
    gload16b(gAr + off,         la + tid*16);
    gload16b(gAr + off + hstep, la + 8192 + tid*16);
    gload16b(gBr + off,         lb + tid*16);
    gload16b(gBr + off + hstep, lb + 8192 + tid*16);
  };

  auto ktile = [&](int buf, bool st, int stile, bool gate0) {
    if (gate0) { asm volatile("s_waitcnt vmcnt(0)" ::: "memory"); }
    else       { asm volatile("s_waitcnt vmcnt(8)" ::: "memory"); }
    __builtin_amdgcn_s_barrier();
    const char* As0 = (const char*)&Lds[buf][0][0][0];
    const char* Bs0 = (const char*)&Lds[buf][0][1][0];
    const char* As1 = (const char*)&Lds[buf][1][0][0];
    const char* Bs1 = (const char*)&Lds[buf][1][1][0];
    bf16x8 a0[4], a1[4], b0[4], a2[4], b1v[4], a3[4];
#pragma unroll
    for (int mi=0;mi<4;mi++) a0[mi] = *(const bf16x8*)(As0 + aoffm + mi*1024 + arow);
#pragma unroll
    for (int ni=0;ni<4;ni++) b0[ni] = *(const bf16x8*)(Bs0 + boff + ni*1024 + arow);
#pragma unroll
    for (int mi=0;mi<4;mi++) a1[mi] = *(const bf16x8*)(As0 + aoffm + 4096 + mi*1024 + arow);
    __builtin_amdgcn_s_setprio(1);
#pragma unroll
    for (int mi=0;mi<4;mi++)
#pragma unroll
      for (int ni=0;ni<4;ni++) acc[mi][ni] = mfma16(a0[mi], b0[ni], acc[mi][ni]);
    __builtin_amdgcn_s_setprio(0);
#pragma unroll
    for (int mi=0;mi<4;mi++) a2[mi]  = *(const bf16x8*)(As1 + aoffm + mi*1024 + arow);
#pragma unroll
    for (int ni=0;ni<4;ni++) b1v[ni] = *(const bf16x8*)(Bs1 + boff + ni*1024 + arow);
    asm volatile("s_waitcnt lgkmcnt(0)" ::: "memory");
    __builtin_amdgcn_s_barrier();
    if (st) stage4(buf, 0, stile);
    __builtin_amdgcn_s_setprio(1);
#pragma unroll
    for (int mi=0;mi<4;mi++)
#pragma unroll
      for (int ni=0;ni<4;ni++) acc[4+mi][ni] = mfma16(a1[mi], b0[ni], acc[4+mi][ni]);
    __builtin_amdgcn_s_setprio(0);
#pragma unroll
    for (int mi=0;mi<4;mi++) a3[mi] = *(const bf16x8*)(As1 + aoffm + 4096 + mi*1024 + arow);
    __builtin_amdgcn_s_setprio(1);
#pragma unroll
    for (int mi=0;mi<4;mi++)
#pragma unroll
      for (int ni=0;ni<4;ni++) acc[mi][ni] = mfma16(a2[mi], b1v[ni], acc[mi][ni]);
    __builtin_amdgcn_s_setprio(0);
    asm volatile("s_waitcnt lgkmcnt(0)" ::: "memory");
    __builtin_amdgcn_s_barrier();
    if (st) stage4(buf, 1, stile);
    __builtin_amdgcn_s_setprio(1);
#pragma unroll
    for (int mi=0;mi<4;mi++)
#pragma unroll
      for (int ni=0;ni<4;ni++) acc[4+mi][ni] = mfma16(a3[mi], b1v[ni], acc[4+mi][ni]);
    __builtin_amdgcn_s_setprio(0);
  };

  stage4(0, 0, 0); stage4(0, 1, 0);
  stage4(1, 0, 1); stage4(1, 1, 1);

  const int NT = K >> 6, NI = NT >> 1;
  for (int i = 0; i < NI; ++i) {
    const bool st = (i + 1 < NI);
    ktile(0, st, 2*i + 2, false);
    ktile(1, st, 2*i + 3, i == NI - 1);
  }

  const int colb = n0 + wn*64 + l15;
#pragma unroll
  for (int mi=0;mi<8;mi++) {
    const int row = m0 + wm*128 + mi*16 + g*4;
#pragma unroll
    for (int ni=0;ni<4;ni++) {
      const int col = colb + ni*16;
      const float bv = (col < s1) ? b1[col] : ((col < s2) ? b2[col-s1] : b3[col-s2]);
      if (OUTMODE == 3 && col >= tsplit) {
        bf16x4 ct;
#pragma unroll
        for (int j=0;j<4;j++) {
          float v = acc[mi][ni][j] + bv;
          if (RELU) v = fmaxf(v, 0.f);
          ct[j] = (__bf16)v;
        }
        *(bf16x4*)(CoutT + (size_t)(col - tsplit)*M + row) = ct;
      } else {
#pragma unroll
        for (int j=0;j<4;j++) {
          float v = acc[mi][ni][j] + bv;
          if (RELU) v = fmaxf(v, 0.f);
          if (OUTMODE == 0) ((float*)CoutRM)[(size_t)(row+j)*ldc + col] = v;
          else              ((__bf16*)CoutRM)[(size_t)(row+j)*ldc + col] = (__bf16)v;
        }
      }
    }
  }
}

// ---------------- Flash attention, causal, NH=16 DH=64, T13 defer-max (unchanged) ----------------
__global__ __launch_bounds__(256) void attn_k(const __bf16* __restrict__ QK,
                                              const __bf16* __restrict__ Vt,
                                              __bf16* __restrict__ O) {
  __shared__ __align__(16) __bf16 Ks[2][4096];
  __shared__ __align__(16) __bf16 Vs[2][4096];
  __shared__ __align__(16) __bf16 Pl[4][32*72];
  const int tid = threadIdx.x;
  const int wv = tid >> 6, ln = tid & 63;
  const int l15 = ln & 15, g = ln >> 4;
  const int wg = xcd_swz(blockIdx.x, 1152);
  const int qb = 8 - (wg % 9);
  const int hd = (wg / 9) & 15;
  const int b  = wg / 144;
  const int q0 = qb*128 + wv*32;

  bf16x8 qf[2][2];
#pragma unroll
  for (int f=0; f<2; ++f)
#pragma unroll
    for (int h=0; h<2; ++h)
      qf[f][h] = *(const bf16x8*)(QK + (size_t)(b*T_ + q0 + f*16 + l15)*2048 + hd*64 + h*32 + g*8);

  const int sr = tid >> 3;
  const int si = tid & 7;
  const int cb0 = (si*16) ^ ((sr & 7) << 4);
  const char* kg = (const char*)(QK + (size_t)b*T_*2048 + 1024 + hd*64);
  const char* vg = (const char*)(Vt + (size_t)hd*64*NROWS_ + (size_t)b*T_);

  const f32x4 zero = {0.f,0.f,0.f,0.f};
  f32x4 o[2][4];
#pragma unroll
  for (int f=0; f<2; ++f)
#pragma unroll
    for (int d=0; d<4; ++d) o[f][d] = zero;
  float mrun[2] = {-3.0e38f, -3.0e38f};
  float lrun[2] = {0.f, 0.f};
  const int nt = 2*qb + 2;

  {
    const int c = 0, kt = 0;
#pragma unroll
    for (int hr=0; hr<2; ++hr) {
      const int r = sr + hr*32;
      gload16((const __bf16*)(kg + (size_t)(kt + r)*4096 + cb0), &Ks[c][0] + hr*2048 + wv*512);
      gload16((const __bf16*)(vg + (size_t)r*(NROWS_*2) + (size_t)kt*2 + cb0), &Vs[c][0] + hr*2048 + wv*512);
    }
  }

  for (int t = 0; t < nt; ++t) {
    __syncthreads();
    if (t+1 < nt) {
      const int c = (t+1)&1, kt2 = (t+1)*64;
#pragma unroll
      for (int hr=0; hr<2; ++hr) {
        const int r = sr + hr*32;
        gload16((const __bf16*)(kg + (size_t)(kt2 + r)*4096 + cb0), &Ks[c][0] + hr*2048 + wv*512);
        gload16((const __bf16*)(vg + (size_t)r*(NROWS_*2) + (size_t)kt2*2 + cb0), &Vs[c][0] + hr*2048 + wv*512);
      }
    }
    const int kt = t*64;
    if (kt > q0 + 31) continue;
    const char* ks = (const char*)&Ks[t&1][0];
    const char* vs = (const char*)&Vs[t&1][0];

#pragma unroll
    for (int f=0; f<2; ++f) {
      const int qrow = q0 + f*16 + l15;
      f32x4 st[4];
      __builtin_amdgcn_s_setprio(1);
#pragma unroll
      for (int kf=0; kf<4; ++kf) {
        const int row = kf*16 + l15;
        const int swz = (row & 7) << 4;
        const bf16x8 k0 = *(const bf16x8*)(ks + row*128 + ((g*16) ^ swz));
        const bf16x8 k1 = *(const bf16x8*)(ks + row*128 + ((64 + g*16) ^ swz));
        st[kf] = mfma16(k1, qf[f][1], mfma16(k0, qf[f][0], zero));
      }
      __builtin_amdgcn_s_setprio(0);
      float p[16];
#pragma unroll
      for (int kf=0; kf<4; ++kf)
#pragma unroll
        for (int r=0; r<4; ++r) {
          const int kgl = kt + kf*16 + g*4 + r;
          p[kf*4+r] = (kgl <= qrow) ? st[kf][r]*0.125f : -3.0e38f;
        }
      float mloc = p[0];
#pragma unroll
      for (int i=1;i<16;i++) mloc = fmaxf(mloc, p[i]);
      mloc = fmaxf(mloc, __shfl_xor(mloc, 16));
      mloc = fmaxf(mloc, __shfl_xor(mloc, 32));
      if (__all(mloc - mrun[f] <= 8.f)) {
        float ls = 0.f;
#pragma unroll
        for (int i=0;i<16;i++) { p[i] = __expf(p[i] - mrun[f]); ls += p[i]; }
        ls += __shfl_xor(ls, 16); ls += __shfl_xor(ls, 32);
        lrun[f] += ls;
      } else {
        const float mnew = fmaxf(mrun[f], mloc);
        const float corr = __expf(mrun[f] - mnew);
        float ls = 0.f;
#pragma unroll
        for (int i=0;i<16;i++) { p[i] = __expf(p[i] - mnew); ls += p[i]; }
        ls += __shfl_xor(ls, 16); ls += __shfl_xor(ls, 32);
        lrun[f] = lrun[f]*corr + ls;
        mrun[f] = mnew;
        float cr[4];
#pragma unroll
        for (int r=0;r<4;r++) cr[r] = __shfl(corr, g*4 + r);
#pragma unroll
        for (int db=0; db<4; ++db)
#pragma unroll
          for (int r=0;r<4;r++) o[f][db][r] *= cr[r];
      }
#pragma unroll
      for (int kf=0; kf<4; ++kf) {
        bf16x4 pw;
#pragma unroll
        for (int r=0;r<4;r++) pw[r] = (__bf16)p[kf*4+r];
        *(bf16x4*)(&Pl[wv][(f*16 + l15)*72 + kf*16 + g*4]) = pw;
      }
    }
    __builtin_amdgcn_s_setprio(1);
#pragma unroll
    for (int f=0; f<2; ++f)
#pragma unroll
      for (int ks2=0; ks2<2; ++ks2) {
        const bf16x8 pa = *(const bf16x8*)(&Pl[wv][(f*16 + l15)*72 + ks2*32 + g*8]);
#pragma unroll
        for (int db=0; db<4; ++db) {
          const int d = db*16 + l15;
          const bf16x8 vf = *(const bf16x8*)(vs + d*128 + ((ks2*64 + g*16) ^ ((d & 7) << 4)));
          o[f][db] = mfma16(pa, vf, o[f][db]);
        }
      }
    __builtin_amdgcn_s_setprio(0);
  }

#pragma unroll
  for (int f=0; f<2; ++f) {
    const float inv = 1.f / lrun[f];
    float ir[4];
#pragma unroll
    for (int r=0;r<4;r++) ir[r] = __shfl(inv, g*4 + r);
#pragma unroll
    for (int db=0; db<4; ++db)
#pragma unroll
      for (int r=0;r<4;r++)
        O[(size_t)(b*T_ + q0 + f*16 + g*4 + r)*D_ + hd*64 + db*16 + l15] = (__bf16)(o[f][db][r]*ir[r]);
  }
}

// ---------------- batched weight prep: 64x64 tiles (4096 blocks, 4x fewer than before) ----------------
// blocks 0..2047: eight 1024x1024 (id>>8 selects matrix, 16x16 tiles of 64);
// 2048..3071: ff1 1024x4096 (16x64); 3072..4095: ff2 4096x1024 (64x16)
__global__ __launch_bounds__(256) void wprep_k(const float* __restrict__ q, const float* __restrict__ k,
                                               const float* __restrict__ v, const float* __restrict__ o,
                                               const float* __restrict__ cq, const float* __restrict__ ck,
                                               const float* __restrict__ cv, const float* __restrict__ co,
                                               const float* __restrict__ f1, const float* __restrict__ f2,
                                               __bf16* __restrict__ wb) {
  __shared__ float tile[64][65];
  const int id = blockIdx.x;
  const float* src; __bf16* dst; int R, C, bx, by;
  if (id < 2048) {
    const int m = id >> 8, t = id & 255; bx = t & 15; by = t >> 4;
    const float* srcs[8] = {q,k,v,o,cq,ck,cv,co};
    src = srcs[m]; dst = wb + (size_t)m*1048576; R = 1024; C = 1024;
  } else if (id < 3072) {
    const int t = id - 2048; bx = t & 63; by = t >> 6;
    src = f1; dst = wb + (size_t)8*1048576; R = 1024; C = 4096;
  } else {
    const int t = id - 3072; bx = t & 15; by = t >> 4;
    src = f2; dst = wb + (size_t)12*1048576; R = 4096; C = 1024;
  }
  const int tx = threadIdx.x & 63, ty = threadIdx.x >> 6;   // 64 x 4
  const int r0 = by*64, c0 = bx*64;
#pragma unroll
  for (int i=0;i<16;i++) tile[ty+i*4][tx] = src[(size_t)(r0+ty+i*4)*C + c0+tx];
  __syncthreads();
#pragma unroll
  for (int i=0;i<16;i++) dst[(size_t)(c0+ty+i*4)*R + r0+tx] = (__bf16)tile[tx][ty+i*4];
}

// ---------------- fused residual + LayerNorm (y is bf16) ----------------
__global__ __launch_bounds__(256) void ln_k(const float* __restrict__ zin, const __bf16* __restrict__ yin,
                                            const float* __restrict__ gam, const float* __restrict__ bet,
                                            float* __restrict__ zout, __bf16* __restrict__ zbout) {
  const int row = blockIdx.x, tid = threadIdx.x;
  const f32x4 zv = ((const f32x4*)(zin + (size_t)row*D_))[tid];
  const bf16x4 yv4 = ((const bf16x4*)(yin + (size_t)row*D_))[tid];
  f32x4 v;
#pragma unroll
  for (int j=0;j<4;j++) v[j] = zv[j] + (float)yv4[j];
  float s1 = v[0]+v[1]+v[2]+v[3];
  float s2 = v[0]*v[0]+v[1]*v[1]+v[2]*v[2]+v[3]*v[3];
#pragma unroll
  for (int off=32; off; off>>=1) { s1 += __shfl_xor(s1,off); s2 += __shfl_xor(s2,off); }
  __shared__ float red[8];
  const int wv = tid>>6, ln = tid&63;
  if (ln==0) { red[wv] = s1; red[4+wv] = s2; }
  __syncthreads();
  s1 = red[0]+red[1]+red[2]+red[3];
  s2 = red[4]+red[5]+red[6]+red[7];
  const float mean = s1 * (1.f/1024.f);
  const float var = s2 * (1.f/1024.f) - mean*mean;
  const float rs = rsqrtf(var + 1e-5f);
  const f32x4 gv = ((const f32x4*)gam)[tid];
  const f32x4 bv = ((const f32x4*)bet)[tid];
  f32x4 r; bf16x4 rb;
#pragma unroll
  for (int j=0;j<4;j++) { float t = (v[j]-mean)*rs*gv[j] + bv[j]; r[j] = t; rb[j] = (__bf16)t; }
  ((f32x4*)(zout + (size_t)row*D_))[tid] = r;
  ((bf16x4*)(zbout + (size_t)row*D_))[tid] = rb;
}

// ---------------- cond MLP branch hiddens ----------------
__global__ __launch_bounds__(256) void cond1_k(const int* __restrict__ t, const float* __restrict__ target,
                                               const float* __restrict__ action,
                                               const float* __restrict__ t_w1, const float* __restrict__ t_b1,
                                               const float* __restrict__ tg_w1, const float* __restrict__ tg_b1,
                                               const float* __restrict__ ac_w1, const float* __restrict__ ac_b1,
                                               float* __restrict__ h3) {
  const int i = blockIdx.x*256 + threadIdx.x;
  const int b = i >> 10, d = i & 1023;
  float u = (float)t[b] * t_w1[d] + t_b1[d];
  h3[i] = u / (1.f + __expf(-u));
  u = tg_b1[d];
#pragma unroll
  for (int j=0;j<3;j++) u += target[b*3+j]*tg_w1[j*1024+d];
  h3[8192 + i] = u / (1.f + __expf(-u));
  u = ac_b1[d];
#pragma unroll
  for (int j=0;j<5;j++) u += action[b*5+j]*ac_w1[j*1024+d];
  h3[16384 + i] = u / (1.f + __expf(-u));
}

__global__ __launch_bounds__(256) void cond2_k(const float* __restrict__ h3,
                                               const float* __restrict__ t_w2, const float* __restrict__ tg_w2,
                                               const float* __restrict__ ac_w2, float* __restrict__ cpart) {
  const int i = blockIdx.x*256 + threadIdx.x;
  const int ks = blockIdx.y;
  const int b = i >> 10, d = i & 1023;
  const float* ht = h3 + b*1024;
  const float* hg = h3 + 8192 + b*1024;
  const float* ha = h3 + 16384 + b*1024;
  float a = 0.f;
  for (int k = ks*128; k < ks*128+128; ++k)
    a += ht[k]*t_w2[(size_t)k*1024+d] + hg[k]*tg_w2[(size_t)k*1024+d] + ha[k]*ac_w2[(size_t)k*1024+d];
  cpart[ks*8192 + i] = a;
}

// ---------------- embedding ----------------
__global__ __launch_bounds__(256) void embed_k(const float* __restrict__ x, const float* __restrict__ hist,
                                               const float* __restrict__ in_w, const float* __restrict__ in_b,
                                               const float* __restrict__ cpart,
                                               const float* __restrict__ t_b2, const float* __restrict__ tg_b2,
                                               const float* __restrict__ ac_b2,
                                               float* __restrict__ z, __bf16* __restrict__ zb,
                                               __bf16* __restrict__ memb) {
  const int row = blockIdx.x, tid = threadIdx.x;
  const int b = row / T_, tt = row - b*T_;
  const float* feat = (tt < HIST_) ? (hist + ((size_t)b*HIST_ + tt)*10) : (x + ((size_t)b*S_ + (tt-HIST_))*10);
  float f[10];
#pragma unroll
  for (int s=0;s<10;s++) f[s] = feat[s];
  const float te = (float)((tt < HIST_) ? tt : tt - HIST_);
  f32x4 a = ((const f32x4*)in_b)[tid];
#pragma unroll
  for (int u=0;u<2;u++) {
    const int d = tid*4 + 2*u;
    const float freq = __expf((float)d * (-9.210340371976184f/1024.f));
    float sn, cs;
    __sincosf(te*freq, &sn, &cs);
    a[2*u] += sn; a[2*u+1] += cs;
  }
  a += ((const f32x4*)t_b2)[tid];
  a += ((const f32x4*)tg_b2)[tid];
  a += ((const f32x4*)ac_b2)[tid];
  const int cb = b*256 + tid;
#pragma unroll
  for (int ks=0;ks<8;ks++) a += ((const f32x4*)cpart)[ks*2048 + cb];
#pragma unroll
  for (int s=0;s<10;s++) {
    const f32x4 wv = ((const f32x4*)(in_w + s*1024))[tid];
    a += wv * f[s];
  }
  ((f32x4*)(z + (size_t)row*D_))[tid] = a;
  bf16x4 ab;
#pragma unroll
  for (int j=0;j<4;j++) ab[j] = (__bf16)a[j];
  ((bf16x4*)(zb + (size_t)row*D_))[tid] = ab;
  ((bf16x4*)(memb + (size_t)row*D_))[tid] = ab;
}

// ---------------- output projection ----------------
__global__ __launch_bounds__(256) void outp_k(const float* __restrict__ z, const float* __restrict__ w,
                                              const float* __restrict__ bo, float* __restrict__ out) {
  const int wv = threadIdx.x>>6, ln = threadIdx.x&63;
  const int row = blockIdx.x*4 + wv;
  const int b = row >> 10, s = row & 1023;
  const float* zr = z + ((size_t)b*T_ + HIST_ + s)*D_;
  float acc[10];
#pragma unroll
  for (int o=0;o<10;o++) acc[o]=0.f;
  for (int k=ln; k<1024; k+=64) {
    const float zv = zr[k];
    const float* wr = w + k*10;
#pragma unroll
    for (int o=0;o<10;o++) acc[o] += zv*wr[o];
  }
#pragma unroll
  for (int o=0;o<10;o++) {
#pragma unroll
    for (int off=32; off; off>>=1) acc[o] += __shfl_xor(acc[o], off);
  }
  if (ln==0) {
#pragma unroll
    for (int o=0;o<10;o++) out[(size_t)row*10+o] = acc[o] + bo[o];
  }
}

extern "C" void kernel_launch(void* const* d_in, const int* in_sizes, int n_in,
                              void* d_out, int out_size, void* d_ws, size_t ws_size,
                              hipStream_t stream) {
  const float* x      = (const float*)d_in[0];
  const int*   t      = (const int*)  d_in[1];
  const float* target = (const float*)d_in[2];
  const float* action = (const float*)d_in[3];
  const float* hist   = (const float*)d_in[4];
  const float* in_w   = (const float*)d_in[5];
  const float* in_b   = (const float*)d_in[6];
  const float* t_w1   = (const float*)d_in[7];
  const float* t_b1   = (const float*)d_in[8];
  const float* t_w2   = (const float*)d_in[9];
  const float* t_b2   = (const float*)d_in[10];
  const float* tg_w1  = (const float*)d_in[11];
  const float* tg_b1  = (const float*)d_in[12];
  const float* tg_w2  = (const float*)d_in[13];
  const float* tg_b2  = (const float*)d_in[14];
  const float* ac_w1  = (const float*)d_in[15];
  const float* ac_b1  = (const float*)d_in[16];
  const float* ac_w2  = (const float*)d_in[17];
  const float* ac_b2  = (const float*)d_in[18];
  const float* sa_wq  = (const float*)d_in[19];
  const float* sa_bq  = (const float*)d_in[20];
  const float* sa_wk  = (const float*)d_in[21];
  const float* sa_bk  = (const float*)d_in[22];
  const float* sa_wv  = (const float*)d_in[23];
  const float* sa_bv  = (const float*)d_in[24];
  const float* sa_wo  = (const float*)d_in[25];
  const float* sa_bo  = (const float*)d_in[26];
  const float* ca_wq  = (const float*)d_in[27];
  const float* ca_bq  = (const float*)d_in[28];
  const float* ca_wk  = (const float*)d_in[29];
  const float* ca_bk  = (const float*)d_in[30];
  const float* ca_wv  = (const float*)d_in[31];
  const float* ca_bv  = (const float*)d_in[32];
  const float* ca_wo  = (const float*)d_in[33];
  const float* ca_bo  = (const float*)d_in[34];
  const float* ln1_g  = (const float*)d_in[35];
  const float* ln1_b  = (const float*)d_in[36];
  const float* ln2_g  = (const float*)d_in[37];
  const float* ln2_b  = (const float*)d_in[38];
  const float* ln3_g  = (const float*)d_in[39];
  const float* ln3_b  = (const float*)d_in[40];
  const float* ff_w1  = (const float*)d_in[41];
  const float* ff_b1  = (const float*)d_in[42];
  const float* ff_w2  = (const float*)d_in[43];
  const float* ff_b2  = (const float*)d_in[44];
  const float* out_w  = (const float*)d_in[45];
  const float* out_b  = (const float*)d_in[46];

  if (ws_size < (size_t)224*1024*1024) return;

  char* p = (char*)d_ws;
  auto take = [&](size_t bytes) { char* r = p; p += (bytes + 255) & ~(size_t)255; return r; };
  __bf16* wbuf = (__bf16*)take((size_t)16*1024*1024*2);
  float*  z    = (float*) take((size_t)NROWS_*D_*4);
  __bf16* zb   = (__bf16*)take((size_t)NROWS_*D_*2);
  __bf16* memb = (__bf16*)take((size_t)NROWS_*D_*2);
  __bf16* qk   = (__bf16*)take((size_t)NROWS_*2048*2);
  __bf16* vt   = (__bf16*)take((size_t)1024*NROWS_*2);
  __bf16* ob   = (__bf16*)take((size_t)NROWS_*D_*2);
  __bf16* y    = (__bf16*)take((size_t)NROWS_*D_*2);
  float*  h3   = (float*) take((size_t)3*8192*4);
  float*  cpart= (float*) take((size_t)8*8192*4);
  __bf16* ffh  = qk;   // FFN hidden aliases qk+vt+ob (75.5 MB)

  const dim3 blk(256);
  const dim3 blk5(512);
  const int BIG = 1<<30;
  cond1_k<<<32, blk, 0, stream>>>(t, target, action, t_w1, t_b1, tg_w1, tg_b1, ac_w1, ac_b1, h3);
  cond2_k<<<dim3(32,8), blk, 0, stream>>>(h3, t_w2, tg_w2, ac_w2, cpart);
  embed_k<<<NROWS_, blk, 0, stream>>>(x, hist, in_w, in_b, cpart, t_b2, tg_b2, ac_b2, z, zb, memb);

  const int M = NROWS_;
  for (int li=0; li<L_; ++li) {
    const size_t w0 = (size_t)li*D_*D_, b0 = (size_t)li*D_;
    const size_t f1 = (size_t)li*D_*FF_, fb1 = (size_t)li*FF_;
    wprep_k<<<4096, blk, 0, stream>>>(sa_wq+w0, sa_wk+w0, sa_wv+w0, sa_wo+w0,
                                      ca_wq+w0, ca_wk+w0, ca_wv+w0, ca_wo+w0,
                                      ff_w1+f1, ff_w2+f1, wbuf);
    // self-attention: fused QKV (N=3072), 256^2 kernel (R8-proven)
    gemm256_k<3,0><<<36*12, blk5, 0, stream>>>(zb, zb, BIG, wbuf+0*1048576,
                                               sa_bq+b0, sa_bk+b0, sa_bv+b0, 1024, 2048,
                                               qk, vt, M, 3072, 1024, 2048, 2048);
    attn_k<<<1152, blk, 0, stream>>>(qk, vt, ob);
    gemm192_k<1,0><<<48*4, blk5, 0, stream>>>(ob, wbuf+3*1048576, sa_bo+b0, y, M, 1024, 1024, 1024);
    ln_k<<<NROWS_, blk, 0, stream>>>(z, y, ln1_g+b0, ln1_b+b0, z, zb);
    // cross-attention: fused Q|KV (N=3072); Q cols read zb, K/V cols read memb
    gemm256_k<3,0><<<36*12, blk5, 0, stream>>>(zb, memb, 1024, wbuf+4*1048576,
                                               ca_bq+b0, ca_bk+b0, ca_bv+b0, 1024, 2048,
                                               qk, vt, M, 3072, 1024, 2048, 2048);
    attn_k<<<1152, blk, 0, stream>>>(qk, vt, ob);
    gemm192_k<1,0><<<48*4, blk5, 0, stream>>>(ob, wbuf+7*1048576, ca_bo+b0, y, M, 1024, 1024, 1024);
    ln_k<<<NROWS_, blk, 0, stream>>>(z, y, ln2_g+b0, ln2_b+b0, z, zb);
    // FFN
    gemm192_k<1,1><<<48*16, blk5, 0, stream>>>(zb, wbuf+(size_t)8*1048576, ff_b1+fb1, ffh, M, 4096, 1024, 4096);
    gemm192_k<1,0><<<48*4, blk5, 0, stream>>>(ffh, wbuf+(size_t)12*1048576, ff_b2+b0, y, M, 1024, 4096, 1024);
    ln_k<<<NROWS_, blk, 0, stream>>>(z, y, ln3_g+b0, ln3_b+b0, z, zb);
  }
  outp_k<<<2048, blk, 0, stream>>>(z, out_w, out_b, (float*)d_out);
}

// Round 11
// 3905.431 us; speedup vs baseline: 1.0657x; 1.0087x over previous
//
#include <hip/hip_runtime.h>
#include <hip/hip_bf16.h>
#include <stdint.h>

#define B_    8
#define S_    1024
#define HIST_ 128
#define T_    1152
#define D_    1024
#define NH_   16
#define DH_   64
#define FF_   4096
#define L_    6
#define NROWS_ (B_*T_)   /* 9216 */

typedef __attribute__((ext_vector_type(8))) __bf16 bf16x8;
typedef __attribute__((ext_vector_type(4))) __bf16 bf16x4;
typedef __attribute__((ext_vector_type(4))) float  f32x4;

static __device__ __forceinline__ f32x4 mfma16(bf16x8 a, bf16x8 b, f32x4 c) {
  return __builtin_amdgcn_mfma_f32_16x16x32_bf16(a, b, c, 0, 0, 0);
}
static __device__ __forceinline__ void gload16(const __bf16* g, __bf16* l) {
  __builtin_amdgcn_global_load_lds((const __attribute__((address_space(1))) void*)g,
                                   (__attribute__((address_space(3))) void*)l, 16, 0, 0);
}
static __device__ __forceinline__ void gload16b(const char* g, char* l) {
  __builtin_amdgcn_global_load_lds((const __attribute__((address_space(1))) void*)g,
                                   (__attribute__((address_space(3))) void*)l, 16, 0, 0);
}
// bijective XCD swizzle (m204)
static __device__ __forceinline__ int xcd_swz(int orig, int nwg) {
  const int q = nwg >> 3, r = nwg & 7;
  const int x = orig & 7, i = orig >> 3;
  return (x < r ? x*(q+1) : r*(q+1) + (x-r)*q) + i;
}

// ---------------- 192x256 GEMM, BK=64, 8 waves (2Mx4N), counted-vmcnt pipeline ----------------
// (o-proj / FFN1 / FFN2) — RESADD fuses the residual add: out = acc + bias + resid (f32)
template<int BF16OUT, int RELU, int RESADD>
__global__ __launch_bounds__(512, 2) void gemm192_k(const __bf16* __restrict__ A,
                                                    const __bf16* __restrict__ Bt,
                                                    const float* __restrict__ bias,
                                                    void* __restrict__ Cout,
                                                    const __bf16* __restrict__ resid,
                                                    int M, int N, int K, int ldc) {
  __shared__ __align__(16) char Lds[2][57344];
  const int tid = threadIdx.x;
  const int wid = tid >> 6, ln = tid & 63;
  const int wm = wid >> 2, wn = wid & 3;
  const int l15 = ln & 15, g = ln >> 4;
  const int nbx = N >> 8;
  const int wg = xcd_swz(blockIdx.x, gridDim.x);
  const int m0 = (wg / nbx) * 192, n0 = (wg % nbx) << 8;
  const size_t rstep = (size_t)K * 2;

  const char* srcp[7];
  int dsto[7];
#pragma unroll
  for (int p = 0; p < 7; ++p) {
    const int off = p*8192 + tid*16;
    int mat, ks, row;
    if (off < 12288)      { mat = 0; ks = 0; row = off >> 6; }
    else if (off < 24576) { mat = 0; ks = 1; row = (off - 12288) >> 6; }
    else if (off < 40960) { mat = 1; ks = 0; row = (off - 24576) >> 6; }
    else                  { mat = 1; ks = 1; row = (off - 40960) >> 6; }
    const int ch = (off >> 4) & 3;
    const int kb = ks*64 + ((ch ^ ((row >> 1) & 3)) << 4);
    srcp[p] = (mat ? (const char*)Bt + (size_t)(n0 + row)*rstep
                   : (const char*)A  + (size_t)(m0 + row)*rstep) + kb;
    dsto[p] = off;
  }
  auto stage = [&](int buf, int t) {
    char* lb = &Lds[buf][0];
    const size_t tb = (size_t)t << 7;
#pragma unroll
    for (int p = 0; p < 7; ++p) gload16b(srcp[p] + tb, lb + dsto[p]);
  };

  const int xr = (g ^ ((l15 >> 1) & 3)) << 4;
  const int arow = l15*64 + xr;
  const int aoffm = (wm*96) * 64;
  const int boff  = 24576 + (wn*64) * 64;

  const f32x4 zero = {0.f,0.f,0.f,0.f};
  f32x4 acc[6][4];
#pragma unroll
  for (int i=0;i<6;i++)
#pragma unroll
    for (int j=0;j<4;j++) acc[i][j] = zero;

  stage(0, 0); stage(1, 1);

  const int NT = K >> 6;
  for (int t = 0; t < NT; ++t) {
    const int buf = t & 1;
    if (t == NT-1) { asm volatile("s_waitcnt vmcnt(0)" ::: "memory"); }
    else           { asm volatile("s_waitcnt vmcnt(7)" ::: "memory"); }
    __builtin_amdgcn_s_barrier();
    const char* bufp = &Lds[buf][0];
    bf16x8 a0[6], a1[6], b0[4], b1[4];
#pragma unroll
    for (int mi=0;mi<6;mi++) a0[mi] = *(const bf16x8*)(bufp + aoffm + mi*1024 + arow);
#pragma unroll
    for (int ni=0;ni<4;ni++) b0[ni] = *(const bf16x8*)(bufp + boff + ni*1024 + arow);
#pragma unroll
    for (int mi=0;mi<6;mi++) a1[mi] = *(const bf16x8*)(bufp + 12288 + aoffm + mi*1024 + arow);
    __builtin_amdgcn_s_setprio(1);
#pragma unroll
    for (int mi=0;mi<6;mi++)
#pragma unroll
      for (int ni=0;ni<4;ni++) acc[mi][ni] = mfma16(a0[mi], b0[ni], acc[mi][ni]);
    __builtin_amdgcn_s_setprio(0);
#pragma unroll
    for (int ni=0;ni<4;ni++) b1[ni] = *(const bf16x8*)(bufp + boff + 16384 + ni*1024 + arow);
    asm volatile("s_waitcnt lgkmcnt(0)" ::: "memory");
    __builtin_amdgcn_sched_barrier(0);
    __builtin_amdgcn_s_barrier();
    if (t + 2 <= NT - 1) stage(buf, t + 2);
    __builtin_amdgcn_s_setprio(1);
#pragma unroll
    for (int mi=0;mi<6;mi++)
#pragma unroll
      for (int ni=0;ni<4;ni++) acc[mi][ni] = mfma16(a1[mi], b1[ni], acc[mi][ni]);
    __builtin_amdgcn_s_setprio(0);
  }

  const int colb = n0 + wn*64 + l15;
#pragma unroll
  for (int mi=0;mi<6;mi++) {
    const int row = m0 + wm*96 + mi*16 + g*4;
#pragma unroll
    for (int ni=0;ni<4;ni++) {
      const int col = colb + ni*16;
      const float bv = bias[col];
#pragma unroll
      for (int j=0;j<4;j++) {
        float v = acc[mi][ni][j] + bv;
        if (RESADD) v += (float)resid[(size_t)(row+j)*ldc + col];
        if (RELU) v = fmaxf(v, 0.f);
        if (BF16OUT) ((__bf16*)Cout)[(size_t)(row+j)*ldc + col] = (__bf16)v;
        else         ((float*)Cout)[(size_t)(row+j)*ldc + col] = v;
      }
    }
  }
}

// ---------------- 256x256 GEMM (QKV shapes) — R8-proven ----------------
template<int OUTMODE, int RELU>
__global__ __launch_bounds__(512, 2) void gemm256_k(const __bf16* __restrict__ A,
                                                    const __bf16* __restrict__ A2, int asplit,
                                                    const __bf16* __restrict__ Bt,
                                                    const float* __restrict__ b1,
                                                    const float* __restrict__ b2,
                                                    const float* __restrict__ b3, int s1, int s2,
                                                    void* __restrict__ CoutRM,
                                                    __bf16* __restrict__ CoutT,
                                                    int M, int N, int K, int ldc, int tsplit) {
  __shared__ __align__(16) __bf16 Lds[2][2][2][8192];
  const int tid = threadIdx.x;
  const int wid = tid >> 6, ln = tid & 63;
  const int wm = wid >> 2, wn = wid & 3;
  const int l15 = ln & 15, g = ln >> 4;
  const int nbx = N >> 8;
  const int wg = xcd_swz(blockIdx.x, gridDim.x);
  const int m0 = (wg / nbx) << 8, n0 = (wg % nbx) << 8;
  const size_t rstep = (size_t)K * 2;
  const __bf16* Aeff = (n0 < asplit) ? A : A2;

  const int srow = tid >> 2, schunk = tid & 3;
  const int sx = (schunk ^ ((srow >> 1) & 3)) << 4;
  const char* gAr = (const char*)Aeff + (size_t)(m0 + srow)*rstep + sx;
  const char* gBr = (const char*)Bt   + (size_t)(n0 + srow)*rstep + sx;
  const size_t hstep = (size_t)128 * rstep;

  const int xr = (g ^ ((l15 >> 1) & 3)) << 4;
  const int arow = l15 * 64 + xr;
  const int aoffm = (wm*128) * 64;
  const int boff  = (wn*64) * 64;

  const f32x4 zero = {0.f,0.f,0.f,0.f};
  f32x4 acc[8][4];
#pragma unroll
  for (int i=0;i<8;i++)
#pragma unroll
    for (int j=0;j<4;j++) acc[i][j] = zero;

  auto stage4 = [&](int buf, int ks, int tile) {
    const size_t off = (size_t)tile*128 + (size_t)ks*64;
    char* la = (char*)&Lds[buf][ks][0][0];
    char* lb = (char*)&Lds[buf][ks][1][0];
    gload16b(gAr + off,         la + tid*16);
    gload16b(gAr + off + hstep, la + 8192 + tid*16);
    gload16b(gBr + off,         lb + tid*16);
    gload16b(gBr + off + hstep, lb + 8192 + tid*16);
  };

  auto ktile = [&](int buf, bool st, int stile, bool gate0) {
    if (gate0) { asm volatile("s_waitcnt vmcnt(0)" ::: "memory"); }
    else       { asm volatile("s_waitcnt vmcnt(8)" ::: "memory"); }
    __builtin_amdgcn_s_barrier();
    const char* As0 = (const char*)&Lds[buf][0][0][0];
    const char* Bs0 = (const char*)&Lds[buf][0][1][0];
    const char* As1 = (const char*)&Lds[buf][1][0][0];
    const char* Bs1 = (const char*)&Lds[buf][1][1][0];
    bf16x8 a0[4], a1[4], b0[4], a2[4], b1v[4], a3[4];
#pragma unroll
    for (int mi=0;mi<4;mi++) a0[mi] = *(const bf16x8*)(As0 + aoffm + mi*1024 + arow);
#pragma unroll
    for (int ni=0;ni<4;ni++) b0[ni] = *(const bf16x8*)(Bs0 + boff + ni*1024 + arow);
#pragma unroll
    for (int mi=0;mi<4;mi++) a1[mi] = *(const bf16x8*)(As0 + aoffm + 4096 + mi*1024 + arow);
    __builtin_amdgcn_s_setprio(1);
#pragma unroll
    for (int mi=0;mi<4;mi++)
#pragma unroll
      for (int ni=0;ni<4;ni++) acc[mi][ni] = mfma16(a0[mi], b0[ni], acc[mi][ni]);
    __builtin_amdgcn_s_setprio(0);
#pragma unroll
    for (int mi=0;mi<4;mi++) a2[mi]  = *(const bf16x8*)(As1 + aoffm + mi*1024 + arow);
#pragma unroll
    for (int ni=0;ni<4;ni++) b1v[ni] = *(const bf16x8*)(Bs1 + boff + ni*1024 + arow);
    asm volatile("s_waitcnt lgkmcnt(0)" ::: "memory");
    __builtin_amdgcn_s_barrier();
    if (st) stage4(buf, 0, stile);
    __builtin_amdgcn_s_setprio(1);
#pragma unroll
    for (int mi=0;mi<4;mi++)
#pragma unroll
      for (int ni=0;ni<4;ni++) acc[4+mi][ni] = mfma16(a1[mi], b0[ni], acc[4+mi][ni]);
    __builtin_amdgcn_s_setprio(0);
#pragma unroll
    for (int mi=0;mi<4;mi++) a3[mi] = *(const bf16x8*)(As1 + aoffm + 4096 + mi*1024 + arow);
    __builtin_amdgcn_s_setprio(1);
#pragma unroll
    for (int mi=0;mi<4;mi++)
#pragma unroll
      for (int ni=0;ni<4;ni++) acc[mi][ni] = mfma16(a2[mi], b1v[ni], acc[mi][ni]);
    __builtin_amdgcn_s_setprio(0);
    asm volatile("s_waitcnt lgkmcnt(0)" ::: "memory");
    __builtin_amdgcn_s_barrier();
    if (st) stage4(buf, 1, stile);
    __builtin_amdgcn_s_setprio(1);
#pragma unroll
    for (int mi=0;mi<4;mi++)
#pragma unroll
      for (int ni=0;ni<4;ni++) acc[4+mi][ni] = mfma16(a3[mi], b1v[ni], acc[4+mi][ni]);
    __builtin_amdgcn_s_setprio(0);
  };

  stage4(0, 0, 0); stage4(0, 1, 0);
  stage4(1, 0, 1); stage4(1, 1, 1);

  const int NT = K >> 6, NI = NT >> 1;
  for (int i = 0; i < NI; ++i) {
    const bool st = (i + 1 < NI);
    ktile(0, st, 2*i + 2, false);
    ktile(1, st, 2*i + 3, i == NI - 1);
  }

  const int colb = n0 + wn*64 + l15;
#pragma unroll
  for (int mi=0;mi<8;mi++) {
    const int row = m0 + wm*128 + mi*16 + g*4;
#pragma unroll
    for (int ni=0;ni<4;ni++) {
      const int col = colb + ni*16;
      const float bv = (col < s1) ? b1[col] : ((col < s2) ? b2[col-s1] : b3[col-s2]);
      if (OUTMODE == 3 && col >= tsplit) {
        bf16x4 ct;
#pragma unroll
        for (int j=0;j<4;j++) {
          float v = acc[mi][ni][j] + bv;
          if (RELU) v = fmaxf(v, 0.f);
          ct[j] = (__bf16)v;
        }
        *(bf16x4*)(CoutT + (size_t)(col - tsplit)*M + row) = ct;
      } else {
#pragma unroll
        for (int j=0;j<4;j++) {
          float v = acc[mi][ni][j] + bv;
          if (RELU) v = fmaxf(v, 0.f);
          if (OUTMODE == 0) ((float*)CoutRM)[(size_t)(row+j)*ldc + col] = v;
          else              ((__bf16*)CoutRM)[(size_t)(row+j)*ldc + col] = (__bf16)v;
        }
      }
    }
  }
}

// ---------------- Flash attention, causal, NH=16 DH=64, T13 defer-max (unchanged) ----------------
__global__ __launch_bounds__(256) void attn_k(const __bf16* __restrict__ QK,
                                              const __bf16* __restrict__ Vt,
                                              __bf16* __restrict__ O) {
  __shared__ __align__(16) __bf16 Ks[2][4096];
  __shared__ __align__(16) __bf16 Vs[2][4096];
  __shared__ __align__(16) __bf16 Pl[4][32*72];
  const int tid = threadIdx.x;
  const int wv = tid >> 6, ln = tid & 63;
  const int l15 = ln & 15, g = ln >> 4;
  const int wg = xcd_swz(blockIdx.x, 1152);
  const int qb = 8 - (wg % 9);
  const int hd = (wg / 9) & 15;
  const int b  = wg / 144;
  const int q0 = qb*128 + wv*32;

  bf16x8 qf[2][2];
#pragma unroll
  for (int f=0; f<2; ++f)
#pragma unroll
    for (int h=0; h<2; ++h)
      qf[f][h] = *(const bf16x8*)(QK + (size_t)(b*T_ + q0 + f*16 + l15)*2048 + hd*64 + h*32 + g*8);

  const int sr = tid >> 3;
  const int si = tid & 7;
  const int cb0 = (si*16) ^ ((sr & 7) << 4);
  const char* kg = (const char*)(QK + (size_t)b*T_*2048 + 1024 + hd*64);
  const char* vg = (const char*)(Vt + (size_t)hd*64*NROWS_ + (size_t)b*T_);

  const f32x4 zero = {0.f,0.f,0.f,0.f};
  f32x4 o[2][4];
#pragma unroll
  for (int f=0; f<2; ++f)
#pragma unroll
    for (int d=0; d<4; ++d) o[f][d] = zero;
  float mrun[2] = {-3.0e38f, -3.0e38f};
  float lrun[2] = {0.f, 0.f};
  const int nt = 2*qb + 2;

  {
    const int c = 0, kt = 0;
#pragma unroll
    for (int hr=0; hr<2; ++hr) {
      const int r = sr + hr*32;
      gload16((const __bf16*)(kg + (size_t)(kt + r)*4096 + cb0), &Ks[c][0] + hr*2048 + wv*512);
      gload16((const __bf16*)(vg + (size_t)r*(NROWS_*2) + (size_t)kt*2 + cb0), &Vs[c][0] + hr*2048 + wv*512);
    }
  }

  for (int t = 0; t < nt; ++t) {
    __syncthreads();
    if (t+1 < nt) {
      const int c = (t+1)&1, kt2 = (t+1)*64;
#pragma unroll
      for (int hr=0; hr<2; ++hr) {
        const int r = sr + hr*32;
        gload16((const __bf16*)(kg + (size_t)(kt2 + r)*4096 + cb0), &Ks[c][0] + hr*2048 + wv*512);
        gload16((const __bf16*)(vg + (size_t)r*(NROWS_*2) + (size_t)kt2*2 + cb0), &Vs[c][0] + hr*2048 + wv*512);
      }
    }
    const int kt = t*64;
    if (kt > q0 + 31) continue;
    const char* ks = (const char*)&Ks[t&1][0];
    const char* vs = (const char*)&Vs[t&1][0];

#pragma unroll
    for (int f=0; f<2; ++f) {
      const int qrow = q0 + f*16 + l15;
      f32x4 st[4];
      __builtin_amdgcn_s_setprio(1);
#pragma unroll
      for (int kf=0; kf<4; ++kf) {
        const int row = kf*16 + l15;
        const int swz = (row & 7) << 4;
        const bf16x8 k0 = *(const bf16x8*)(ks + row*128 + ((g*16) ^ swz));
        const bf16x8 k1 = *(const bf16x8*)(ks + row*128 + ((64 + g*16) ^ swz));
        st[kf] = mfma16(k1, qf[f][1], mfma16(k0, qf[f][0], zero));
      }
      __builtin_amdgcn_s_setprio(0);
      float p[16];
#pragma unroll
      for (int kf=0; kf<4; ++kf)
#pragma unroll
        for (int r=0; r<4; ++r) {
          const int kgl = kt + kf*16 + g*4 + r;
          p[kf*4+r] = (kgl <= qrow) ? st[kf][r]*0.125f : -3.0e38f;
        }
      float mloc = p[0];
#pragma unroll
      for (int i=1;i<16;i++) mloc = fmaxf(mloc, p[i]);
      mloc = fmaxf(mloc, __shfl_xor(mloc, 16));
      mloc = fmaxf(mloc, __shfl_xor(mloc, 32));
      if (__all(mloc - mrun[f] <= 8.f)) {
        float ls = 0.f;
#pragma unroll
        for (int i=0;i<16;i++) { p[i] = __expf(p[i] - mrun[f]); ls += p[i]; }
        ls += __shfl_xor(ls, 16); ls += __shfl_xor(ls, 32);
        lrun[f] += ls;
      } else {
        const float mnew = fmaxf(mrun[f], mloc);
        const float corr = __expf(mrun[f] - mnew);
        float ls = 0.f;
#pragma unroll
        for (int i=0;i<16;i++) { p[i] = __expf(p[i] - mnew); ls += p[i]; }
        ls += __shfl_xor(ls, 16); ls += __shfl_xor(ls, 32);
        lrun[f] = lrun[f]*corr + ls;
        mrun[f] = mnew;
        float cr[4];
#pragma unroll
        for (int r=0;r<4;r++) cr[r] = __shfl(corr, g*4 + r);
#pragma unroll
        for (int db=0; db<4; ++db)
#pragma unroll
          for (int r=0;r<4;r++) o[f][db][r] *= cr[r];
      }
#pragma unroll
      for (int kf=0; kf<4; ++kf) {
        bf16x4 pw;
#pragma unroll
        for (int r=0;r<4;r++) pw[r] = (__bf16)p[kf*4+r];
        *(bf16x4*)(&Pl[wv][(f*16 + l15)*72 + kf*16 + g*4]) = pw;
      }
    }
    __builtin_amdgcn_s_setprio(1);
#pragma unroll
    for (int f=0; f<2; ++f)
#pragma unroll
      for (int ks2=0; ks2<2; ++ks2) {
        const bf16x8 pa = *(const bf16x8*)(&Pl[wv][(f*16 + l15)*72 + ks2*32 + g*8]);
#pragma unroll
        for (int db=0; db<4; ++db) {
          const int d = db*16 + l15;
          const bf16x8 vf = *(const bf16x8*)(vs + d*128 + ((ks2*64 + g*16) ^ ((d & 7) << 4)));
          o[f][db] = mfma16(pa, vf, o[f][db]);
        }
      }
    __builtin_amdgcn_s_setprio(0);
  }

#pragma unroll
  for (int f=0; f<2; ++f) {
    const float inv = 1.f / lrun[f];
    float ir[4];
#pragma unroll
    for (int r=0;r<4;r++) ir[r] = __shfl(inv, g*4 + r);
#pragma unroll
    for (int db=0; db<4; ++db)
#pragma unroll
      for (int r=0;r<4;r++)
        O[(size_t)(b*T_ + q0 + f*16 + g*4 + r)*D_ + hd*64 + db*16 + l15] = (__bf16)(o[f][db][r]*ir[r]);
  }
}

// ---------------- batched weight prep: 64x64 tiles ----------------
__global__ __launch_bounds__(256) void wprep_k(const float* __restrict__ q, const float* __restrict__ k,
                                               const float* __restrict__ v, const float* __restrict__ o,
                                               const float* __restrict__ cq, const float* __restrict__ ck,
                                               const float* __restrict__ cv, const float* __restrict__ co,
                                               const float* __restrict__ f1, const float* __restrict__ f2,
                                               __bf16* __restrict__ wb) {
  __shared__ float tile[64][65];
  const int id = blockIdx.x;
  const float* src; __bf16* dst; int R, C, bx, by;
  if (id < 2048) {
    const int m = id >> 8, t = id & 255; bx = t & 15; by = t >> 4;
    const float* srcs[8] = {q,k,v,o,cq,ck,cv,co};
    src = srcs[m]; dst = wb + (size_t)m*1048576; R = 1024; C = 1024;
  } else if (id < 3072) {
    const int t = id - 2048; bx = t & 63; by = t >> 6;
    src = f1; dst = wb + (size_t)8*1048576; R = 1024; C = 4096;
  } else {
    const int t = id - 3072; bx = t & 15; by = t >> 4;
    src = f2; dst = wb + (size_t)12*1048576; R = 4096; C = 1024;
  }
  const int tx = threadIdx.x & 63, ty = threadIdx.x >> 6;
  const int r0 = by*64, c0 = bx*64;
#pragma unroll
  for (int i=0;i<16;i++) tile[ty+i*4][tx] = src[(size_t)(r0+ty+i*4)*C + c0+tx];
  __syncthreads();
#pragma unroll
  for (int i=0;i<16;i++) dst[(size_t)(c0+ty+i*4)*R + r0+tx] = (__bf16)tile[tx][ty+i*4];
}

// ---------------- LayerNorm: zb = LN(ysum)*g+b  (ysum f32 already includes residual) ----------------
__global__ __launch_bounds__(256) void ln_k(const float* __restrict__ ysum,
                                            const float* __restrict__ gam, const float* __restrict__ bet,
                                            __bf16* __restrict__ zbout) {
  const int row = blockIdx.x, tid = threadIdx.x;
  const f32x4 v = ((const f32x4*)(ysum + (size_t)row*D_))[tid];
  float s1 = v[0]+v[1]+v[2]+v[3];
  float s2 = v[0]*v[0]+v[1]*v[1]+v[2]*v[2]+v[3]*v[3];
#pragma unroll
  for (int off=32; off; off>>=1) { s1 += __shfl_xor(s1,off); s2 += __shfl_xor(s2,off); }
  __shared__ float red[8];
  const int wv = tid>>6, ln = tid&63;
  if (ln==0) { red[wv] = s1; red[4+wv] = s2; }
  __syncthreads();
  s1 = red[0]+red[1]+red[2]+red[3];
  s2 = red[4]+red[5]+red[6]+red[7];
  const float mean = s1 * (1.f/1024.f);
  const float var = s2 * (1.f/1024.f) - mean*mean;
  const float rs = rsqrtf(var + 1e-5f);
  const f32x4 gv = ((const f32x4*)gam)[tid];
  const f32x4 bv = ((const f32x4*)bet)[tid];
  bf16x4 rb;
#pragma unroll
  for (int j=0;j<4;j++) rb[j] = (__bf16)((v[j]-mean)*rs*gv[j] + bv[j]);
  ((bf16x4*)(zbout + (size_t)row*D_))[tid] = rb;
}

// ---------------- cond MLP branch hiddens ----------------
__global__ __launch_bounds__(256) void cond1_k(const int* __restrict__ t, const float* __restrict__ target,
                                               const float* __restrict__ action,
                                               const float* __restrict__ t_w1, const float* __restrict__ t_b1,
                                               const float* __restrict__ tg_w1, const float* __restrict__ tg_b1,
                                               const float* __restrict__ ac_w1, const float* __restrict__ ac_b1,
                                               float* __restrict__ h3) {
  const int i = blockIdx.x*256 + threadIdx.x;
  const int b = i >> 10, d = i & 1023;
  float u = (float)t[b] * t_w1[d] + t_b1[d];
  h3[i] = u / (1.f + __expf(-u));
  u = tg_b1[d];
#pragma unroll
  for (int j=0;j<3;j++) u += target[b*3+j]*tg_w1[j*1024+d];
  h3[8192 + i] = u / (1.f + __expf(-u));
  u = ac_b1[d];
#pragma unroll
  for (int j=0;j<5;j++) u += action[b*5+j]*ac_w1[j*1024+d];
  h3[16384 + i] = u / (1.f + __expf(-u));
}

__global__ __launch_bounds__(256) void cond2_k(const float* __restrict__ h3,
                                               const float* __restrict__ t_w2, const float* __restrict__ tg_w2,
                                               const float* __restrict__ ac_w2, float* __restrict__ cpart) {
  const int i = blockIdx.x*256 + threadIdx.x;
  const int ks = blockIdx.y;
  const int b = i >> 10, d = i & 1023;
  const float* ht = h3 + b*1024;
  const float* hg = h3 + 8192 + b*1024;
  const float* ha = h3 + 16384 + b*1024;
  float a = 0.f;
  for (int k = ks*128; k < ks*128+128; ++k)
    a += ht[k]*t_w2[(size_t)k*1024+d] + hg[k]*tg_w2[(size_t)k*1024+d] + ha[k]*ac_w2[(size_t)k*1024+d];
  cpart[ks*8192 + i] = a;
}

// ---------------- embedding: writes zb + memb (bf16 stream) ----------------
__global__ __launch_bounds__(256) void embed_k(const float* __restrict__ x, const float* __restrict__ hist,
                                               const float* __restrict__ in_w, const float* __restrict__ in_b,
                                               const float* __restrict__ cpart,
                                               const float* __restrict__ t_b2, const float* __restrict__ tg_b2,
                                               const float* __restrict__ ac_b2,
                                               __bf16* __restrict__ zb, __bf16* __restrict__ memb) {
  const int row = blockIdx.x, tid = threadIdx.x;
  const int b = row / T_, tt = row - b*T_;
  const float* feat = (tt < HIST_) ? (hist + ((size_t)b*HIST_ + tt)*10) : (x + ((size_t)b*S_ + (tt-HIST_))*10);
  float f[10];
#pragma unroll
  for (int s=0;s<10;s++) f[s] = feat[s];
  const float te = (float)((tt < HIST_) ? tt : tt - HIST_);
  f32x4 a = ((const f32x4*)in_b)[tid];
#pragma unroll
  for (int u=0;u<2;u++) {
    const int d = tid*4 + 2*u;
    const float freq = __expf((float)d * (-9.210340371976184f/1024.f));
    float sn, cs;
    __sincosf(te*freq, &sn, &cs);
    a[2*u] += sn; a[2*u+1] += cs;
  }
  a += ((const f32x4*)t_b2)[tid];
  a += ((const f32x4*)tg_b2)[tid];
  a += ((const f32x4*)ac_b2)[tid];
  const int cb = b*256 + tid;
#pragma unroll
  for (int ks=0;ks<8;ks++) a += ((const f32x4*)cpart)[ks*2048 + cb];
#pragma unroll
  for (int s=0;s<10;s++) {
    const f32x4 wv = ((const f32x4*)(in_w + s*1024))[tid];
    a += wv * f[s];
  }
  bf16x4 ab;
#pragma unroll
  for (int j=0;j<4;j++) ab[j] = (__bf16)a[j];
  ((bf16x4*)(zb + (size_t)row*D_))[tid] = ab;
  ((bf16x4*)(memb + (size_t)row*D_))[tid] = ab;
}

// ---------------- output projection (reads bf16 stream) ----------------
__global__ __launch_bounds__(256) void outp_k(const __bf16* __restrict__ z, const float* __restrict__ w,
                                              const float* __restrict__ bo, float* __restrict__ out) {
  const int wv = threadIdx.x>>6, ln = threadIdx.x&63;
  const int row = blockIdx.x*4 + wv;
  const int b = row >> 10, s = row & 1023;
  const __bf16* zr = z + ((size_t)b*T_ + HIST_ + s)*D_;
  float acc[10];
#pragma unroll
  for (int o=0;o<10;o++) acc[o]=0.f;
  for (int k=ln; k<1024; k+=64) {
    const float zv = (float)zr[k];
    const float* wr = w + k*10;
#pragma unroll
    for (int o=0;o<10;o++) acc[o] += zv*wr[o];
  }
#pragma unroll
  for (int o=0;o<10;o++) {
#pragma unroll
    for (int off=32; off; off>>=1) acc[o] += __shfl_xor(acc[o], off);
  }
  if (ln==0) {
#pragma unroll
    for (int o=0;o<10;o++) out[(size_t)row*10+o] = acc[o] + bo[o];
  }
}

extern "C" void kernel_launch(void* const* d_in, const int* in_sizes, int n_in,
                              void* d_out, int out_size, void* d_ws, size_t ws_size,
                              hipStream_t stream) {
  const float* x      = (const float*)d_in[0];
  const int*   t      = (const int*)  d_in[1];
  const float* target = (const float*)d_in[2];
  const float* action = (const float*)d_in[3];
  const float* hist   = (const float*)d_in[4];
  const float* in_w   = (const float*)d_in[5];
  const float* in_b   = (const float*)d_in[6];
  const float* t_w1   = (const float*)d_in[7];
  const float* t_b1   = (const float*)d_in[8];
  const float* t_w2   = (const float*)d_in[9];
  const float* t_b2   = (const float*)d_in[10];
  const float* tg_w1  = (const float*)d_in[11];
  const float* tg_b1  = (const float*)d_in[12];
  const float* tg_w2  = (const float*)d_in[13];
  const float* tg_b2  = (const float*)d_in[14];
  const float* ac_w1  = (const float*)d_in[15];
  const float* ac_b1  = (const float*)d_in[16];
  const float* ac_w2  = (const float*)d_in[17];
  const float* ac_b2  = (const float*)d_in[18];
  const float* sa_wq  = (const float*)d_in[19];
  const float* sa_bq  = (const float*)d_in[20];
  const float* sa_wk  = (const float*)d_in[21];
  const float* sa_bk  = (const float*)d_in[22];
  const float* sa_wv  = (const float*)d_in[23];
  const float* sa_bv  = (const float*)d_in[24];
  const float* sa_wo  = (const float*)d_in[25];
  const float* sa_bo  = (const float*)d_in[26];
  const float* ca_wq  = (const float*)d_in[27];
  const float* ca_bq  = (const float*)d_in[28];
  const float* ca_wk  = (const float*)d_in[29];
  const float* ca_bk  = (const float*)d_in[30];
  const float* ca_wv  = (const float*)d_in[31];
  const float* ca_bv  = (const float*)d_in[32];
  const float* ca_wo  = (const float*)d_in[33];
  const float* ca_bo  = (const float*)d_in[34];
  const float* ln1_g  = (const float*)d_in[35];
  const float* ln1_b  = (const float*)d_in[36];
  const float* ln2_g  = (const float*)d_in[37];
  const float* ln2_b  = (const float*)d_in[38];
  const float* ln3_g  = (const float*)d_in[39];
  const float* ln3_b  = (const float*)d_in[40];
  const float* ff_w1  = (const float*)d_in[41];
  const float* ff_b1  = (const float*)d_in[42];
  const float* ff_w2  = (const float*)d_in[43];
  const float* ff_b2  = (const float*)d_in[44];
  const float* out_w  = (const float*)d_in[45];
  const float* out_b  = (const float*)d_in[46];

  if (ws_size < (size_t)224*1024*1024) return;

  char* p = (char*)d_ws;
  auto take = [&](size_t bytes) { char* r = p; p += (bytes + 255) & ~(size_t)255; return r; };
  __bf16* wbuf = (__bf16*)take((size_t)16*1024*1024*2);
  __bf16* zb   = (__bf16*)take((size_t)NROWS_*D_*2);
  __bf16* memb = (__bf16*)take((size_t)NROWS_*D_*2);
  __bf16* qk   = (__bf16*)take((size_t)NROWS_*2048*2);
  __bf16* vt   = (__bf16*)take((size_t)1024*NROWS_*2);
  __bf16* ob   = (__bf16*)take((size_t)NROWS_*D_*2);
  float*  ysum = (float*) take((size_t)NROWS_*D_*4);
  float*  h3   = (float*) take((size_t)3*8192*4);
  float*  cpart= (float*) take((size_t)8*8192*4);
  __bf16* ffh  = qk;   // FFN hidden aliases qk+vt+ob (75.5 MB)

  const dim3 blk(256);
  const dim3 blk5(512);
  const int BIG = 1<<30;
  cond1_k<<<32, blk, 0, stream>>>(t, target, action, t_w1, t_b1, tg_w1, tg_b1, ac_w1, ac_b1, h3);
  cond2_k<<<dim3(32,8), blk, 0, stream>>>(h3, t_w2, tg_w2, ac_w2, cpart);
  embed_k<<<NROWS_, blk, 0, stream>>>(x, hist, in_w, in_b, cpart, t_b2, tg_b2, ac_b2, zb, memb);

  const int M = NROWS_;
  for (int li=0; li<L_; ++li) {
    const size_t w0 = (size_t)li*D_*D_, b0 = (size_t)li*D_;
    const size_t f1 = (size_t)li*D_*FF_, fb1 = (size_t)li*FF_;
    wprep_k<<<4096, blk, 0, stream>>>(sa_wq+w0, sa_wk+w0, sa_wv+w0, sa_wo+w0,
                                      ca_wq+w0, ca_wk+w0, ca_wv+w0, ca_wo+w0,
                                      ff_w1+f1, ff_w2+f1, wbuf);
    // self-attention: fused QKV (N=3072), 256^2 kernel
    gemm256_k<3,0><<<36*12, blk5, 0, stream>>>(zb, zb, BIG, wbuf+0*1048576,
                                               sa_bq+b0, sa_bk+b0, sa_bv+b0, 1024, 2048,
                                               qk, vt, M, 3072, 1024, 2048, 2048);
    attn_k<<<1152, blk, 0, stream>>>(qk, vt, ob);
    // o-proj + residual(zb) -> ysum (f32)
    gemm192_k<0,0,1><<<48*4, blk5, 0, stream>>>(ob, wbuf+3*1048576, sa_bo+b0, ysum, zb,
                                                M, 1024, 1024, 1024);
    ln_k<<<NROWS_, blk, 0, stream>>>(ysum, ln1_g+b0, ln1_b+b0, zb);
    // cross-attention: fused Q|KV (N=3072); Q cols read zb, K/V cols read memb
    gemm256_k<3,0><<<36*12, blk5, 0, stream>>>(zb, memb, 1024, wbuf+4*1048576,
                                               ca_bq+b0, ca_bk+b0, ca_bv+b0, 1024, 2048,
                                               qk, vt, M, 3072, 1024, 2048, 2048);
    attn_k<<<1152, blk, 0, stream>>>(qk, vt, ob);
    gemm192_k<0,0,1><<<48*4, blk5, 0, stream>>>(ob, wbuf+7*1048576, ca_bo+b0, ysum, zb,
                                                M, 1024, 1024, 1024);
    ln_k<<<NROWS_, blk, 0, stream>>>(ysum, ln2_g+b0, ln2_b+b0, zb);
    // FFN
    gemm192_k<1,1,0><<<48*16, blk5, 0, stream>>>(zb, wbuf+(size_t)8*1048576, ff_b1+fb1, ffh, nullptr,
                                                 M, 4096, 1024, 4096);
    gemm192_k<0,0,1><<<48*4, blk5, 0, stream>>>(ffh, wbuf+(size_t)12*1048576, ff_b2+b0, ysum, zb,
                                                M, 1024, 4096, 1024);
    ln_k<<<NROWS_, blk, 0, stream>>>(ysum, ln3_g+b0, ln3_b+b0, zb);
  }
  outp_k<<<2048, blk, 0, stream>>>(zb, out_w, out_b, (float*)d_out);
}

// Round 12
// 3872.443 us; speedup vs baseline: 1.0748x; 1.0085x over previous
//
#include <hip/hip_runtime.h>
#include <hip/hip_bf16.h>
#include <stdint.h>

#define B_    8
#define S_    1024
#define HIST_ 128
#define T_    1152
#define D_    1024
#define NH_   16
#define DH_   64
#define FF_   4096
#define L_    6
#define NROWS_ (B_*T_)   /* 9216 */

typedef __attribute__((ext_vector_type(8))) __bf16 bf16x8;
typedef __attribute__((ext_vector_type(4))) __bf16 bf16x4;
typedef __attribute__((ext_vector_type(4))) float  f32x4;

static __device__ __forceinline__ f32x4 mfma16(bf16x8 a, bf16x8 b, f32x4 c) {
  return __builtin_amdgcn_mfma_f32_16x16x32_bf16(a, b, c, 0, 0, 0);
}
static __device__ __forceinline__ void gload16(const __bf16* g, __bf16* l) {
  __builtin_amdgcn_global_load_lds((const __attribute__((address_space(1))) void*)g,
                                   (__attribute__((address_space(3))) void*)l, 16, 0, 0);
}
static __device__ __forceinline__ void gload16b(const char* g, char* l) {
  __builtin_amdgcn_global_load_lds((const __attribute__((address_space(1))) void*)g,
                                   (__attribute__((address_space(3))) void*)l, 16, 0, 0);
}
// bijective XCD swizzle (m204)
static __device__ __forceinline__ int xcd_swz(int orig, int nwg) {
  const int q = nwg >> 3, r = nwg & 7;
  const int x = orig & 7, i = orig >> 3;
  return (x < r ? x*(q+1) : r*(q+1) + (x-r)*q) + i;
}

// ---------------- 192x256 GEMM, BK=64, 8 waves (2Mx4N), counted-vmcnt pipeline ----------------
// (o-proj / FFN1 / FFN2) — RESADD fuses the residual add: out = acc + bias + resid (f32)
// R12: sched_barrier(0) removed (reads are compiler-emitted; rule-18 inapplicable);
//      stage split 4+3 around the ks1 MFMA block (ledger unchanged: vmcnt(7) gate).
template<int BF16OUT, int RELU, int RESADD>
__global__ __launch_bounds__(512, 2) void gemm192_k(const __bf16* __restrict__ A,
                                                    const __bf16* __restrict__ Bt,
                                                    const float* __restrict__ bias,
                                                    void* __restrict__ Cout,
                                                    const __bf16* __restrict__ resid,
                                                    int M, int N, int K, int ldc) {
  __shared__ __align__(16) char Lds[2][57344];
  const int tid = threadIdx.x;
  const int wid = tid >> 6, ln = tid & 63;
  const int wm = wid >> 2, wn = wid & 3;
  const int l15 = ln & 15, g = ln >> 4;
  const int nbx = N >> 8;
  const int wg = xcd_swz(blockIdx.x, gridDim.x);
  const int m0 = (wg / nbx) * 192, n0 = (wg % nbx) << 8;
  const size_t rstep = (size_t)K * 2;

  const char* srcp[7];
  int dsto[7];
#pragma unroll
  for (int p = 0; p < 7; ++p) {
    const int off = p*8192 + tid*16;
    int mat, ks, row;
    if (off < 12288)      { mat = 0; ks = 0; row = off >> 6; }
    else if (off < 24576) { mat = 0; ks = 1; row = (off - 12288) >> 6; }
    else if (off < 40960) { mat = 1; ks = 0; row = (off - 24576) >> 6; }
    else                  { mat = 1; ks = 1; row = (off - 40960) >> 6; }
    const int ch = (off >> 4) & 3;
    const int kb = ks*64 + ((ch ^ ((row >> 1) & 3)) << 4);
    srcp[p] = (mat ? (const char*)Bt + (size_t)(n0 + row)*rstep
                   : (const char*)A  + (size_t)(m0 + row)*rstep) + kb;
    dsto[p] = off;
  }
  auto stage_range = [&](int buf, int t, int p0, int p1) {
    char* lb = &Lds[buf][0];
    const size_t tb = (size_t)t << 7;
#pragma unroll
    for (int p = p0; p < p1; ++p) gload16b(srcp[p] + tb, lb + dsto[p]);
  };

  const int xr = (g ^ ((l15 >> 1) & 3)) << 4;
  const int arow = l15*64 + xr;
  const int aoffm = (wm*96) * 64;
  const int boff  = 24576 + (wn*64) * 64;

  const f32x4 zero = {0.f,0.f,0.f,0.f};
  f32x4 acc[6][4];
#pragma unroll
  for (int i=0;i<6;i++)
#pragma unroll
    for (int j=0;j<4;j++) acc[i][j] = zero;

  stage_range(0, 0, 0, 7); stage_range(1, 1, 0, 7);

  const int NT = K >> 6;
  for (int t = 0; t < NT; ++t) {
    const int buf = t & 1;
    if (t == NT-1) { asm volatile("s_waitcnt vmcnt(0)" ::: "memory"); }
    else           { asm volatile("s_waitcnt vmcnt(7)" ::: "memory"); }
    __builtin_amdgcn_s_barrier();
    const char* bufp = &Lds[buf][0];
    bf16x8 a0[6], a1[6], b0[4], b1[4];
#pragma unroll
    for (int mi=0;mi<6;mi++) a0[mi] = *(const bf16x8*)(bufp + aoffm + mi*1024 + arow);
#pragma unroll
    for (int ni=0;ni<4;ni++) b0[ni] = *(const bf16x8*)(bufp + boff + ni*1024 + arow);
#pragma unroll
    for (int mi=0;mi<6;mi++) a1[mi] = *(const bf16x8*)(bufp + 12288 + aoffm + mi*1024 + arow);
    __builtin_amdgcn_s_setprio(1);
#pragma unroll
    for (int mi=0;mi<6;mi++)
#pragma unroll
      for (int ni=0;ni<4;ni++) acc[mi][ni] = mfma16(a0[mi], b0[ni], acc[mi][ni]);
    __builtin_amdgcn_s_setprio(0);
#pragma unroll
    for (int ni=0;ni<4;ni++) b1[ni] = *(const bf16x8*)(bufp + boff + 16384 + ni*1024 + arow);
    asm volatile("s_waitcnt lgkmcnt(0)" ::: "memory");
    __builtin_amdgcn_s_barrier();           // all waves done reading buf
    const bool st = (t + 2 <= NT - 1);
    if (st) stage_range(buf, t + 2, 0, 4);  // first 4 staging passes
    __builtin_amdgcn_s_setprio(1);
#pragma unroll
    for (int mi=0;mi<6;mi++)
#pragma unroll
      for (int ni=0;ni<4;ni++) acc[mi][ni] = mfma16(a1[mi], b1[ni], acc[mi][ni]);
    __builtin_amdgcn_s_setprio(0);
    if (st) stage_range(buf, t + 2, 4, 7);  // remaining 3 passes
  }

  const int colb = n0 + wn*64 + l15;
#pragma unroll
  for (int mi=0;mi<6;mi++) {
    const int row = m0 + wm*96 + mi*16 + g*4;
#pragma unroll
    for (int ni=0;ni<4;ni++) {
      const int col = colb + ni*16;
      const float bv = bias[col];
#pragma unroll
      for (int j=0;j<4;j++) {
        float v = acc[mi][ni][j] + bv;
        if (RESADD) v += (float)resid[(size_t)(row+j)*ldc + col];
        if (RELU) v = fmaxf(v, 0.f);
        if (BF16OUT) ((__bf16*)Cout)[(size_t)(row+j)*ldc + col] = (__bf16)v;
        else         ((float*)Cout)[(size_t)(row+j)*ldc + col] = v;
      }
    }
  }
}

// ---------------- 256x256 GEMM (QKV shapes) — R8-proven ----------------
template<int OUTMODE, int RELU>
__global__ __launch_bounds__(512, 2) void gemm256_k(const __bf16* __restrict__ A,
                                                    const __bf16* __restrict__ A2, int asplit,
                                                    const __bf16* __restrict__ Bt,
                                                    const float* __restrict__ b1,
                                                    const float* __restrict__ b2,
                                                    const float* __restrict__ b3, int s1, int s2,
                                                    void* __restrict__ CoutRM,
                                                    __bf16* __restrict__ CoutT,
                                                    int M, int N, int K, int ldc, int tsplit) {
  __shared__ __align__(16) __bf16 Lds[2][2][2][8192];
  const int tid = threadIdx.x;
  const int wid = tid >> 6, ln = tid & 63;
  const int wm = wid >> 2, wn = wid & 3;
  const int l15 = ln & 15, g = ln >> 4;
  const int nbx = N >> 8;
  const int wg = xcd_swz(blockIdx.x, gridDim.x);
  const int m0 = (wg / nbx) << 8, n0 = (wg % nbx) << 8;
  const size_t rstep = (size_t)K * 2;
  const __bf16* Aeff = (n0 < asplit) ? A : A2;

  const int srow = tid >> 2, schunk = tid & 3;
  const int sx = (schunk ^ ((srow >> 1) & 3)) << 4;
  const char* gAr = (const char*)Aeff + (size_t)(m0 + srow)*rstep + sx;
  const char* gBr = (const char*)Bt   + (size_t)(n0 + srow)*rstep + sx;
  const size_t hstep = (size_t)128 * rstep;

  const int xr = (g ^ ((l15 >> 1) & 3)) << 4;
  const int arow = l15 * 64 + xr;
  const int aoffm = (wm*128) * 64;
  const int boff  = (wn*64) * 64;

  const f32x4 zero = {0.f,0.f,0.f,0.f};
  f32x4 acc[8][4];
#pragma unroll
  for (int i=0;i<8;i++)
#pragma unroll
    for (int j=0;j<4;j++) acc[i][j] = zero;

  auto stage4 = [&](int buf, int ks, int tile) {
    const size_t off = (size_t)tile*128 + (size_t)ks*64;
    char* la = (char*)&Lds[buf][ks][0][0];
    char* lb = (char*)&Lds[buf][ks][1][0];
    gload16b(gAr + off,         la + tid*16);
    gload16b(gAr + off + hstep, la + 8192 + tid*16);
    gload16b(gBr + off,         lb + tid*16);
    gload16b(gBr + off + hstep, lb + 8192 + tid*16);
  };

  auto ktile = [&](int buf, bool st, int stile, bool gate0) {
    if (gate0) { asm volatile("s_waitcnt vmcnt(0)" ::: "memory"); }
    else       { asm volatile("s_waitcnt vmcnt(8)" ::: "memory"); }
    __builtin_amdgcn_s_barrier();
    const char* As0 = (const char*)&Lds[buf][0][0][0];
    const char* Bs0 = (const char*)&Lds[buf][0][1][0];
    const char* As1 = (const char*)&Lds[buf][1][0][0];
    const char* Bs1 = (const char*)&Lds[buf][1][1][0];
    bf16x8 a0[4], a1[4], b0[4], a2[4], b1v[4], a3[4];
#pragma unroll
    for (int mi=0;mi<4;mi++) a0[mi] = *(const bf16x8*)(As0 + aoffm + mi*1024 + arow);
#pragma unroll
    for (int ni=0;ni<4;ni++) b0[ni] = *(const bf16x8*)(Bs0 + boff + ni*1024 + arow);
#pragma unroll
    for (int mi=0;mi<4;mi++) a1[mi] = *(const bf16x8*)(As0 + aoffm + 4096 + mi*1024 + arow);
    __builtin_amdgcn_s_setprio(1);
#pragma unroll
    for (int mi=0;mi<4;mi++)
#pragma unroll
      for (int ni=0;ni<4;ni++) acc[mi][ni] = mfma16(a0[mi], b0[ni], acc[mi][ni]);
    __builtin_amdgcn_s_setprio(0);
#pragma unroll
    for (int mi=0;mi<4;mi++) a2[mi]  = *(const bf16x8*)(As1 + aoffm + mi*1024 + arow);
#pragma unroll
    for (int ni=0;ni<4;ni++) b1v[ni] = *(const bf16x8*)(Bs1 + boff + ni*1024 + arow);
    asm volatile("s_waitcnt lgkmcnt(0)" ::: "memory");
    __builtin_amdgcn_s_barrier();
    if (st) stage4(buf, 0, stile);
    __builtin_amdgcn_s_setprio(1);
#pragma unroll
    for (int mi=0;mi<4;mi++)
#pragma unroll
      for (int ni=0;ni<4;ni++) acc[4+mi][ni] = mfma16(a1[mi], b0[ni], acc[4+mi][ni]);
    __builtin_amdgcn_s_setprio(0);
#pragma unroll
    for (int mi=0;mi<4;mi++) a3[mi] = *(const bf16x8*)(As1 + aoffm + 4096 + mi*1024 + arow);
    __builtin_amdgcn_s_setprio(1);
#pragma unroll
    for (int mi=0;mi<4;mi++)
#pragma unroll
      for (int ni=0;ni<4;ni++) acc[mi][ni] = mfma16(a2[mi], b1v[ni], acc[mi][ni]);
    __builtin_amdgcn_s_setprio(0);
    asm volatile("s_waitcnt lgkmcnt(0)" ::: "memory");
    __builtin_amdgcn_s_barrier();
    if (st) stage4(buf, 1, stile);
    __builtin_amdgcn_s_setprio(1);
#pragma unroll
    for (int mi=0;mi<4;mi++)
#pragma unroll
      for (int ni=0;ni<4;ni++) acc[4+mi][ni] = mfma16(a3[mi], b1v[ni], acc[4+mi][ni]);
    __builtin_amdgcn_s_setprio(0);
  };

  stage4(0, 0, 0); stage4(0, 1, 0);
  stage4(1, 0, 1); stage4(1, 1, 1);

  const int NT = K >> 6, NI = NT >> 1;
  for (int i = 0; i < NI; ++i) {
    const bool st = (i + 1 < NI);
    ktile(0, st, 2*i + 2, false);
    ktile(1, st, 2*i + 3, i == NI - 1);
  }

  const int colb = n0 + wn*64 + l15;
#pragma unroll
  for (int mi=0;mi<8;mi++) {
    const int row = m0 + wm*128 + mi*16 + g*4;
#pragma unroll
    for (int ni=0;ni<4;ni++) {
      const int col = colb + ni*16;
      const float bv = (col < s1) ? b1[col] : ((col < s2) ? b2[col-s1] : b3[col-s2]);
      if (OUTMODE == 3 && col >= tsplit) {
        bf16x4 ct;
#pragma unroll
        for (int j=0;j<4;j++) {
          float v = acc[mi][ni][j] + bv;
          if (RELU) v = fmaxf(v, 0.f);
          ct[j] = (__bf16)v;
        }
        *(bf16x4*)(CoutT + (size_t)(col - tsplit)*M + row) = ct;
      } else {
#pragma unroll
        for (int j=0;j<4;j++) {
          float v = acc[mi][ni][j] + bv;
          if (RELU) v = fmaxf(v, 0.f);
          if (OUTMODE == 0) ((float*)CoutRM)[(size_t)(row+j)*ldc + col] = v;
          else              ((__bf16*)CoutRM)[(size_t)(row+j)*ldc + col] = (__bf16)v;
        }
      }
    }
  }
}

// ---------------- Flash attention, causal, NH=16 DH=64, T13 defer-max (unchanged) ----------------
__global__ __launch_bounds__(256) void attn_k(const __bf16* __restrict__ QK,
                                              const __bf16* __restrict__ Vt,
                                              __bf16* __restrict__ O) {
  __shared__ __align__(16) __bf16 Ks[2][4096];
  __shared__ __align__(16) __bf16 Vs[2][4096];
  __shared__ __align__(16) __bf16 Pl[4][32*72];
  const int tid = threadIdx.x;
  const int wv = tid >> 6, ln = tid & 63;
  const int l15 = ln & 15, g = ln >> 4;
  const int wg = xcd_swz(blockIdx.x, 1152);
  const int qb = 8 - (wg % 9);
  const int hd = (wg / 9) & 15;
  const int b  = wg / 144;
  const int q0 = qb*128 + wv*32;

  bf16x8 qf[2][2];
#pragma unroll
  for (int f=0; f<2; ++f)
#pragma unroll
    for (int h=0; h<2; ++h)
      qf[f][h] = *(const bf16x8*)(QK + (size_t)(b*T_ + q0 + f*16 + l15)*2048 + hd*64 + h*32 + g*8);

  const int sr = tid >> 3;
  const int si = tid & 7;
  const int cb0 = (si*16) ^ ((sr & 7) << 4);
  const char* kg = (const char*)(QK + (size_t)b*T_*2048 + 1024 + hd*64);
  const char* vg = (const char*)(Vt + (size_t)hd*64*NROWS_ + (size_t)b*T_);

  const f32x4 zero = {0.f,0.f,0.f,0.f};
  f32x4 o[2][4];
#pragma unroll
  for (int f=0; f<2; ++f)
#pragma unroll
    for (int d=0; d<4; ++d) o[f][d] = zero;
  float mrun[2] = {-3.0e38f, -3.0e38f};
  float lrun[2] = {0.f, 0.f};
  const int nt = 2*qb + 2;

  {
    const int c = 0, kt = 0;
#pragma unroll
    for (int hr=0; hr<2; ++hr) {
      const int r = sr + hr*32;
      gload16((const __bf16*)(kg + (size_t)(kt + r)*4096 + cb0), &Ks[c][0] + hr*2048 + wv*512);
      gload16((const __bf16*)(vg + (size_t)r*(NROWS_*2) + (size_t)kt*2 + cb0), &Vs[c][0] + hr*2048 + wv*512);
    }
  }

  for (int t = 0; t < nt; ++t) {
    __syncthreads();
    if (t+1 < nt) {
      const int c = (t+1)&1, kt2 = (t+1)*64;
#pragma unroll
      for (int hr=0; hr<2; ++hr) {
        const int r = sr + hr*32;
        gload16((const __bf16*)(kg + (size_t)(kt2 + r)*4096 + cb0), &Ks[c][0] + hr*2048 + wv*512);
        gload16((const __bf16*)(vg + (size_t)r*(NROWS_*2) + (size_t)kt2*2 + cb0), &Vs[c][0] + hr*2048 + wv*512);
      }
    }
    const int kt = t*64;
    if (kt > q0 + 31) continue;
    const char* ks = (const char*)&Ks[t&1][0];
    const char* vs = (const char*)&Vs[t&1][0];

#pragma unroll
    for (int f=0; f<2; ++f) {
      const int qrow = q0 + f*16 + l15;
      f32x4 st[4];
      __builtin_amdgcn_s_setprio(1);
#pragma unroll
      for (int kf=0; kf<4; ++kf) {
        const int row = kf*16 + l15;
        const int swz = (row & 7) << 4;
        const bf16x8 k0 = *(const bf16x8*)(ks + row*128 + ((g*16) ^ swz));
        const bf16x8 k1 = *(const bf16x8*)(ks + row*128 + ((64 + g*16) ^ swz));
        st[kf] = mfma16(k1, qf[f][1], mfma16(k0, qf[f][0], zero));
      }
      __builtin_amdgcn_s_setprio(0);
      float p[16];
#pragma unroll
      for (int kf=0; kf<4; ++kf)
#pragma unroll
        for (int r=0; r<4; ++r) {
          const int kgl = kt + kf*16 + g*4 + r;
          p[kf*4+r] = (kgl <= qrow) ? st[kf][r]*0.125f : -3.0e38f;
        }
      float mloc = p[0];
#pragma unroll
      for (int i=1;i<16;i++) mloc = fmaxf(mloc, p[i]);
      mloc = fmaxf(mloc, __shfl_xor(mloc, 16));
      mloc = fmaxf(mloc, __shfl_xor(mloc, 32));
      if (__all(mloc - mrun[f] <= 8.f)) {
        float ls = 0.f;
#pragma unroll
        for (int i=0;i<16;i++) { p[i] = __expf(p[i] - mrun[f]); ls += p[i]; }
        ls += __shfl_xor(ls, 16); ls += __shfl_xor(ls, 32);
        lrun[f] += ls;
      } else {
        const float mnew = fmaxf(mrun[f], mloc);
        const float corr = __expf(mrun[f] - mnew);
        float ls = 0.f;
#pragma unroll
        for (int i=0;i<16;i++) { p[i] = __expf(p[i] - mnew); ls += p[i]; }
        ls += __shfl_xor(ls, 16); ls += __shfl_xor(ls, 32);
        lrun[f] = lrun[f]*corr + ls;
        mrun[f] = mnew;
        float cr[4];
#pragma unroll
        for (int r=0;r<4;r++) cr[r] = __shfl(corr, g*4 + r);
#pragma unroll
        for (int db=0; db<4; ++db)
#pragma unroll
          for (int r=0;r<4;r++) o[f][db][r] *= cr[r];
      }
#pragma unroll
      for (int kf=0; kf<4; ++kf) {
        bf16x4 pw;
#pragma unroll
        for (int r=0;r<4;r++) pw[r] = (__bf16)p[kf*4+r];
        *(bf16x4*)(&Pl[wv][(f*16 + l15)*72 + kf*16 + g*4]) = pw;
      }
    }
    __builtin_amdgcn_s_setprio(1);
#pragma unroll
    for (int f=0; f<2; ++f)
#pragma unroll
      for (int ks2=0; ks2<2; ++ks2) {
        const bf16x8 pa = *(const bf16x8*)(&Pl[wv][(f*16 + l15)*72 + ks2*32 + g*8]);
#pragma unroll
        for (int db=0; db<4; ++db) {
          const int d = db*16 + l15;
          const bf16x8 vf = *(const bf16x8*)(vs + d*128 + ((ks2*64 + g*16) ^ ((d & 7) << 4)));
          o[f][db] = mfma16(pa, vf, o[f][db]);
        }
      }
    __builtin_amdgcn_s_setprio(0);
  }

#pragma unroll
  for (int f=0; f<2; ++f) {
    const float inv = 1.f / lrun[f];
    float ir[4];
#pragma unroll
    for (int r=0;r<4;r++) ir[r] = __shfl(inv, g*4 + r);
#pragma unroll
    for (int db=0; db<4; ++db)
#pragma unroll
      for (int r=0;r<4;r++)
        O[(size_t)(b*T_ + q0 + f*16 + g*4 + r)*D_ + hd*64 + db*16 + l15] = (__bf16)(o[f][db][r]*ir[r]);
  }
}

// ---------------- batched weight prep: 64x64 tiles ----------------
__global__ __launch_bounds__(256) void wprep_k(const float* __restrict__ q, const float* __restrict__ k,
                                               const float* __restrict__ v, const float* __restrict__ o,
                                               const float* __restrict__ cq, const float* __restrict__ ck,
                                               const float* __restrict__ cv, const float* __restrict__ co,
                                               const float* __restrict__ f1, const float* __restrict__ f2,
                                               __bf16* __restrict__ wb) {
  __shared__ float tile[64][65];
  const int id = blockIdx.x;
  const float* src; __bf16* dst; int R, C, bx, by;
  if (id < 2048) {
    const int m = id >> 8, t = id & 255; bx = t & 15; by = t >> 4;
    const float* srcs[8] = {q,k,v,o,cq,ck,cv,co};
    src = srcs[m]; dst = wb + (size_t)m*1048576; R = 1024; C = 1024;
  } else if (id < 3072) {
    const int t = id - 2048; bx = t & 63; by = t >> 6;
    src = f1; dst = wb + (size_t)8*1048576; R = 1024; C = 4096;
  } else {
    const int t = id - 3072; bx = t & 15; by = t >> 4;
    src = f2; dst = wb + (size_t)12*1048576; R = 4096; C = 1024;
  }
  const int tx = threadIdx.x & 63, ty = threadIdx.x >> 6;
  const int r0 = by*64, c0 = bx*64;
#pragma unroll
  for (int i=0;i<16;i++) tile[ty+i*4][tx] = src[(size_t)(r0+ty+i*4)*C + c0+tx];
  __syncthreads();
#pragma unroll
  for (int i=0;i<16;i++) dst[(size_t)(c0+ty+i*4)*R + r0+tx] = (__bf16)tile[tx][ty+i*4];
}

// ---------------- LayerNorm: zb = LN(ysum)*g+b ----------------
__global__ __launch_bounds__(256) void ln_k(const float* __restrict__ ysum,
                                            const float* __restrict__ gam, const float* __restrict__ bet,
                                            __bf16* __restrict__ zbout) {
  const int row = blockIdx.x, tid = threadIdx.x;
  const f32x4 v = ((const f32x4*)(ysum + (size_t)row*D_))[tid];
  float s1 = v[0]+v[1]+v[2]+v[3];
  float s2 = v[0]*v[0]+v[1]*v[1]+v[2]*v[2]+v[3]*v[3];
#pragma unroll
  for (int off=32; off; off>>=1) { s1 += __shfl_xor(s1,off); s2 += __shfl_xor(s2,off); }
  __shared__ float red[8];
  const int wv = tid>>6, ln = tid&63;
  if (ln==0) { red[wv] = s1; red[4+wv] = s2; }
  __syncthreads();
  s1 = red[0]+red[1]+red[2]+red[3];
  s2 = red[4]+red[5]+red[6]+red[7];
  const float mean = s1 * (1.f/1024.f);
  const float var = s2 * (1.f/1024.f) - mean*mean;
  const float rs = rsqrtf(var + 1e-5f);
  const f32x4 gv = ((const f32x4*)gam)[tid];
  const f32x4 bv = ((const f32x4*)bet)[tid];
  bf16x4 rb;
#pragma unroll
  for (int j=0;j<4;j++) rb[j] = (__bf16)((v[j]-mean)*rs*gv[j] + bv[j]);
  ((bf16x4*)(zbout + (size_t)row*D_))[tid] = rb;
}

// ---------------- cond MLP branch hiddens ----------------
__global__ __launch_bounds__(256) void cond1_k(const int* __restrict__ t, const float* __restrict__ target,
                                               const float* __restrict__ action,
                                               const float* __restrict__ t_w1, const float* __restrict__ t_b1,
                                               const float* __restrict__ tg_w1, const float* __restrict__ tg_b1,
                                               const float* __restrict__ ac_w1, const float* __restrict__ ac_b1,
                                               float* __restrict__ h3) {
  const int i = blockIdx.x*256 + threadIdx.x;
  const int b = i >> 10, d = i & 1023;
  float u = (float)t[b] * t_w1[d] + t_b1[d];
  h3[i] = u / (1.f + __expf(-u));
  u = tg_b1[d];
#pragma unroll
  for (int j=0;j<3;j++) u += target[b*3+j]*tg_w1[j*1024+d];
  h3[8192 + i] = u / (1.f + __expf(-u));
  u = ac_b1[d];
#pragma unroll
  for (int j=0;j<5;j++) u += action[b*5+j]*ac_w1[j*1024+d];
  h3[16384 + i] = u / (1.f + __expf(-u));
}

__global__ __launch_bounds__(256) void cond2_k(const float* __restrict__ h3,
                                               const float* __restrict__ t_w2, const float* __restrict__ tg_w2,
                                               const float* __restrict__ ac_w2, float* __restrict__ cpart) {
  const int i = blockIdx.x*256 + threadIdx.x;
  const int ks = blockIdx.y;
  const int b = i >> 10, d = i & 1023;
  const float* ht = h3 + b*1024;
  const float* hg = h3 + 8192 + b*1024;
  const float* ha = h3 + 16384 + b*1024;
  float a = 0.f;
  for (int k = ks*128; k < ks*128+128; ++k)
    a += ht[k]*t_w2[(size_t)k*1024+d] + hg[k]*tg_w2[(size_t)k*1024+d] + ha[k]*ac_w2[(size_t)k*1024+d];
  cpart[ks*8192 + i] = a;
}

// ---------------- embedding: writes zb + memb (bf16 stream) ----------------
__global__ __launch_bounds__(256) void embed_k(const float* __restrict__ x, const float* __restrict__ hist,
                                               const float* __restrict__ in_w, const float* __restrict__ in_b,
                                               const float* __restrict__ cpart,
                                               const float* __restrict__ t_b2, const float* __restrict__ tg_b2,
                                               const float* __restrict__ ac_b2,
                                               __bf16* __restrict__ zb, __bf16* __restrict__ memb) {
  const int row = blockIdx.x, tid = threadIdx.x;
  const int b = row / T_, tt = row - b*T_;
  const float* feat = (tt < HIST_) ? (hist + ((size_t)b*HIST_ + tt)*10) : (x + ((size_t)b*S_ + (tt-HIST_))*10);
  float f[10];
#pragma unroll
  for (int s=0;s<10;s++) f[s] = feat[s];
  const float te = (float)((tt < HIST_) ? tt : tt - HIST_);
  f32x4 a = ((const f32x4*)in_b)[tid];
#pragma unroll
  for (int u=0;u<2;u++) {
    const int d = tid*4 + 2*u;
    const float freq = __expf((float)d * (-9.210340371976184f/1024.f));
    float sn, cs;
    __sincosf(te*freq, &sn, &cs);
    a[2*u] += sn; a[2*u+1] += cs;
  }
  a += ((const f32x4*)t_b2)[tid];
  a += ((const f32x4*)tg_b2)[tid];
  a += ((const f32x4*)ac_b2)[tid];
  const int cb = b*256 + tid;
#pragma unroll
  for (int ks=0;ks<8;ks++) a += ((const f32x4*)cpart)[ks*2048 + cb];
#pragma unroll
  for (int s=0;s<10;s++) {
    const f32x4 wv = ((const f32x4*)(in_w + s*1024))[tid];
    a += wv * f[s];
  }
  bf16x4 ab;
#pragma unroll
  for (int j=0;j<4;j++) ab[j] = (__bf16)a[j];
  ((bf16x4*)(zb + (size_t)row*D_))[tid] = ab;
  ((bf16x4*)(memb + (size_t)row*D_))[tid] = ab;
}

// ---------------- output projection (reads bf16 stream) ----------------
__global__ __launch_bounds__(256) void outp_k(const __bf16* __restrict__ z, const float* __restrict__ w,
                                              const float* __restrict__ bo, float* __restrict__ out) {
  const int wv = threadIdx.x>>6, ln = threadIdx.x&63;
  const int row = blockIdx.x*4 + wv;
  const int b = row >> 10, s = row & 1023;
  const __bf16* zr = z + ((size_t)b*T_ + HIST_ + s)*D_;
  float acc[10];
#pragma unroll
  for (int o=0;o<10;o++) acc[o]=0.f;
  for (int k=ln; k<1024; k+=64) {
    const float zv = (float)zr[k];
    const float* wr = w + k*10;
#pragma unroll
    for (int o=0;o<10;o++) acc[o] += zv*wr[o];
  }
#pragma unroll
  for (int o=0;o<10;o++) {
#pragma unroll
    for (int off=32; off; off>>=1) acc[o] += __shfl_xor(acc[o], off);
  }
  if (ln==0) {
#pragma unroll
    for (int o=0;o<10;o++) out[(size_t)row*10+o] = acc[o] + bo[o];
  }
}

extern "C" void kernel_launch(void* const* d_in, const int* in_sizes, int n_in,
                              void* d_out, int out_size, void* d_ws, size_t ws_size,
                              hipStream_t stream) {
  const float* x      = (const float*)d_in[0];
  const int*   t      = (const int*)  d_in[1];
  const float* target = (const float*)d_in[2];
  const float* action = (const float*)d_in[3];
  const float* hist   = (const float*)d_in[4];
  const float* in_w   = (const float*)d_in[5];
  const float* in_b   = (const float*)d_in[6];
  const float* t_w1   = (const float*)d_in[7];
  const float* t_b1   = (const float*)d_in[8];
  const float* t_w2   = (const float*)d_in[9];
  const float* t_b2   = (const float*)d_in[10];
  const float* tg_w1  = (const float*)d_in[11];
  const float* tg_b1  = (const float*)d_in[12];
  const float* tg_w2  = (const float*)d_in[13];
  const float* tg_b2  = (const float*)d_in[14];
  const float* ac_w1  = (const float*)d_in[15];
  const float* ac_b1  = (const float*)d_in[16];
  const float* ac_w2  = (const float*)d_in[17];
  const float* ac_b2  = (const float*)d_in[18];
  const float* sa_wq  = (const float*)d_in[19];
  const float* sa_bq  = (const float*)d_in[20];
  const float* sa_wk  = (const float*)d_in[21];
  const float* sa_bk  = (const float*)d_in[22];
  const float* sa_wv  = (const float*)d_in[23];
  const float* sa_bv  = (const float*)d_in[24];
  const float* sa_wo  = (const float*)d_in[25];
  const float* sa_bo  = (const float*)d_in[26];
  const float* ca_wq  = (const float*)d_in[27];
  const float* ca_bq  = (const float*)d_in[28];
  const float* ca_wk  = (const float*)d_in[29];
  const float* ca_bk  = (const float*)d_in[30];
  const float* ca_wv  = (const float*)d_in[31];
  const float* ca_bv  = (const float*)d_in[32];
  const float* ca_wo  = (const float*)d_in[33];
  const float* ca_bo  = (const float*)d_in[34];
  const float* ln1_g  = (const float*)d_in[35];
  const float* ln1_b  = (const float*)d_in[36];
  const float* ln2_g  = (const float*)d_in[37];
  const float* ln2_b  = (const float*)d_in[38];
  const float* ln3_g  = (const float*)d_in[39];
  const float* ln3_b  = (const float*)d_in[40];
  const float* ff_w1  = (const float*)d_in[41];
  const float* ff_b1  = (const float*)d_in[42];
  const float* ff_w2  = (const float*)d_in[43];
  const float* ff_b2  = (const float*)d_in[44];
  const float* out_w  = (const float*)d_in[45];
  const float* out_b  = (const float*)d_in[46];

  if (ws_size < (size_t)224*1024*1024) return;

  char* p = (char*)d_ws;
  auto take = [&](size_t bytes) { char* r = p; p += (bytes + 255) & ~(size_t)255; return r; };
  __bf16* wbuf = (__bf16*)take((size_t)16*1024*1024*2);
  __bf16* zb   = (__bf16*)take((size_t)NROWS_*D_*2);
  __bf16* memb = (__bf16*)take((size_t)NROWS_*D_*2);
  __bf16* qk   = (__bf16*)take((size_t)NROWS_*2048*2);
  __bf16* vt   = (__bf16*)take((size_t)1024*NROWS_*2);
  __bf16* ob   = (__bf16*)take((size_t)NROWS_*D_*2);
  float*  ysum = (float*) take((size_t)NROWS_*D_*4);
  float*  h3   = (float*) take((size_t)3*8192*4);
  float*  cpart= (float*) take((size_t)8*8192*4);
  __bf16* ffh  = qk;   // FFN hidden aliases qk+vt+ob (75.5 MB)

  const dim3 blk(256);
  const dim3 blk5(512);
  const int BIG = 1<<30;
  cond1_k<<<32, blk, 0, stream>>>(t, target, action, t_w1, t_b1, tg_w1, tg_b1, ac_w1, ac_b1, h3);
  cond2_k<<<dim3(32,8), blk, 0, stream>>>(h3, t_w2, tg_w2, ac_w2, cpart);
  embed_k<<<NROWS_, blk, 0, stream>>>(x, hist, in_w, in_b, cpart, t_b2, tg_b2, ac_b2, zb, memb);

  const int M = NROWS_;
  for (int li=0; li<L_; ++li) {
    const size_t w0 = (size_t)li*D_*D_, b0 = (size_t)li*D_;
    const size_t f1 = (size_t)li*D_*FF_, fb1 = (size_t)li*FF_;
    wprep_k<<<4096, blk, 0, stream>>>(sa_wq+w0, sa_wk+w0, sa_wv+w0, sa_wo+w0,
                                      ca_wq+w0, ca_wk+w0, ca_wv+w0, ca_wo+w0,
                                      ff_w1+f1, ff_w2+f1, wbuf);
    // self-attention: fused QKV (N=3072), 256^2 kernel
    gemm256_k<3,0><<<36*12, blk5, 0, stream>>>(zb, zb, BIG, wbuf+0*1048576,
                                               sa_bq+b0, sa_bk+b0, sa_bv+b0, 1024, 2048,
                                               qk, vt, M, 3072, 1024, 2048, 2048);
    attn_k<<<1152, blk, 0, stream>>>(qk, vt, ob);
    // o-proj + residual(zb) -> ysum (f32)
    gemm192_k<0,0,1><<<48*4, blk5, 0, stream>>>(ob, wbuf+3*1048576, sa_bo+b0, ysum, zb,
                                                M, 1024, 1024, 1024);
    ln_k<<<NROWS_, blk, 0, stream>>>(ysum, ln1_g+b0, ln1_b+b0, zb);
    // cross-attention: fused Q|KV (N=3072); Q cols read zb, K/V cols read memb
    gemm256_k<3,0><<<36*12, blk5, 0, stream>>>(zb, memb, 1024, wbuf+4*1048576,
                                               ca_bq+b0, ca_bk+b0, ca_bv+b0, 1024, 2048,
                                               qk, vt, M, 3072, 1024, 2048, 2048);
    attn_k<<<1152, blk, 0, stream>>>(qk, vt, ob);
    gemm192_k<0,0,1><<<48*4, blk5, 0, stream>>>(ob, wbuf+7*1048576, ca_bo+b0, ysum, zb,
                                                M, 1024, 1024, 1024);
    ln_k<<<NROWS_, blk, 0, stream>>>(ysum, ln2_g+b0, ln2_b+b0, zb);
    // FFN
    gemm192_k<1,1,0><<<48*16, blk5, 0, stream>>>(zb, wbuf+(size_t)8*1048576, ff_b1+fb1, ffh, nullptr,
                                                 M, 4096, 1024, 4096);
    gemm192_k<0,0,1><<<48*4, blk5, 0, stream>>>(ffh, wbuf+(size_t)12*1048576, ff_b2+b0, ysum, zb,
                                                M, 1024, 4096, 1024);
    ln_k<<<NROWS_, blk, 0, stream>>>(ysum, ln3_g+b0, ln3_b+b0, zb);
  }
  outp_k<<<2048, blk, 0, stream>>>(zb, out_w, out_b, (float*)d_out);
}

// Round 15
// 3865.372 us; speedup vs baseline: 1.0768x; 1.0018x over previous
//
#include <hip/hip_runtime.h>
#include <hip/hip_bf16.h>
#include <stdint.h>

#define B_    8
#define S_    1024
#define HIST_ 128
#define T_    1152
#define D_    1024
#define NH_   16
#define DH_   64
#define FF_   4096
#define L_    6
#define NROWS_ (B_*T_)   /* 9216 */

typedef __attribute__((ext_vector_type(8))) __bf16 bf16x8;
typedef __attribute__((ext_vector_type(4))) __bf16 bf16x4;
typedef __attribute__((ext_vector_type(4))) float  f32x4;

static __device__ __forceinline__ f32x4 mfma16(bf16x8 a, bf16x8 b, f32x4 c) {
  return __builtin_amdgcn_mfma_f32_16x16x32_bf16(a, b, c, 0, 0, 0);
}
static __device__ __forceinline__ void gload16(const __bf16* g, __bf16* l) {
  __builtin_amdgcn_global_load_lds((const __attribute__((address_space(1))) void*)g,
                                   (__attribute__((address_space(3))) void*)l, 16, 0, 0);
}
static __device__ __forceinline__ void gload16b(const char* g, char* l) {
  __builtin_amdgcn_global_load_lds((const __attribute__((address_space(1))) void*)g,
                                   (__attribute__((address_space(3))) void*)l, 16, 0, 0);
}
// bijective XCD swizzle (m204)
static __device__ __forceinline__ int xcd_swz(int orig, int nwg) {
  const int q = nwg >> 3, r = nwg & 7;
  const int x = orig & 7, i = orig >> 3;
  return (x < r ? x*(q+1) : r*(q+1) + (x-r)*q) + i;
}

// ---------------- 192x256 GEMM, BK=64, 8 waves (2Mx4N), counted-vmcnt pipeline ----------------
// (o-proj / FFN1 / FFN2) — RESADD fuses the residual add: out = acc + bias + resid (f32)
template<int BF16OUT, int RELU, int RESADD>
__global__ __launch_bounds__(512, 2) void gemm192_k(const __bf16* __restrict__ A,
                                                    const __bf16* __restrict__ Bt,
                                                    const float* __restrict__ bias,
                                                    void* __restrict__ Cout,
                                                    const __bf16* __restrict__ resid,
                                                    int M, int N, int K, int ldc) {
  __shared__ __align__(16) char Lds[2][57344];
  const int tid = threadIdx.x;
  const int wid = tid >> 6, ln = tid & 63;
  const int wm = wid >> 2, wn = wid & 3;
  const int l15 = ln & 15, g = ln >> 4;
  const int nbx = N >> 8;
  const int wg = xcd_swz(blockIdx.x, gridDim.x);
  const int m0 = (wg / nbx) * 192, n0 = (wg % nbx) << 8;
  const size_t rstep = (size_t)K * 2;

  const char* srcp[7];
  int dsto[7];
#pragma unroll
  for (int p = 0; p < 7; ++p) {
    const int off = p*8192 + tid*16;
    int mat, ks, row;
    if (off < 12288)      { mat = 0; ks = 0; row = off >> 6; }
    else if (off < 24576) { mat = 0; ks = 1; row = (off - 12288) >> 6; }
    else if (off < 40960) { mat = 1; ks = 0; row = (off - 24576) >> 6; }
    else                  { mat = 1; ks = 1; row = (off - 40960) >> 6; }
    const int chn = (off >> 4) & 3;
    const int kb = ks*64 + ((chn ^ ((row >> 1) & 3)) << 4);
    srcp[p] = (mat ? (const char*)Bt + (size_t)(n0 + row)*rstep
                   : (const char*)A  + (size_t)(m0 + row)*rstep) + kb;
    dsto[p] = off;
  }
  auto stage_range = [&](int buf, int t, int p0, int p1) {
    char* lb = &Lds[buf][0];
    const size_t tb = (size_t)t << 7;
#pragma unroll
    for (int p = p0; p < p1; ++p) gload16b(srcp[p] + tb, lb + dsto[p]);
  };

  const int xr = (g ^ ((l15 >> 1) & 3)) << 4;
  const int arow = l15*64 + xr;
  const int aoffm = (wm*96) * 64;
  const int boff  = 24576 + (wn*64) * 64;

  const f32x4 zero = {0.f,0.f,0.f,0.f};
  f32x4 acc[6][4];
#pragma unroll
  for (int i=0;i<6;i++)
#pragma unroll
    for (int j=0;j<4;j++) acc[i][j] = zero;

  stage_range(0, 0, 0, 7); stage_range(1, 1, 0, 7);

  const int NT = K >> 6;
  for (int t = 0; t < NT; ++t) {
    const int buf = t & 1;
    if (t == NT-1) { asm volatile("s_waitcnt vmcnt(0)" ::: "memory"); }
    else           { asm volatile("s_waitcnt vmcnt(7)" ::: "memory"); }
    __builtin_amdgcn_s_barrier();
    const char* bufp = &Lds[buf][0];
    bf16x8 a0[6], a1[6], b0[4], b1[4];
#pragma unroll
    for (int mi=0;mi<6;mi++) a0[mi] = *(const bf16x8*)(bufp + aoffm + mi*1024 + arow);
#pragma unroll
    for (int ni=0;ni<4;ni++) b0[ni] = *(const bf16x8*)(bufp + boff + ni*1024 + arow);
#pragma unroll
    for (int mi=0;mi<6;mi++) a1[mi] = *(const bf16x8*)(bufp + 12288 + aoffm + mi*1024 + arow);
    __builtin_amdgcn_s_setprio(1);
#pragma unroll
    for (int mi=0;mi<6;mi++)
#pragma unroll
      for (int ni=0;ni<4;ni++) acc[mi][ni] = mfma16(a0[mi], b0[ni], acc[mi][ni]);
    __builtin_amdgcn_s_setprio(0);
#pragma unroll
    for (int ni=0;ni<4;ni++) b1[ni] = *(const bf16x8*)(bufp + boff + 16384 + ni*1024 + arow);
    asm volatile("s_waitcnt lgkmcnt(0)" ::: "memory");
    __builtin_amdgcn_s_barrier();           // all waves done reading buf
    const bool st = (t + 2 <= NT - 1);
    if (st) stage_range(buf, t + 2, 0, 4);
    __builtin_amdgcn_s_setprio(1);
#pragma unroll
    for (int mi=0;mi<6;mi++)
#pragma unroll
      for (int ni=0;ni<4;ni++) acc[mi][ni] = mfma16(a1[mi], b1[ni], acc[mi][ni]);
    __builtin_amdgcn_s_setprio(0);
    if (st) stage_range(buf, t + 2, 4, 7);
  }

  const int colb = n0 + wn*64 + l15;
#pragma unroll
  for (int mi=0;mi<6;mi++) {
    const int row = m0 + wm*96 + mi*16 + g*4;
#pragma unroll
    for (int ni=0;ni<4;ni++) {
      const int col = colb + ni*16;
      const float bv = bias[col];
#pragma unroll
      for (int j=0;j<4;j++) {
        float v = acc[mi][ni][j] + bv;
        if (RESADD) v += (float)resid[(size_t)(row+j)*ldc + col];
        if (RELU) v = fmaxf(v, 0.f);
        if (BF16OUT) ((__bf16*)Cout)[(size_t)(row+j)*ldc + col] = (__bf16)v;
        else         ((float*)Cout)[(size_t)(row+j)*ldc + col] = v;
      }
    }
  }
}

// ---------------- 256x256 GEMM (QKV shapes) — R8-proven ----------------
template<int OUTMODE, int RELU>
__global__ __launch_bounds__(512, 2) void gemm256_k(const __bf16* __restrict__ A,
                                                    const __bf16* __restrict__ A2, int asplit,
                                                    const __bf16* __restrict__ Bt,
                                                    const float* __restrict__ b1,
                                                    const float* __restrict__ b2,
                                                    const float* __restrict__ b3, int s1, int s2,
                                                    void* __restrict__ CoutRM,
                                                    __bf16* __restrict__ CoutT,
                                                    int M, int N, int K, int ldc, int tsplit) {
  __shared__ __align__(16) __bf16 Lds[2][2][2][8192];
  const int tid = threadIdx.x;
  const int wid = tid >> 6, ln = tid & 63;
  const int wm = wid >> 2, wn = wid & 3;
  const int l15 = ln & 15, g = ln >> 4;
  const int nbx = N >> 8;
  const int wg = xcd_swz(blockIdx.x, gridDim.x);
  const int m0 = (wg / nbx) << 8, n0 = (wg % nbx) << 8;
  const size_t rstep = (size_t)K * 2;
  const __bf16* Aeff = (n0 < asplit) ? A : A2;

  const int srow = tid >> 2, schunk = tid & 3;
  const int sx = (schunk ^ ((srow >> 1) & 3)) << 4;
  const char* gAr = (const char*)Aeff + (size_t)(m0 + srow)*rstep + sx;
  const char* gBr = (const char*)Bt   + (size_t)(n0 + srow)*rstep + sx;
  const size_t hstep = (size_t)128 * rstep;

  const int xr = (g ^ ((l15 >> 1) & 3)) << 4;
  const int arow = l15 * 64 + xr;
  const int aoffm = (wm*128) * 64;
  const int boff  = (wn*64) * 64;

  const f32x4 zero = {0.f,0.f,0.f,0.f};
  f32x4 acc[8][4];
#pragma unroll
  for (int i=0;i<8;i++)
#pragma unroll
    for (int j=0;j<4;j++) acc[i][j] = zero;

  auto stage4 = [&](int buf, int ks, int tile) {
    const size_t off = (size_t)tile*128 + (size_t)ks*64;
    char* la = (char*)&Lds[buf][ks][0][0];
    char* lb = (char*)&Lds[buf][ks][1][0];
    gload16b(gAr + off,         la + tid*16);
    gload16b(gAr + off + hstep, la + 8192 + tid*16);
    gload16b(gBr + off,         lb + tid*16);
    gload16b(gBr + off + hstep, lb + 8192 + tid*16);
  };

  auto ktile = [&](int buf, bool st, int stile, bool gate0) {
    if (gate0) { asm volatile("s_waitcnt vmcnt(0)" ::: "memory"); }
    else       { asm volatile("s_waitcnt vmcnt(8)" ::: "memory"); }
    __builtin_amdgcn_s_barrier();
    const char* As0 = (const char*)&Lds[buf][0][0][0];
    const char* Bs0 = (const char*)&Lds[buf][0][1][0];
    const char* As1 = (const char*)&Lds[buf][1][0][0];
    const char* Bs1 = (const char*)&Lds[buf][1][1][0];
    bf16x8 a0[4], a1[4], b0[4], a2[4], b1v[4], a3[4];
#pragma unroll
    for (int mi=0;mi<4;mi++) a0[mi] = *(const bf16x8*)(As0 + aoffm + mi*1024 + arow);
#pragma unroll
    for (int ni=0;ni<4;ni++) b0[ni] = *(const bf16x8*)(Bs0 + boff + ni*1024 + arow);
#pragma unroll
    for (int mi=0;mi<4;mi++) a1[mi] = *(const bf16x8*)(As0 + aoffm + 4096 + mi*1024 + arow);
    __builtin_amdgcn_s_setprio(1);
#pragma unroll
    for (int mi=0;mi<4;mi++)
#pragma unroll
      for (int ni=0;ni<4;ni++) acc[mi][ni] = mfma16(a0[mi], b0[ni], acc[mi][ni]);
    __builtin_amdgcn_s_setprio(0);
#pragma unroll
    for (int mi=0;mi<4;mi++) a2[mi]  = *(const bf16x8*)(As1 + aoffm + mi*1024 + arow);
#pragma unroll
    for (int ni=0;ni<4;ni++) b1v[ni] = *(const bf16x8*)(Bs1 + boff + ni*1024 + arow);
    asm volatile("s_waitcnt lgkmcnt(0)" ::: "memory");
    __builtin_amdgcn_s_barrier();
    if (st) stage4(buf, 0, stile);
    __builtin_amdgcn_s_setprio(1);
#pragma unroll
    for (int mi=0;mi<4;mi++)
#pragma unroll
      for (int ni=0;ni<4;ni++) acc[4+mi][ni] = mfma16(a1[mi], b0[ni], acc[4+mi][ni]);
    __builtin_amdgcn_s_setprio(0);
#pragma unroll
    for (int mi=0;mi<4;mi++) a3[mi] = *(const bf16x8*)(As1 + aoffm + 4096 + mi*1024 + arow);
    __builtin_amdgcn_s_setprio(1);
#pragma unroll
    for (int mi=0;mi<4;mi++)
#pragma unroll
      for (int ni=0;ni<4;ni++) acc[mi][ni] = mfma16(a2[mi], b1v[ni], acc[mi][ni]);
    __builtin_amdgcn_s_setprio(0);
    asm volatile("s_waitcnt lgkmcnt(0)" ::: "memory");
    __builtin_amdgcn_s_barrier();
    if (st) stage4(buf, 1, stile);
    __builtin_amdgcn_s_setprio(1);
#pragma unroll
    for (int mi=0;mi<4;mi++)
#pragma unroll
      for (int ni=0;ni<4;ni++) acc[4+mi][ni] = mfma16(a3[mi], b1v[ni], acc[4+mi][ni]);
    __builtin_amdgcn_s_setprio(0);
  };

  stage4(0, 0, 0); stage4(0, 1, 0);
  stage4(1, 0, 1); stage4(1, 1, 1);

  const int NT = K >> 6, NI = NT >> 1;
  for (int i = 0; i < NI; ++i) {
    const bool st = (i + 1 < NI);
    ktile(0, st, 2*i + 2, false);
    ktile(1, st, 2*i + 3, i == NI - 1);
  }

  const int colb = n0 + wn*64 + l15;
#pragma unroll
  for (int mi=0;mi<8;mi++) {
    const int row = m0 + wm*128 + mi*16 + g*4;
#pragma unroll
    for (int ni=0;ni<4;ni++) {
      const int col = colb + ni*16;
      const float bv = (col < s1) ? b1[col] : ((col < s2) ? b2[col-s1] : b3[col-s2]);
      if (OUTMODE == 3 && col >= tsplit) {
        bf16x4 ct;
#pragma unroll
        for (int j=0;j<4;j++) {
          float v = acc[mi][ni][j] + bv;
          if (RELU) v = fmaxf(v, 0.f);
          ct[j] = (__bf16)v;
        }
        *(bf16x4*)(CoutT + (size_t)(col - tsplit)*M + row) = ct;
      } else {
#pragma unroll
        for (int j=0;j<4;j++) {
          float v = acc[mi][ni][j] + bv;
          if (RELU) v = fmaxf(v, 0.f);
          if (OUTMODE == 0) ((float*)CoutRM)[(size_t)(row+j)*ldc + col] = v;
          else              ((__bf16*)CoutRM)[(size_t)(row+j)*ldc + col] = (__bf16)v;
        }
      }
    }
  }
}

// ---------------- Flash attention, causal, NH=16 DH=64, T13 defer-max ----------------
__global__ __launch_bounds__(256) void attn_k(const __bf16* __restrict__ QK,
                                              const __bf16* __restrict__ Vt,
                                              __bf16* __restrict__ O) {
  __shared__ __align__(16) __bf16 Ks[2][4096];
  __shared__ __align__(16) __bf16 Vs[2][4096];
  __shared__ __align__(16) __bf16 Pl[4][32*72];
  const int tid = threadIdx.x;
  const int wv = tid >> 6, ln = tid & 63;
  const int l15 = ln & 15, g = ln >> 4;
  const int wg = xcd_swz(blockIdx.x, 1152);
  const int qb = 8 - (wg % 9);
  const int hd = (wg / 9) & 15;
  const int b  = wg / 144;
  const int q0 = qb*128 + wv*32;

  bf16x8 qf[2][2];
#pragma unroll
  for (int f=0; f<2; ++f)
#pragma unroll
    for (int h=0; h<2; ++h)
      qf[f][h] = *(const bf16x8*)(QK + (size_t)(b*T_ + q0 + f*16 + l15)*2048 + hd*64 + h*32 + g*8);

  const int sr = tid >> 3;
  const int si = tid & 7;
  const int cb0 = (si*16) ^ ((sr & 7) << 4);
  const char* kg = (const char*)(QK + (size_t)b*T_*2048 + 1024 + hd*64);
  const char* vg = (const char*)(Vt + (size_t)hd*64*NROWS_ + (size_t)b*T_);

  const f32x4 zero = {0.f,0.f,0.f,0.f};
  f32x4 o[2][4];
#pragma unroll
  for (int f=0; f<2; ++f)
#pragma unroll
    for (int d=0; d<4; ++d) o[f][d] = zero;
  float mrun[2] = {-3.0e38f, -3.0e38f};
  float lrun[2] = {0.f, 0.f};
  const int nt = 2*qb + 2;

  {
    const int c = 0, kt = 0;
#pragma unroll
    for (int hr=0; hr<2; ++hr) {
      const int r = sr + hr*32;
      gload16((const __bf16*)(kg + (size_t)(kt + r)*4096 + cb0), &Ks[c][0] + hr*2048 + wv*512);
      gload16((const __bf16*)(vg + (size_t)r*(NROWS_*2) + (size_t)kt*2 + cb0), &Vs[c][0] + hr*2048 + wv*512);
    }
  }

  for (int t = 0; t < nt; ++t) {
    __syncthreads();
    if (t+1 < nt) {
      const int c = (t+1)&1, kt2 = (t+1)*64;
#pragma unroll
      for (int hr=0; hr<2; ++hr) {
        const int r = sr + hr*32;
        gload16((const __bf16*)(kg + (size_t)(kt2 + r)*4096 + cb0), &Ks[c][0] + hr*2048 + wv*512);
        gload16((const __bf16*)(vg + (size_t)r*(NROWS_*2) + (size_t)kt2*2 + cb0), &Vs[c][0] + hr*2048 + wv*512);
      }
    }
    const int kt = t*64;
    if (kt > q0 + 31) continue;
    const char* ks = (const char*)&Ks[t&1][0];
    const char* vs = (const char*)&Vs[t&1][0];

#pragma unroll
    for (int f=0; f<2; ++f) {
      const int qrow = q0 + f*16 + l15;
      f32x4 st[4];
      __builtin_amdgcn_s_setprio(1);
#pragma unroll
      for (int kf=0; kf<4; ++kf) {
        const int row = kf*16 + l15;
        const int swz = (row & 7) << 4;
        const bf16x8 k0 = *(const bf16x8*)(ks + row*128 + ((g*16) ^ swz));
        const bf16x8 k1 = *(const bf16x8*)(ks + row*128 + ((64 + g*16) ^ swz));
        st[kf] = mfma16(k1, qf[f][1], mfma16(k0, qf[f][0], zero));
      }
      __builtin_amdgcn_s_setprio(0);
      float p[16];
#pragma unroll
      for (int kf=0; kf<4; ++kf)
#pragma unroll
        for (int r=0; r<4; ++r) {
          const int kgl = kt + kf*16 + g*4 + r;
          p[kf*4+r] = (kgl <= qrow) ? st[kf][r]*0.125f : -3.0e38f;
        }
      float mloc = p[0];
#pragma unroll
      for (int i=1;i<16;i++) mloc = fmaxf(mloc, p[i]);
      mloc = fmaxf(mloc, __shfl_xor(mloc, 16));
      mloc = fmaxf(mloc, __shfl_xor(mloc, 32));
      if (__all(mloc - mrun[f] <= 8.f)) {
        float ls = 0.f;
#pragma unroll
        for (int i=0;i<16;i++) { p[i] = __expf(p[i] - mrun[f]); ls += p[i]; }
        ls += __shfl_xor(ls, 16); ls += __shfl_xor(ls, 32);
        lrun[f] += ls;
      } else {
        const float mnew = fmaxf(mrun[f], mloc);
        const float corr = __expf(mrun[f] - mnew);
        float ls = 0.f;
#pragma unroll
        for (int i=0;i<16;i++) { p[i] = __expf(p[i] - mnew); ls += p[i]; }
        ls += __shfl_xor(ls, 16); ls += __shfl_xor(ls, 32);
        lrun[f] = lrun[f]*corr + ls;
        mrun[f] = mnew;
        float cr[4];
#pragma unroll
        for (int r=0;r<4;r++) cr[r] = __shfl(corr, g*4 + r);
#pragma unroll
        for (int db=0; db<4; ++db)
#pragma unroll
          for (int r=0;r<4;r++) o[f][db][r] *= cr[r];
      }
#pragma unroll
      for (int kf=0; kf<4; ++kf) {
        bf16x4 pw;
#pragma unroll
        for (int r=0;r<4;r++) pw[r] = (__bf16)p[kf*4+r];
        *(bf16x4*)(&Pl[wv][(f*16 + l15)*72 + kf*16 + g*4]) = pw;
      }
    }
    __builtin_amdgcn_s_setprio(1);
#pragma unroll
    for (int f=0; f<2; ++f)
#pragma unroll
      for (int ks2=0; ks2<2; ++ks2) {
        const bf16x8 pa = *(const bf16x8*)(&Pl[wv][(f*16 + l15)*72 + ks2*32 + g*8]);
#pragma unroll
        for (int db=0; db<4; ++db) {
          const int d = db*16 + l15;
          const bf16x8 vf = *(const bf16x8*)(vs + d*128 + ((ks2*64 + g*16) ^ ((d & 7) << 4)));
          o[f][db] = mfma16(pa, vf, o[f][db]);
        }
      }
    __builtin_amdgcn_s_setprio(0);
  }

#pragma unroll
  for (int f=0; f<2; ++f) {
    const float inv = 1.f / lrun[f];
    float ir[4];
#pragma unroll
    for (int r=0;r<4;r++) ir[r] = __shfl(inv, g*4 + r);
#pragma unroll
    for (int db=0; db<4; ++db)
#pragma unroll
      for (int r=0;r<4;r++)
        O[(size_t)(b*T_ + q0 + f*16 + g*4 + r)*D_ + hd*64 + db*16 + l15] = (__bf16)(o[f][db][r]*ir[r]);
  }
}

// ---------------- batched weight prep: 64x64 tiles ----------------
__global__ __launch_bounds__(256) void wprep_k(const float* __restrict__ q, const float* __restrict__ k,
                                               const float* __restrict__ v, const float* __restrict__ o,
                                               const float* __restrict__ cq, const float* __restrict__ ck,
                                               const float* __restrict__ cv, const float* __restrict__ co,
                                               const float* __restrict__ f1, const float* __restrict__ f2,
                                               __bf16* __restrict__ wb) {
  __shared__ float tile[64][65];
  const int id = blockIdx.x;
  const float* src; __bf16* dst; int R, C, bx, by;
  if (id < 2048) {
    const int m = id >> 8, t = id & 255; bx = t & 15; by = t >> 4;
    const float* srcs[8] = {q,k,v,o,cq,ck,cv,co};
    src = srcs[m]; dst = wb + (size_t)m*1048576; R = 1024; C = 1024;
  } else if (id < 3072) {
    const int t = id - 2048; bx = t & 63; by = t >> 6;
    src = f1; dst = wb + (size_t)8*1048576; R = 1024; C = 4096;
  } else {
    const int t = id - 3072; bx = t & 15; by = t >> 4;
    src = f2; dst = wb + (size_t)12*1048576; R = 4096; C = 1024;
  }
  const int tx = threadIdx.x & 63, ty = threadIdx.x >> 6;
  const int r0 = by*64, c0 = bx*64;
#pragma unroll
  for (int i=0;i<16;i++) tile[ty+i*4][tx] = src[(size_t)(r0+ty+i*4)*C + c0+tx];
  __syncthreads();
#pragma unroll
  for (int i=0;i<16;i++) dst[(size_t)(c0+ty+i*4)*R + r0+tx] = (__bf16)tile[tx][ty+i*4];
}

// ---------------- LayerNorm: zb = LN(ysum)*g+b ----------------
__global__ __launch_bounds__(256) void ln_k(const float* __restrict__ ysum,
                                            const float* __restrict__ gam, const float* __restrict__ bet,
                                            __bf16* __restrict__ zbout) {
  const int row = blockIdx.x, tid = threadIdx.x;
  const f32x4 v = ((const f32x4*)(ysum + (size_t)row*D_))[tid];
  float s1 = v[0]+v[1]+v[2]+v[3];
  float s2 = v[0]*v[0]+v[1]*v[1]+v[2]*v[2]+v[3]*v[3];
#pragma unroll
  for (int off=32; off; off>>=1) { s1 += __shfl_xor(s1,off); s2 += __shfl_xor(s2,off); }
  __shared__ float red[8];
  const int wv = tid>>6, ln = tid&63;
  if (ln==0) { red[wv] = s1; red[4+wv] = s2; }
  __syncthreads();
  s1 = red[0]+red[1]+red[2]+red[3];
  s2 = red[4]+red[5]+red[6]+red[7];
  const float mean = s1 * (1.f/1024.f);
  const float var = s2 * (1.f/1024.f) - mean*mean;
  const float rs = rsqrtf(var + 1e-5f);
  const f32x4 gv = ((const f32x4*)gam)[tid];
  const f32x4 bv = ((const f32x4*)bet)[tid];
  bf16x4 rb;
#pragma unroll
  for (int j=0;j<4;j++) rb[j] = (__bf16)((v[j]-mean)*rs*gv[j] + bv[j]);
  ((bf16x4*)(zbout + (size_t)row*D_))[tid] = rb;
}

// ---------------- cond MLP branch hiddens ----------------
__global__ __launch_bounds__(256) void cond1_k(const int* __restrict__ t, const float* __restrict__ target,
                                               const float* __restrict__ action,
                                               const float* __restrict__ t_w1, const float* __restrict__ t_b1,
                                               const float* __restrict__ tg_w1, const float* __restrict__ tg_b1,
                                               const float* __restrict__ ac_w1, const float* __restrict__ ac_b1,
                                               float* __restrict__ h3) {
  const int i = blockIdx.x*256 + threadIdx.x;
  const int b = i >> 10, d = i & 1023;
  float u = (float)t[b] * t_w1[d] + t_b1[d];
  h3[i] = u / (1.f + __expf(-u));
  u = tg_b1[d];
#pragma unroll
  for (int j=0;j<3;j++) u += target[b*3+j]*tg_w1[j*1024+d];
  h3[8192 + i] = u / (1.f + __expf(-u));
  u = ac_b1[d];
#pragma unroll
  for (int j=0;j<5;j++) u += action[b*5+j]*ac_w1[j*1024+d];
  h3[16384 + i] = u / (1.f + __expf(-u));
}

__global__ __launch_bounds__(256) void cond2_k(const float* __restrict__ h3,
                                               const float* __restrict__ t_w2, const float* __restrict__ tg_w2,
                                               const float* __restrict__ ac_w2, float* __restrict__ cpart) {
  const int i = blockIdx.x*256 + threadIdx.x;
  const int ks = blockIdx.y;
  const int b = i >> 10, d = i & 1023;
  const float* ht = h3 + b*1024;
  const float* hg = h3 + 8192 + b*1024;
  const float* ha = h3 + 16384 + b*1024;
  float a = 0.f;
  for (int k = ks*128; k < ks*128+128; ++k)
    a += ht[k]*t_w2[(size_t)k*1024+d] + hg[k]*tg_w2[(size_t)k*1024+d] + ha[k]*ac_w2[(size_t)k*1024+d];
  cpart[ks*8192 + i] = a;
}

// ---------------- embedding: writes zb + memb (bf16 stream) ----------------
__global__ __launch_bounds__(256) void embed_k(const float* __restrict__ x, const float* __restrict__ hist,
                                               const float* __restrict__ in_w, const float* __restrict__ in_b,
                                               const float* __restrict__ cpart,
                                               const float* __restrict__ t_b2, const float* __restrict__ tg_b2,
                                               const float* __restrict__ ac_b2,
                                               __bf16* __restrict__ zb, __bf16* __restrict__ memb) {
  const int row = blockIdx.x, tid = threadIdx.x;
  const int b = row / T_, tt = row - b*T_;
  const float* feat = (tt < HIST_) ? (hist + ((size_t)b*HIST_ + tt)*10) : (x + ((size_t)b*S_ + (tt-HIST_))*10);
  float f[10];
#pragma unroll
  for (int s=0;s<10;s++) f[s] = feat[s];
  const float te = (float)((tt < HIST_) ? tt : tt - HIST_);
  f32x4 a = ((const f32x4*)in_b)[tid];
#pragma unroll
  for (int u=0;u<2;u++) {
    const int d = tid*4 + 2*u;
    const float freq = __expf((float)d * (-9.210340371976184f/1024.f));
    float sn, cs;
    __sincosf(te*freq, &sn, &cs);
    a[2*u] += sn; a[2*u+1] += cs;
  }
  a += ((const f32x4*)t_b2)[tid];
  a += ((const f32x4*)tg_b2)[tid];
  a += ((const f32x4*)ac_b2)[tid];
  const int cb = b*256 + tid;
#pragma unroll
  for (int ks=0;ks<8;ks++) a += ((const f32x4*)cpart)[ks*2048 + cb];
#pragma unroll
  for (int s=0;s<10;s++) {
    const f32x4 wv = ((const f32x4*)(in_w + s*1024))[tid];
    a += wv * f[s];
  }
  bf16x4 ab;
#pragma unroll
  for (int j=0;j<4;j++) ab[j] = (__bf16)a[j];
  ((bf16x4*)(zb + (size_t)row*D_))[tid] = ab;
  ((bf16x4*)(memb + (size_t)row*D_))[tid] = ab;
}

// ---------------- output projection (reads bf16 stream) ----------------
__global__ __launch_bounds__(256) void outp_k(const __bf16* __restrict__ z, const float* __restrict__ w,
                                              const float* __restrict__ bo, float* __restrict__ out) {
  const int wv = threadIdx.x>>6, ln = threadIdx.x&63;
  const int row = blockIdx.x*4 + wv;
  const int b = row >> 10, s = row & 1023;
  const __bf16* zr = z + ((size_t)b*T_ + HIST_ + s)*D_;
  float acc[10];
#pragma unroll
  for (int o=0;o<10;o++) acc[o]=0.f;
  for (int k=ln; k<1024; k+=64) {
    const float zv = (float)zr[k];
    const float* wr = w + k*10;
#pragma unroll
    for (int o=0;o<10;o++) acc[o] += zv*wr[o];
  }
#pragma unroll
  for (int o=0;o<10;o++) {
#pragma unroll
    for (int off=32; off; off>>=1) acc[o] += __shfl_xor(acc[o], off);
  }
  if (ln==0) {
#pragma unroll
    for (int o=0;o<10;o++) out[(size_t)row*10+o] = acc[o] + bo[o];
  }
}

extern "C" void kernel_launch(void* const* d_in, const int* in_sizes, int n_in,
                              void* d_out, int out_size, void* d_ws, size_t ws_size,
                              hipStream_t stream) {
  const float* x      = (const float*)d_in[0];
  const int*   t      = (const int*)  d_in[1];
  const float* target = (const float*)d_in[2];
  const float* action = (const float*)d_in[3];
  const float* hist   = (const float*)d_in[4];
  const float* in_w   = (const float*)d_in[5];
  const float* in_b   = (const float*)d_in[6];
  const float* t_w1   = (const float*)d_in[7];
  const float* t_b1   = (const float*)d_in[8];
  const float* t_w2   = (const float*)d_in[9];
  const float* t_b2   = (const float*)d_in[10];
  const float* tg_w1  = (const float*)d_in[11];
  const float* tg_b1  = (const float*)d_in[12];
  const float* tg_w2  = (const float*)d_in[13];
  const float* tg_b2  = (const float*)d_in[14];
  const float* ac_w1  = (const float*)d_in[15];
  const float* ac_b1  = (const float*)d_in[16];
  const float* ac_w2  = (const float*)d_in[17];
  const float* ac_b2  = (const float*)d_in[18];
  const float* sa_wq  = (const float*)d_in[19];
  const float* sa_bq  = (const float*)d_in[20];
  const float* sa_wk  = (const float*)d_in[21];
  const float* sa_bk  = (const float*)d_in[22];
  const float* sa_wv  = (const float*)d_in[23];
  const float* sa_bv  = (const float*)d_in[24];
  const float* sa_wo  = (const float*)d_in[25];
  const float* sa_bo  = (const float*)d_in[26];
  const float* ca_wq  = (const float*)d_in[27];
  const float* ca_bq  = (const float*)d_in[28];
  const float* ca_wk  = (const float*)d_in[29];
  const float* ca_bk  = (const float*)d_in[30];
  const float* ca_wv  = (const float*)d_in[31];
  const float* ca_bv  = (const float*)d_in[32];
  const float* ca_wo  = (const float*)d_in[33];
  const float* ca_bo  = (const float*)d_in[34];
  const float* ln1_g  = (const float*)d_in[35];
  const float* ln1_b  = (const float*)d_in[36];
  const float* ln2_g  = (const float*)d_in[37];
  const float* ln2_b  = (const float*)d_in[38];
  const float* ln3_g  = (const float*)d_in[39];
  const float* ln3_b  = (const float*)d_in[40];
  const float* ff_w1  = (const float*)d_in[41];
  const float* ff_b1  = (const float*)d_in[42];
  const float* ff_w2  = (const float*)d_in[43];
  const float* ff_b2  = (const float*)d_in[44];
  const float* out_w  = (const float*)d_in[45];
  const float* out_b  = (const float*)d_in[46];

  if (ws_size < (size_t)224*1024*1024) return;

  char* p = (char*)d_ws;
  auto take = [&](size_t bytes) { char* r = p; p += (bytes + 255) & ~(size_t)255; return r; };
  __bf16* wbuf = (__bf16*)take((size_t)16*1024*1024*2);
  __bf16* zb   = (__bf16*)take((size_t)NROWS_*D_*2);
  __bf16* memb = (__bf16*)take((size_t)NROWS_*D_*2);
  __bf16* qk   = (__bf16*)take((size_t)NROWS_*2048*2);
  __bf16* vt   = (__bf16*)take((size_t)1024*NROWS_*2);
  __bf16* ob   = (__bf16*)take((size_t)NROWS_*D_*2);
  float*  ysum = (float*) take((size_t)NROWS_*D_*4);
  float*  h3   = (float*) take((size_t)3*8192*4);
  float*  cpart= (float*) take((size_t)8*8192*4);
  __bf16* ffh  = qk;   // FFN hidden aliases qk+vt+ob (75.5 MB)

  const dim3 blk(256);
  const dim3 blk5(512);
  const int BIG = 1<<30;
  cond1_k<<<32, blk, 0, stream>>>(t, target, action, t_w1, t_b1, tg_w1, tg_b1, ac_w1, ac_b1, h3);
  cond2_k<<<dim3(32,8), blk, 0, stream>>>(h3, t_w2, tg_w2, ac_w2, cpart);
  embed_k<<<NROWS_, blk, 0, stream>>>(x, hist, in_w, in_b, cpart, t_b2, tg_b2, ac_b2, zb, memb);

  const int M = NROWS_;
  for (int li=0; li<L_; ++li) {
    const size_t w0 = (size_t)li*D_*D_, b0 = (size_t)li*D_;
    const size_t f1 = (size_t)li*D_*FF_, fb1 = (size_t)li*FF_;
    wprep_k<<<4096, blk, 0, stream>>>(sa_wq+w0, sa_wk+w0, sa_wv+w0, sa_wo+w0,
                                      ca_wq+w0, ca_wk+w0, ca_wv+w0, ca_wo+w0,
                                      ff_w1+f1, ff_w2+f1, wbuf);
    // self-attention: fused QKV (N=3072), 256^2 kernel
    gemm256_k<3,0><<<36*12, blk5, 0, stream>>>(zb, zb, BIG, wbuf+0*1048576,
                                               sa_bq+b0, sa_bk+b0, sa_bv+b0, 1024, 2048,
                                               qk, vt, M, 3072, 1024, 2048, 2048);
    attn_k<<<1152, blk, 0, stream>>>(qk, vt, ob);
    // o-proj + residual(zb) -> ysum (f32)
    gemm192_k<0,0,1><<<48*4, blk5, 0, stream>>>(ob, wbuf+3*1048576, sa_bo+b0, ysum, zb,
                                                M, 1024, 1024, 1024);
    ln_k<<<NROWS_, blk, 0, stream>>>(ysum, ln1_g+b0, ln1_b+b0, zb);
    // cross-attention: fused Q|KV (N=3072); Q cols read zb, K/V cols read memb
    gemm256_k<3,0><<<36*12, blk5, 0, stream>>>(zb, memb, 1024, wbuf+4*1048576,
                                               ca_bq+b0, ca_bk+b0, ca_bv+b0, 1024, 2048,
                                               qk, vt, M, 3072, 1024, 2048, 2048);
    attn_k<<<1152, blk, 0, stream>>>(qk, vt, ob);
    gemm192_k<0,0,1><<<48*4, blk5, 0, stream>>>(ob, wbuf+7*1048576, ca_bo+b0, ysum, zb,
                                                M, 1024, 1024, 1024);
    ln_k<<<NROWS_, blk, 0, stream>>>(ysum, ln2_g+b0, ln2_b+b0, zb);
    // FFN
    gemm192_k<1,1,0><<<48*16, blk5, 0, stream>>>(zb, wbuf+(size_t)8*1048576, ff_b1+fb1, ffh, nullptr,
                                                 M, 4096, 1024, 4096);
    gemm192_k<0,0,1><<<48*4, blk5, 0, stream>>>(ffh, wbuf+(size_t)12*1048576, ff_b2+b0, ysum, zb,
                                                M, 1024, 4096, 1024);
    ln_k<<<NROWS_, blk, 0, stream>>>(ysum, ln3_g+b0, ln3_b+b0, zb);
  }
  outp_k<<<2048, blk, 0, stream>>>(zb, out_w, out_b, (float*)d_out);
}

// Round 16
// 3861.883 us; speedup vs baseline: 1.0777x; 1.0009x over previous
//
#include <hip/hip_runtime.h>
#include <hip/hip_bf16.h>
#include <stdint.h>

#define B_    8
#define S_    1024
#define HIST_ 128
#define T_    1152
#define D_    1024
#define NH_   16
#define DH_   64
#define FF_   4096
#define L_    6
#define NROWS_ (B_*T_)   /* 9216 */

typedef __attribute__((ext_vector_type(8))) __bf16 bf16x8;
typedef __attribute__((ext_vector_type(4))) __bf16 bf16x4;
typedef __attribute__((ext_vector_type(4))) float  f32x4;

static __device__ __forceinline__ f32x4 mfma16(bf16x8 a, bf16x8 b, f32x4 c) {
  return __builtin_amdgcn_mfma_f32_16x16x32_bf16(a, b, c, 0, 0, 0);
}
static __device__ __forceinline__ void gload16(const __bf16* g, __bf16* l) {
  __builtin_amdgcn_global_load_lds((const __attribute__((address_space(1))) void*)g,
                                   (__attribute__((address_space(3))) void*)l, 16, 0, 0);
}
static __device__ __forceinline__ void gload16b(const char* g, char* l) {
  __builtin_amdgcn_global_load_lds((const __attribute__((address_space(1))) void*)g,
                                   (__attribute__((address_space(3))) void*)l, 16, 0, 0);
}
// bijective XCD swizzle (m204)
static __device__ __forceinline__ int xcd_swz(int orig, int nwg) {
  const int q = nwg >> 3, r = nwg & 7;
  const int x = orig & 7, i = orig >> 3;
  return (x < r ? x*(q+1) : r*(q+1) + (x-r)*q) + i;
}

// ---------------- 192x256 GEMM, BK=64, 8 waves (2Mx4N), counted-vmcnt pipeline ----------------
// (o-proj / FFN1 / FFN2) — RESADD fuses the residual add: out = acc + bias + resid (f32)
template<int BF16OUT, int RELU, int RESADD>
__global__ __launch_bounds__(512, 2) void gemm192_k(const __bf16* __restrict__ A,
                                                    const __bf16* __restrict__ Bt,
                                                    const float* __restrict__ bias,
                                                    void* __restrict__ Cout,
                                                    const __bf16* __restrict__ resid,
                                                    int M, int N, int K, int ldc) {
  __shared__ __align__(16) char Lds[2][57344];
  const int tid = threadIdx.x;
  const int wid = tid >> 6, ln = tid & 63;
  const int wm = wid >> 2, wn = wid & 3;
  const int l15 = ln & 15, g = ln >> 4;
  const int nbx = N >> 8;
  const int wg = xcd_swz(blockIdx.x, gridDim.x);
  const int m0 = (wg / nbx) * 192, n0 = (wg % nbx) << 8;
  const size_t rstep = (size_t)K * 2;

  const char* srcp[7];
  int dsto[7];
#pragma unroll
  for (int p = 0; p < 7; ++p) {
    const int off = p*8192 + tid*16;
    int mat, ks, row;
    if (off < 12288)      { mat = 0; ks = 0; row = off >> 6; }
    else if (off < 24576) { mat = 0; ks = 1; row = (off - 12288) >> 6; }
    else if (off < 40960) { mat = 1; ks = 0; row = (off - 24576) >> 6; }
    else                  { mat = 1; ks = 1; row = (off - 40960) >> 6; }
    const int chn = (off >> 4) & 3;
    const int kb = ks*64 + ((chn ^ ((row >> 1) & 3)) << 4);
    srcp[p] = (mat ? (const char*)Bt + (size_t)(n0 + row)*rstep
                   : (const char*)A  + (size_t)(m0 + row)*rstep) + kb;
    dsto[p] = off;
  }
  auto stage_range = [&](int buf, int t, int p0, int p1) {
    char* lb = &Lds[buf][0];
    const size_t tb = (size_t)t << 7;
#pragma unroll
    for (int p = p0; p < p1; ++p) gload16b(srcp[p] + tb, lb + dsto[p]);
  };

  const int xr = (g ^ ((l15 >> 1) & 3)) << 4;
  const int arow = l15*64 + xr;
  const int aoffm = (wm*96) * 64;
  const int boff  = 24576 + (wn*64) * 64;

  const f32x4 zero = {0.f,0.f,0.f,0.f};
  f32x4 acc[6][4];
#pragma unroll
  for (int i=0;i<6;i++)
#pragma unroll
    for (int j=0;j<4;j++) acc[i][j] = zero;

  stage_range(0, 0, 0, 7); stage_range(1, 1, 0, 7);

  const int NT = K >> 6;
  for (int t = 0; t < NT; ++t) {
    const int buf = t & 1;
    if (t == NT-1) { asm volatile("s_waitcnt vmcnt(0)" ::: "memory"); }
    else           { asm volatile("s_waitcnt vmcnt(7)" ::: "memory"); }
    __builtin_amdgcn_s_barrier();
    const char* bufp = &Lds[buf][0];
    bf16x8 a0[6], a1[6], b0[4], b1[4];
#pragma unroll
    for (int mi=0;mi<6;mi++) a0[mi] = *(const bf16x8*)(bufp + aoffm + mi*1024 + arow);
#pragma unroll
    for (int ni=0;ni<4;ni++) b0[ni] = *(const bf16x8*)(bufp + boff + ni*1024 + arow);
#pragma unroll
    for (int mi=0;mi<6;mi++) a1[mi] = *(const bf16x8*)(bufp + 12288 + aoffm + mi*1024 + arow);
    __builtin_amdgcn_s_setprio(1);
#pragma unroll
    for (int mi=0;mi<6;mi++)
#pragma unroll
      for (int ni=0;ni<4;ni++) acc[mi][ni] = mfma16(a0[mi], b0[ni], acc[mi][ni]);
    __builtin_amdgcn_s_setprio(0);
#pragma unroll
    for (int ni=0;ni<4;ni++) b1[ni] = *(const bf16x8*)(bufp + boff + 16384 + ni*1024 + arow);
    asm volatile("s_waitcnt lgkmcnt(0)" ::: "memory");
    __builtin_amdgcn_s_barrier();           // all waves done reading buf
    const bool st = (t + 2 <= NT - 1);
    if (st) stage_range(buf, t + 2, 0, 4);
    __builtin_amdgcn_s_setprio(1);
#pragma unroll
    for (int mi=0;mi<6;mi++)
#pragma unroll
      for (int ni=0;ni<4;ni++) acc[mi][ni] = mfma16(a1[mi], b1[ni], acc[mi][ni]);
    __builtin_amdgcn_s_setprio(0);
    if (st) stage_range(buf, t + 2, 4, 7);
  }

  const int colb = n0 + wn*64 + l15;
#pragma unroll
  for (int mi=0;mi<6;mi++) {
    const int row = m0 + wm*96 + mi*16 + g*4;
#pragma unroll
    for (int ni=0;ni<4;ni++) {
      const int col = colb + ni*16;
      const float bv = bias[col];
#pragma unroll
      for (int j=0;j<4;j++) {
        float v = acc[mi][ni][j] + bv;
        if (RESADD) v += (float)resid[(size_t)(row+j)*ldc + col];
        if (RELU) v = fmaxf(v, 0.f);
        if (BF16OUT) ((__bf16*)Cout)[(size_t)(row+j)*ldc + col] = (__bf16)v;
        else         ((float*)Cout)[(size_t)(row+j)*ldc + col] = v;
      }
    }
  }
}

// ---------------- 256x256 GEMM (QKV shapes) — R8-proven ----------------
template<int OUTMODE, int RELU>
__global__ __launch_bounds__(512, 2) void gemm256_k(const __bf16* __restrict__ A,
                                                    const __bf16* __restrict__ A2, int asplit,
                                                    const __bf16* __restrict__ Bt,
                                                    const float* __restrict__ b1,
                                                    const float* __restrict__ b2,
                                                    const float* __restrict__ b3, int s1, int s2,
                                                    void* __restrict__ CoutRM,
                                                    __bf16* __restrict__ CoutT,
                                                    int M, int N, int K, int ldc, int tsplit) {
  __shared__ __align__(16) __bf16 Lds[2][2][2][8192];
  const int tid = threadIdx.x;
  const int wid = tid >> 6, ln = tid & 63;
  const int wm = wid >> 2, wn = wid & 3;
  const int l15 = ln & 15, g = ln >> 4;
  const int nbx = N >> 8;
  const int wg = xcd_swz(blockIdx.x, gridDim.x);
  const int m0 = (wg / nbx) << 8, n0 = (wg % nbx) << 8;
  const size_t rstep = (size_t)K * 2;
  const __bf16* Aeff = (n0 < asplit) ? A : A2;

  const int srow = tid >> 2, schunk = tid & 3;
  const int sx = (schunk ^ ((srow >> 1) & 3)) << 4;
  const char* gAr = (const char*)Aeff + (size_t)(m0 + srow)*rstep + sx;
  const char* gBr = (const char*)Bt   + (size_t)(n0 + srow)*rstep + sx;
  const size_t hstep = (size_t)128 * rstep;

  const int xr = (g ^ ((l15 >> 1) & 3)) << 4;
  const int arow = l15 * 64 + xr;
  const int aoffm = (wm*128) * 64;
  const int boff  = (wn*64) * 64;

  const f32x4 zero = {0.f,0.f,0.f,0.f};
  f32x4 acc[8][4];
#pragma unroll
  for (int i=0;i<8;i++)
#pragma unroll
    for (int j=0;j<4;j++) acc[i][j] = zero;

  auto stage4 = [&](int buf, int ks, int tile) {
    const size_t off = (size_t)tile*128 + (size_t)ks*64;
    char* la = (char*)&Lds[buf][ks][0][0];
    char* lb = (char*)&Lds[buf][ks][1][0];
    gload16b(gAr + off,         la + tid*16);
    gload16b(gAr + off + hstep, la + 8192 + tid*16);
    gload16b(gBr + off,         lb + tid*16);
    gload16b(gBr + off + hstep, lb + 8192 + tid*16);
  };

  auto ktile = [&](int buf, bool st, int stile, bool gate0) {
    if (gate0) { asm volatile("s_waitcnt vmcnt(0)" ::: "memory"); }
    else       { asm volatile("s_waitcnt vmcnt(8)" ::: "memory"); }
    __builtin_amdgcn_s_barrier();
    const char* As0 = (const char*)&Lds[buf][0][0][0];
    const char* Bs0 = (const char*)&Lds[buf][0][1][0];
    const char* As1 = (const char*)&Lds[buf][1][0][0];
    const char* Bs1 = (const char*)&Lds[buf][1][1][0];
    bf16x8 a0[4], a1[4], b0[4], a2[4], b1v[4], a3[4];
#pragma unroll
    for (int mi=0;mi<4;mi++) a0[mi] = *(const bf16x8*)(As0 + aoffm + mi*1024 + arow);
#pragma unroll
    for (int ni=0;ni<4;ni++) b0[ni] = *(const bf16x8*)(Bs0 + boff + ni*1024 + arow);
#pragma unroll
    for (int mi=0;mi<4;mi++) a1[mi] = *(const bf16x8*)(As0 + aoffm + 4096 + mi*1024 + arow);
    __builtin_amdgcn_s_setprio(1);
#pragma unroll
    for (int mi=0;mi<4;mi++)
#pragma unroll
      for (int ni=0;ni<4;ni++) acc[mi][ni] = mfma16(a0[mi], b0[ni], acc[mi][ni]);
    __builtin_amdgcn_s_setprio(0);
#pragma unroll
    for (int mi=0;mi<4;mi++) a2[mi]  = *(const bf16x8*)(As1 + aoffm + mi*1024 + arow);
#pragma unroll
    for (int ni=0;ni<4;ni++) b1v[ni] = *(const bf16x8*)(Bs1 + boff + ni*1024 + arow);
    asm volatile("s_waitcnt lgkmcnt(0)" ::: "memory");
    __builtin_amdgcn_s_barrier();
    if (st) stage4(buf, 0, stile);
    __builtin_amdgcn_s_setprio(1);
#pragma unroll
    for (int mi=0;mi<4;mi++)
#pragma unroll
      for (int ni=0;ni<4;ni++) acc[4+mi][ni] = mfma16(a1[mi], b0[ni], acc[4+mi][ni]);
    __builtin_amdgcn_s_setprio(0);
#pragma unroll
    for (int mi=0;mi<4;mi++) a3[mi] = *(const bf16x8*)(As1 + aoffm + 4096 + mi*1024 + arow);
    __builtin_amdgcn_s_setprio(1);
#pragma unroll
    for (int mi=0;mi<4;mi++)
#pragma unroll
      for (int ni=0;ni<4;ni++) acc[mi][ni] = mfma16(a2[mi], b1v[ni], acc[mi][ni]);
    __builtin_amdgcn_s_setprio(0);
    asm volatile("s_waitcnt lgkmcnt(0)" ::: "memory");
    __builtin_amdgcn_s_barrier();
    if (st) stage4(buf, 1, stile);
    __builtin_amdgcn_s_setprio(1);
#pragma unroll
    for (int mi=0;mi<4;mi++)
#pragma unroll
      for (int ni=0;ni<4;ni++) acc[4+mi][ni] = mfma16(a3[mi], b1v[ni], acc[4+mi][ni]);
    __builtin_amdgcn_s_setprio(0);
  };

  stage4(0, 0, 0); stage4(0, 1, 0);
  stage4(1, 0, 1); stage4(1, 1, 1);

  const int NT = K >> 6, NI = NT >> 1;
  for (int i = 0; i < NI; ++i) {
    const bool st = (i + 1 < NI);
    ktile(0, st, 2*i + 2, false);
    ktile(1, st, 2*i + 3, i == NI - 1);
  }

  const int colb = n0 + wn*64 + l15;
#pragma unroll
  for (int mi=0;mi<8;mi++) {
    const int row = m0 + wm*128 + mi*16 + g*4;
#pragma unroll
    for (int ni=0;ni<4;ni++) {
      const int col = colb + ni*16;
      const float bv = (col < s1) ? b1[col] : ((col < s2) ? b2[col-s1] : b3[col-s2]);
      if (OUTMODE == 3 && col >= tsplit) {
        bf16x4 ct;
#pragma unroll
        for (int j=0;j<4;j++) {
          float v = acc[mi][ni][j] + bv;
          if (RELU) v = fmaxf(v, 0.f);
          ct[j] = (__bf16)v;
        }
        *(bf16x4*)(CoutT + (size_t)(col - tsplit)*M + row) = ct;
      } else {
#pragma unroll
        for (int j=0;j<4;j++) {
          float v = acc[mi][ni][j] + bv;
          if (RELU) v = fmaxf(v, 0.f);
          if (OUTMODE == 0) ((float*)CoutRM)[(size_t)(row+j)*ldc + col] = v;
          else              ((__bf16*)CoutRM)[(size_t)(row+j)*ldc + col] = (__bf16)v;
        }
      }
    }
  }
}

// ---------------- Flash attention, causal, NH=16 DH=64, T13 defer-max ----------------
__global__ __launch_bounds__(256) void attn_k(const __bf16* __restrict__ QK,
                                              const __bf16* __restrict__ Vt,
                                              __bf16* __restrict__ O) {
  __shared__ __align__(16) __bf16 Ks[2][4096];
  __shared__ __align__(16) __bf16 Vs[2][4096];
  __shared__ __align__(16) __bf16 Pl[4][32*72];
  const int tid = threadIdx.x;
  const int wv = tid >> 6, ln = tid & 63;
  const int l15 = ln & 15, g = ln >> 4;
  const int wg = xcd_swz(blockIdx.x, 1152);
  const int qb = 8 - (wg % 9);
  const int hd = (wg / 9) & 15;
  const int b  = wg / 144;
  const int q0 = qb*128 + wv*32;

  bf16x8 qf[2][2];
#pragma unroll
  for (int f=0; f<2; ++f)
#pragma unroll
    for (int h=0; h<2; ++h)
      qf[f][h] = *(const bf16x8*)(QK + (size_t)(b*T_ + q0 + f*16 + l15)*2048 + hd*64 + h*32 + g*8);

  const int sr = tid >> 3;
  const int si = tid & 7;
  const int cb0 = (si*16) ^ ((sr & 7) << 4);
  const char* kg = (const char*)(QK + (size_t)b*T_*2048 + 1024 + hd*64);
  const char* vg = (const char*)(Vt + (size_t)hd*64*NROWS_ + (size_t)b*T_);

  const f32x4 zero = {0.f,0.f,0.f,0.f};
  f32x4 o[2][4];
#pragma unroll
  for (int f=0; f<2; ++f)
#pragma unroll
    for (int d=0; d<4; ++d) o[f][d] = zero;
  float mrun[2] = {-3.0e38f, -3.0e38f};
  float lrun[2] = {0.f, 0.f};
  const int nt = 2*qb + 2;

  {
    const int c = 0, kt = 0;
#pragma unroll
    for (int hr=0; hr<2; ++hr) {
      const int r = sr + hr*32;
      gload16((const __bf16*)(kg + (size_t)(kt + r)*4096 + cb0), &Ks[c][0] + hr*2048 + wv*512);
      gload16((const __bf16*)(vg + (size_t)r*(NROWS_*2) + (size_t)kt*2 + cb0), &Vs[c][0] + hr*2048 + wv*512);
    }
  }

  for (int t = 0; t < nt; ++t) {
    __syncthreads();
    if (t+1 < nt) {
      const int c = (t+1)&1, kt2 = (t+1)*64;
#pragma unroll
      for (int hr=0; hr<2; ++hr) {
        const int r = sr + hr*32;
        gload16((const __bf16*)(kg + (size_t)(kt2 + r)*4096 + cb0), &Ks[c][0] + hr*2048 + wv*512);
        gload16((const __bf16*)(vg + (size_t)r*(NROWS_*2) + (size_t)kt2*2 + cb0), &Vs[c][0] + hr*2048 + wv*512);
      }
    }
    const int kt = t*64;
    if (kt > q0 + 31) continue;
    const char* ks = (const char*)&Ks[t&1][0];
    const char* vs = (const char*)&Vs[t&1][0];

#pragma unroll
    for (int f=0; f<2; ++f) {
      const int qrow = q0 + f*16 + l15;
      f32x4 st[4];
      __builtin_amdgcn_s_setprio(1);
#pragma unroll
      for (int kf=0; kf<4; ++kf) {
        const int row = kf*16 + l15;
        const int swz = (row & 7) << 4;
        const bf16x8 k0 = *(const bf16x8*)(ks + row*128 + ((g*16) ^ swz));
        const bf16x8 k1 = *(const bf16x8*)(ks + row*128 + ((64 + g*16) ^ swz));
        st[kf] = mfma16(k1, qf[f][1], mfma16(k0, qf[f][0], zero));
      }
      __builtin_amdgcn_s_setprio(0);
      float p[16];
#pragma unroll
      for (int kf=0; kf<4; ++kf)
#pragma unroll
        for (int r=0; r<4; ++r) {
          const int kgl = kt + kf*16 + g*4 + r;
          p[kf*4+r] = (kgl <= qrow) ? st[kf][r]*0.125f : -3.0e38f;
        }
      float mloc = p[0];
#pragma unroll
      for (int i=1;i<16;i++) mloc = fmaxf(mloc, p[i]);
      mloc = fmaxf(mloc, __shfl_xor(mloc, 16));
      mloc = fmaxf(mloc, __shfl_xor(mloc, 32));
      if (__all(mloc - mrun[f] <= 8.f)) {
        float ls = 0.f;
#pragma unroll
        for (int i=0;i<16;i++) { p[i] = __expf(p[i] - mrun[f]); ls += p[i]; }
        ls += __shfl_xor(ls, 16); ls += __shfl_xor(ls, 32);
        lrun[f] += ls;
      } else {
        const float mnew = fmaxf(mrun[f], mloc);
        const float corr = __expf(mrun[f] - mnew);
        float ls = 0.f;
#pragma unroll
        for (int i=0;i<16;i++) { p[i] = __expf(p[i] - mnew); ls += p[i]; }
        ls += __shfl_xor(ls, 16); ls += __shfl_xor(ls, 32);
        lrun[f] = lrun[f]*corr + ls;
        mrun[f] = mnew;
        float cr[4];
#pragma unroll
        for (int r=0;r<4;r++) cr[r] = __shfl(corr, g*4 + r);
#pragma unroll
        for (int db=0; db<4; ++db)
#pragma unroll
          for (int r=0;r<4;r++) o[f][db][r] *= cr[r];
      }
#pragma unroll
      for (int kf=0; kf<4; ++kf) {
        bf16x4 pw;
#pragma unroll
        for (int r=0;r<4;r++) pw[r] = (__bf16)p[kf*4+r];
        *(bf16x4*)(&Pl[wv][(f*16 + l15)*72 + kf*16 + g*4]) = pw;
      }
    }
    __builtin_amdgcn_s_setprio(1);
#pragma unroll
    for (int f=0; f<2; ++f)
#pragma unroll
      for (int ks2=0; ks2<2; ++ks2) {
        const bf16x8 pa = *(const bf16x8*)(&Pl[wv][(f*16 + l15)*72 + ks2*32 + g*8]);
#pragma unroll
        for (int db=0; db<4; ++db) {
          const int d = db*16 + l15;
          const bf16x8 vf = *(const bf16x8*)(vs + d*128 + ((ks2*64 + g*16) ^ ((d & 7) << 4)));
          o[f][db] = mfma16(pa, vf, o[f][db]);
        }
      }
    __builtin_amdgcn_s_setprio(0);
  }

#pragma unroll
  for (int f=0; f<2; ++f) {
    const float inv = 1.f / lrun[f];
    float ir[4];
#pragma unroll
    for (int r=0;r<4;r++) ir[r] = __shfl(inv, g*4 + r);
#pragma unroll
    for (int db=0; db<4; ++db)
#pragma unroll
      for (int r=0;r<4;r++)
        O[(size_t)(b*T_ + q0 + f*16 + g*4 + r)*D_ + hd*64 + db*16 + l15] = (__bf16)(o[f][db][r]*ir[r]);
  }
}

// ---------------- batched weight prep: 64x64 tiles ----------------
__global__ __launch_bounds__(256) void wprep_k(const float* __restrict__ q, const float* __restrict__ k,
                                               const float* __restrict__ v, const float* __restrict__ o,
                                               const float* __restrict__ cq, const float* __restrict__ ck,
                                               const float* __restrict__ cv, const float* __restrict__ co,
                                               const float* __restrict__ f1, const float* __restrict__ f2,
                                               __bf16* __restrict__ wb) {
  __shared__ float tile[64][65];
  const int id = blockIdx.x;
  const float* src; __bf16* dst; int R, C, bx, by;
  if (id < 2048) {
    const int m = id >> 8, t = id & 255; bx = t & 15; by = t >> 4;
    const float* srcs[8] = {q,k,v,o,cq,ck,cv,co};
    src = srcs[m]; dst = wb + (size_t)m*1048576; R = 1024; C = 1024;
  } else if (id < 3072) {
    const int t = id - 2048; bx = t & 63; by = t >> 6;
    src = f1; dst = wb + (size_t)8*1048576; R = 1024; C = 4096;
  } else {
    const int t = id - 3072; bx = t & 15; by = t >> 4;
    src = f2; dst = wb + (size_t)12*1048576; R = 4096; C = 1024;
  }
  const int tx = threadIdx.x & 63, ty = threadIdx.x >> 6;
  const int r0 = by*64, c0 = bx*64;
#pragma unroll
  for (int i=0;i<16;i++) tile[ty+i*4][tx] = src[(size_t)(r0+ty+i*4)*C + c0+tx];
  __syncthreads();
#pragma unroll
  for (int i=0;i<16;i++) dst[(size_t)(c0+ty+i*4)*R + r0+tx] = (__bf16)tile[tx][ty+i*4];
}

// ---------------- LayerNorm: zb = LN(ysum)*g+b ----------------
__global__ __launch_bounds__(256) void ln_k(const float* __restrict__ ysum,
                                            const float* __restrict__ gam, const float* __restrict__ bet,
                                            __bf16* __restrict__ zbout) {
  const int row = blockIdx.x, tid = threadIdx.x;
  const f32x4 v = ((const f32x4*)(ysum + (size_t)row*D_))[tid];
  float s1 = v[0]+v[1]+v[2]+v[3];
  float s2 = v[0]*v[0]+v[1]*v[1]+v[2]*v[2]+v[3]*v[3];
#pragma unroll
  for (int off=32; off; off>>=1) { s1 += __shfl_xor(s1,off); s2 += __shfl_xor(s2,off); }
  __shared__ float red[8];
  const int wv = tid>>6, ln = tid&63;
  if (ln==0) { red[wv] = s1; red[4+wv] = s2; }
  __syncthreads();
  s1 = red[0]+red[1]+red[2]+red[3];
  s2 = red[4]+red[5]+red[6]+red[7];
  const float mean = s1 * (1.f/1024.f);
  const float var = s2 * (1.f/1024.f) - mean*mean;
  const float rs = rsqrtf(var + 1e-5f);
  const f32x4 gv = ((const f32x4*)gam)[tid];
  const f32x4 bv = ((const f32x4*)bet)[tid];
  bf16x4 rb;
#pragma unroll
  for (int j=0;j<4;j++) rb[j] = (__bf16)((v[j]-mean)*rs*gv[j] + bv[j]);
  ((bf16x4*)(zbout + (size_t)row*D_))[tid] = rb;
}

// ---------------- cond MLP branch hiddens ----------------
__global__ __launch_bounds__(256) void cond1_k(const int* __restrict__ t, const float* __restrict__ target,
                                               const float* __restrict__ action,
                                               const float* __restrict__ t_w1, const float* __restrict__ t_b1,
                                               const float* __restrict__ tg_w1, const float* __restrict__ tg_b1,
                                               const float* __restrict__ ac_w1, const float* __restrict__ ac_b1,
                                               float* __restrict__ h3) {
  const int i = blockIdx.x*256 + threadIdx.x;
  const int b = i >> 10, d = i & 1023;
  float u = (float)t[b] * t_w1[d] + t_b1[d];
  h3[i] = u / (1.f + __expf(-u));
  u = tg_b1[d];
#pragma unroll
  for (int j=0;j<3;j++) u += target[b*3+j]*tg_w1[j*1024+d];
  h3[8192 + i] = u / (1.f + __expf(-u));
  u = ac_b1[d];
#pragma unroll
  for (int j=0;j<5;j++) u += action[b*5+j]*ac_w1[j*1024+d];
  h3[16384 + i] = u / (1.f + __expf(-u));
}

__global__ __launch_bounds__(256) void cond2_k(const float* __restrict__ h3,
                                               const float* __restrict__ t_w2, const float* __restrict__ tg_w2,
                                               const float* __restrict__ ac_w2, float* __restrict__ cpart) {
  const int i = blockIdx.x*256 + threadIdx.x;
  const int ks = blockIdx.y;
  const int b = i >> 10, d = i & 1023;
  const float* ht = h3 + b*1024;
  const float* hg = h3 + 8192 + b*1024;
  const float* ha = h3 + 16384 + b*1024;
  float a = 0.f;
  for (int k = ks*128; k < ks*128+128; ++k)
    a += ht[k]*t_w2[(size_t)k*1024+d] + hg[k]*tg_w2[(size_t)k*1024+d] + ha[k]*ac_w2[(size_t)k*1024+d];
  cpart[ks*8192 + i] = a;
}

// ---------------- embedding: writes zb + memb (bf16 stream) ----------------
__global__ __launch_bounds__(256) void embed_k(const float* __restrict__ x, const float* __restrict__ hist,
                                               const float* __restrict__ in_w, const float* __restrict__ in_b,
                                               const float* __restrict__ cpart,
                                               const float* __restrict__ t_b2, const float* __restrict__ tg_b2,
                                               const float* __restrict__ ac_b2,
                                               __bf16* __restrict__ zb, __bf16* __restrict__ memb) {
  const int row = blockIdx.x, tid = threadIdx.x;
  const int b = row / T_, tt = row - b*T_;
  const float* feat = (tt < HIST_) ? (hist + ((size_t)b*HIST_ + tt)*10) : (x + ((size_t)b*S_ + (tt-HIST_))*10);
  float f[10];
#pragma unroll
  for (int s=0;s<10;s++) f[s] = feat[s];
  const float te = (float)((tt < HIST_) ? tt : tt - HIST_);
  f32x4 a = ((const f32x4*)in_b)[tid];
#pragma unroll
  for (int u=0;u<2;u++) {
    const int d = tid*4 + 2*u;
    const float freq = __expf((float)d * (-9.210340371976184f/1024.f));
    float sn, cs;
    __sincosf(te*freq, &sn, &cs);
    a[2*u] += sn; a[2*u+1] += cs;
  }
  a += ((const f32x4*)t_b2)[tid];
  a += ((const f32x4*)tg_b2)[tid];
  a += ((const f32x4*)ac_b2)[tid];
  const int cb = b*256 + tid;
#pragma unroll
  for (int ks=0;ks<8;ks++) a += ((const f32x4*)cpart)[ks*2048 + cb];
#pragma unroll
  for (int s=0;s<10;s++) {
    const f32x4 wv = ((const f32x4*)(in_w + s*1024))[tid];
    a += wv * f[s];
  }
  bf16x4 ab;
#pragma unroll
  for (int j=0;j<4;j++) ab[j] = (__bf16)a[j];
  ((bf16x4*)(zb + (size_t)row*D_))[tid] = ab;
  ((bf16x4*)(memb + (size_t)row*D_))[tid] = ab;
}

// ---------------- output projection (reads bf16 stream) ----------------
__global__ __launch_bounds__(256) void outp_k(const __bf16* __restrict__ z, const float* __restrict__ w,
                                              const float* __restrict__ bo, float* __restrict__ out) {
  const int wv = threadIdx.x>>6, ln = threadIdx.x&63;
  const int row = blockIdx.x*4 + wv;
  const int b = row >> 10, s = row & 1023;
  const __bf16* zr = z + ((size_t)b*T_ + HIST_ + s)*D_;
  float acc[10];
#pragma unroll
  for (int o=0;o<10;o++) acc[o]=0.f;
  for (int k=ln; k<1024; k+=64) {
    const float zv = (float)zr[k];
    const float* wr = w + k*10;
#pragma unroll
    for (int o=0;o<10;o++) acc[o] += zv*wr[o];
  }
#pragma unroll
  for (int o=0;o<10;o++) {
#pragma unroll
    for (int off=32; off; off>>=1) acc[o] += __shfl_xor(acc[o], off);
  }
  if (ln==0) {
#pragma unroll
    for (int o=0;o<10;o++) out[(size_t)row*10+o] = acc[o] + bo[o];
  }
}

extern "C" void kernel_launch(void* const* d_in, const int* in_sizes, int n_in,
                              void* d_out, int out_size, void* d_ws, size_t ws_size,
                              hipStream_t stream) {
  const float* x      = (const float*)d_in[0];
  const int*   t      = (const int*)  d_in[1];
  const float* target = (const float*)d_in[2];
  const float* action = (const float*)d_in[3];
  const float* hist   = (const float*)d_in[4];
  const float* in_w   = (const float*)d_in[5];
  const float* in_b   = (const float*)d_in[6];
  const float* t_w1   = (const float*)d_in[7];
  const float* t_b1   = (const float*)d_in[8];
  const float* t_w2   = (const float*)d_in[9];
  const float* t_b2   = (const float*)d_in[10];
  const float* tg_w1  = (const float*)d_in[11];
  const float* tg_b1  = (const float*)d_in[12];
  const float* tg_w2  = (const float*)d_in[13];
  const float* tg_b2  = (const float*)d_in[14];
  const float* ac_w1  = (const float*)d_in[15];
  const float* ac_b1  = (const float*)d_in[16];
  const float* ac_w2  = (const float*)d_in[17];
  const float* ac_b2  = (const float*)d_in[18];
  const float* sa_wq  = (const float*)d_in[19];
  const float* sa_bq  = (const float*)d_in[20];
  const float* sa_wk  = (const float*)d_in[21];
  const float* sa_bk  = (const float*)d_in[22];
  const float* sa_wv  = (const float*)d_in[23];
  const float* sa_bv  = (const float*)d_in[24];
  const float* sa_wo  = (const float*)d_in[25];
  const float* sa_bo  = (const float*)d_in[26];
  const float* ca_wq  = (const float*)d_in[27];
  const float* ca_bq  = (const float*)d_in[28];
  const float* ca_wk  = (const float*)d_in[29];
  const float* ca_bk  = (const float*)d_in[30];
  const float* ca_wv  = (const float*)d_in[31];
  const float* ca_bv  = (const float*)d_in[32];
  const float* ca_wo  = (const float*)d_in[33];
  const float* ca_bo  = (const float*)d_in[34];
  const float* ln1_g  = (const float*)d_in[35];
  const float* ln1_b  = (const float*)d_in[36];
  const float* ln2_g  = (const float*)d_in[37];
  const float* ln2_b  = (const float*)d_in[38];
  const float* ln3_g  = (const float*)d_in[39];
  const float* ln3_b  = (const float*)d_in[40];
  const float* ff_w1  = (const float*)d_in[41];
  const float* ff_b1  = (const float*)d_in[42];
  const float* ff_w2  = (const float*)d_in[43];
  const float* ff_b2  = (const float*)d_in[44];
  const float* out_w  = (const float*)d_in[45];
  const float* out_b  = (const float*)d_in[46];

  if (ws_size < (size_t)224*1024*1024) return;

  char* p = (char*)d_ws;
  auto take = [&](size_t bytes) { char* r = p; p += (bytes + 255) & ~(size_t)255; return r; };
  __bf16* wbuf = (__bf16*)take((size_t)16*1024*1024*2);
  __bf16* zb   = (__bf16*)take((size_t)NROWS_*D_*2);
  __bf16* memb = (__bf16*)take((size_t)NROWS_*D_*2);
  __bf16* qk   = (__bf16*)take((size_t)NROWS_*2048*2);
  __bf16* vt   = (__bf16*)take((size_t)1024*NROWS_*2);
  __bf16* ob   = (__bf16*)take((size_t)NROWS_*D_*2);
  float*  ysum = (float*) take((size_t)NROWS_*D_*4);
  float*  h3   = (float*) take((size_t)3*8192*4);
  float*  cpart= (float*) take((size_t)8*8192*4);
  __bf16* ffh  = qk;   // FFN hidden aliases qk+vt+ob (75.5 MB)

  const dim3 blk(256);
  const dim3 blk5(512);
  const int BIG = 1<<30;
  cond1_k<<<32, blk, 0, stream>>>(t, target, action, t_w1, t_b1, tg_w1, tg_b1, ac_w1, ac_b1, h3);
  cond2_k<<<dim3(32,8), blk, 0, stream>>>(h3, t_w2, tg_w2, ac_w2, cpart);
  embed_k<<<NROWS_, blk, 0, stream>>>(x, hist, in_w, in_b, cpart, t_b2, tg_b2, ac_b2, zb, memb);

  const int M = NROWS_;
  for (int li=0; li<L_; ++li) {
    const size_t w0 = (size_t)li*D_*D_, b0 = (size_t)li*D_;
    const size_t f1 = (size_t)li*D_*FF_, fb1 = (size_t)li*FF_;
    wprep_k<<<4096, blk, 0, stream>>>(sa_wq+w0, sa_wk+w0, sa_wv+w0, sa_wo+w0,
                                      ca_wq+w0, ca_wk+w0, ca_wv+w0, ca_wo+w0,
                                      ff_w1+f1, ff_w2+f1, wbuf);
    // self-attention: fused QKV (N=3072), 256^2 kernel
    gemm256_k<3,0><<<36*12, blk5, 0, stream>>>(zb, zb, BIG, wbuf+0*1048576,
                                               sa_bq+b0, sa_bk+b0, sa_bv+b0, 1024, 2048,
                                               qk, vt, M, 3072, 1024, 2048, 2048);
    attn_k<<<1152, blk, 0, stream>>>(qk, vt, ob);
    // o-proj + residual(zb) -> ysum (f32)
    gemm192_k<0,0,1><<<48*4, blk5, 0, stream>>>(ob, wbuf+3*1048576, sa_bo+b0, ysum, zb,
                                                M, 1024, 1024, 1024);
    ln_k<<<NROWS_, blk, 0, stream>>>(ysum, ln1_g+b0, ln1_b+b0, zb);
    // cross-attention: fused Q|KV (N=3072); Q cols read zb, K/V cols read memb
    gemm256_k<3,0><<<36*12, blk5, 0, stream>>>(zb, memb, 1024, wbuf+4*1048576,
                                               ca_bq+b0, ca_bk+b0, ca_bv+b0, 1024, 2048,
                                               qk, vt, M, 3072, 1024, 2048, 2048);
    attn_k<<<1152, blk, 0, stream>>>(qk, vt, ob);
    gemm192_k<0,0,1><<<48*4, blk5, 0, stream>>>(ob, wbuf+7*1048576, ca_bo+b0, ysum, zb,
                                                M, 1024, 1024, 1024);
    ln_k<<<NROWS_, blk, 0, stream>>>(ysum, ln2_g+b0, ln2_b+b0, zb);
    // FFN
    gemm192_k<1,1,0><<<48*16, blk5, 0, stream>>>(zb, wbuf+(size_t)8*1048576, ff_b1+fb1, ffh, nullptr,
                                                 M, 4096, 1024, 4096);
    gemm192_k<0,0,1><<<48*4, blk5, 0, stream>>>(ffh, wbuf+(size_t)12*1048576, ff_b2+b0, ysum, zb,
                                                M, 1024, 4096, 1024);
    ln_k<<<NROWS_, blk, 0, stream>>>(ysum, ln3_g+b0, ln3_b+b0, zb);
  }
  outp_k<<<2048, blk, 0, stream>>>(zb, out_w, out_b, (float*)d_out);
}